// Round 1
// baseline (12648.072 us; speedup 1.0000x reference)
//
#include <hip/hip_runtime.h>
#include <math.h>

#define TS 64
#define NN 2048
#define NE 32768
#define NH 6
#define NB 128   // 2*TS graph instances

__device__ __forceinline__ float lrelu(float x){ return x >= 0.0f ? x : 0.2f*x; }
__device__ __forceinline__ float eluf(float x){ return x > 0.0f ? x : expm1f(x); }
__device__ __forceinline__ float sigm(float x){ return 1.0f/(1.0f+expf(-x)); }

// ---------- per-layer prep: uS,uD [H*FIN], Wcat [H*FIN, FOUT] (mean folded) ----------
__global__ void prep_layer_kernel(const float* __restrict__ W,
                                  const float* __restrict__ aS,
                                  const float* __restrict__ aD,
                                  float* __restrict__ uS, float* __restrict__ uD,
                                  float* __restrict__ wcat, int FIN, int FOUT) {
  int idx = blockIdx.x * blockDim.x + threadIdx.x;
  int totw = NH * FIN * FOUT;
  if (idx < totw) {
    int k = idx / FOUT, o = idx - k * FOUT;
    int h = k / FIN, f = k - h * FIN;
    wcat[idx] = W[(size_t)(f * NH + h) * FOUT + o] * (1.0f / NH);
  }
  if (idx < NH * FIN) {
    int h = idx / FIN, f = idx - h * FIN;
    const float* wr = W + (size_t)(f * NH + h) * FOUT;
    const float* as = aS + h * FOUT;
    const float* ad = aD + h * FOUT;
    float ss = 0.f, dd = 0.f;
    for (int o = 0; o < FOUT; ++o) { float w = wr[o]; ss += w * as[o]; dd += w * ad[o]; }
    uS[idx] = ss; uD[idx] = dd;
  }
}

// ---------- CSR build ----------
__global__ void hist_kernel(const int* __restrict__ ei1, const int* __restrict__ ei2,
                            int* __restrict__ deg) {
  int gid = blockIdx.x * blockDim.x + threadIdx.x;
  if (gid >= NB * NE) return;
  int gi = gid / NE, e = gid - gi * NE;
  int t = gi >> 1, s = gi & 1;
  const int* ei = s ? ei2 : ei1;
  int dst = ei[(size_t)(t * 2 + 1) * NE + e];
  atomicAdd(&deg[gi * NN + dst], 1);
}

__global__ void scan_kernel(int* __restrict__ degcur, int* __restrict__ row_ptr) {
  int g = blockIdx.x, t = threadIdx.x;           // 128 blocks x 256 threads
  const int PER = NN / 256;                       // 8
  int base = g * NN;
  int loc[PER]; int run = 0;
  for (int i = 0; i < PER; ++i) { loc[i] = run; run += degcur[base + t*PER + i]; }
  __shared__ int part[256];
  __shared__ int offs[256];
  part[t] = run;
  __syncthreads();
  if (t == 0) { int acc = 0; for (int i = 0; i < 256; ++i) { offs[i] = acc; acc += part[i]; } }
  __syncthreads();
  int o = offs[t];
  for (int i = 0; i < PER; ++i) {
    int v = o + loc[i];
    row_ptr[g * (NN + 1) + t*PER + i] = v;
    degcur[base + t*PER + i] = v;                 // becomes scatter cursor
  }
  if (t == 255) row_ptr[g * (NN + 1) + NN] = o + run;
}

__global__ void scatter_kernel(const int* __restrict__ ei1, const int* __restrict__ ei2,
                               const float* __restrict__ ew1, const float* __restrict__ ew2,
                               int* __restrict__ cursor, int* __restrict__ src_sorted,
                               float* __restrict__ ew_sorted) {
  int gid = blockIdx.x * blockDim.x + threadIdx.x;
  if (gid >= NB * NE) return;
  int gi = gid / NE, e = gid - gi * NE;
  int t = gi >> 1, s = gi & 1;
  const int* ei = s ? ei2 : ei1;
  const float* ew = s ? ew2 : ew1;
  int src = ei[(size_t)(t * 2) * NE + e];
  int dst = ei[(size_t)(t * 2 + 1) * NE + e];
  float w = ew[(size_t)t * NE + e];
  int pos = atomicAdd(&cursor[gi * NN + dst], 1);
  src_sorted[(size_t)gi * NE + pos] = src;
  ew_sorted[(size_t)gi * NE + pos] = w;
}

// ---------- stage x into h_ping (stride 4) ----------
__global__ void copyx_kernel(const float* __restrict__ x1, const float* __restrict__ x2,
                             float* __restrict__ hping, int c0, int G) {
  int gid = blockIdx.x * blockDim.x + threadIdx.x;
  int tot = G * NN * 4;
  if (gid >= tot) return;
  int gl = gid / (NN * 4);
  int rem = gid - gl * (NN * 4);
  int gi = c0 + gl;
  int t = gi >> 1, s = gi & 1;
  const float* x = s ? x2 : x1;
  hping[(size_t)gl * NN * 4 + rem] = x[(size_t)t * NN * 4 + rem];
}

// ---------- s/d logits: sdv[row*12 + j] ; j<6 = s(h), j>=6 = d(h) ----------
__global__ void sd_kernel(const float* __restrict__ h, const float* __restrict__ uS,
                          const float* __restrict__ uD, float* __restrict__ sdv,
                          int FIN, int rows) {
  int gid = blockIdx.x * blockDim.x + threadIdx.x;
  if (gid >= rows * 12) return;
  int n = gid / 12, j = gid - n * 12;
  const float* u = (j < 6 ? uS + j * FIN : uD + (j - 6) * FIN);
  const float* hr = h + (size_t)n * FIN;
  float a = 0.f;
  for (int f = 0; f < FIN; f += 4) {
    float4 hv = *(const float4*)(hr + f);
    float4 uv = *(const float4*)(u + f);
    a += hv.x*uv.x + hv.y*uv.y + hv.z*uv.z + hv.w*uv.w;
  }
  sdv[gid] = a;
}

// ---------- per-dst-node softmax + weighted aggregation (two-pass, no atomics) ----------
template<int FIN, int THREADS, int NACC>
__global__ __launch_bounds__(THREADS)
void agg_kernel(const float* __restrict__ h, const float* __restrict__ sdv,
                const int* __restrict__ row_ptr, const int* __restrict__ src_sorted,
                const float* __restrict__ ew_sorted, float* __restrict__ agg, int c0) {
  const int K = NH * FIN;
  int gl = blockIdx.x / NN;
  int n  = blockIdx.x - gl * NN;
  int gi = c0 + gl;
  int t  = threadIdx.x;
  int rp = row_ptr[gi * (NN + 1) + n];
  int re = row_ptr[gi * (NN + 1) + n + 1];
  const int*   srcs = src_sorted + (size_t)gi * NE;
  const float* ews  = ew_sorted  + (size_t)gi * NE;
  size_t nb = (size_t)gl * NN;
  int hh[NACC], ff[NACC]; bool act[NACC]; float dh[NACC];
  #pragma unroll
  for (int i = 0; i < NACC; ++i) {
    int idx = t + i * THREADS;
    act[i] = idx < K;
    hh[i] = idx / FIN;
    ff[i] = idx % FIN;
    dh[i] = act[i] ? sdv[(nb + n) * 12 + 6 + hh[i]] : 0.f;
  }
  float m[NACC], den[NACC], acc[NACC];
  #pragma unroll
  for (int i = 0; i < NACC; ++i) { m[i] = -INFINITY; den[i] = 0.f; acc[i] = 0.f; }
  for (int e = rp; e < re; ++e) {
    int src = srcs[e];
    const float* srow = sdv + (nb + src) * 12;
    #pragma unroll
    for (int i = 0; i < NACC; ++i)
      if (act[i]) m[i] = fmaxf(m[i], lrelu(srow[hh[i]] + dh[i]));
  }
  for (int e = rp; e < re; ++e) {
    int src = srcs[e];
    float w = ews[e];
    const float* srow = sdv + (nb + src) * 12;
    const float* hrow = h + (nb + src) * FIN;
    #pragma unroll
    for (int i = 0; i < NACC; ++i) {
      if (act[i]) {
        float ex = expf(lrelu(srow[hh[i]] + dh[i]) - m[i]);
        den[i] += ex;
        acc[i] += ex * w * hrow[ff[i]];
      }
    }
  }
  float* arow = agg + (nb + n) * K;
  #pragma unroll
  for (int i = 0; i < NACC; ++i)
    if (act[i]) arow[t + i * THREADS] = acc[i] / (den[i] + 1e-16f);
}

// ---------- f32 tiled GEMM: C[M,Nc] = A[M,K] * B[K,Nc] + bias (+ELU) ----------
__global__ __launch_bounds__(256)
void gemm_kernel(const float* __restrict__ A, const float* __restrict__ B,
                 const float* __restrict__ bias, float* __restrict__ C,
                 int M, int K, int Nc, int act) {
  __shared__ float As[16][64];
  __shared__ float Bs[16][64];
  int tid = threadIdx.x;
  int tx = tid & 15, ty = tid >> 4;
  int m0 = blockIdx.x * 64, n0 = blockIdx.y * 64;
  int lam = tid >> 2;           // 0..63 (A tile row)
  int lak = (tid & 3) << 2;     // 0,4,8,12 (A tile k)
  int lbr = tid >> 4;           // 0..15 (B tile k)
  int lbc = (tid & 15) << 2;    // 0..60 (B tile col)
  float acc[4][4] = {{0.f}};
  for (int k0 = 0; k0 < K; k0 += 16) {
    float4 av = make_float4(0.f, 0.f, 0.f, 0.f);
    if (k0 + lak < K) av = *(const float4*)(A + (size_t)(m0 + lam) * K + k0 + lak);
    As[lak + 0][lam] = av.x; As[lak + 1][lam] = av.y;
    As[lak + 2][lam] = av.z; As[lak + 3][lam] = av.w;
    float4 bv = make_float4(0.f, 0.f, 0.f, 0.f);
    if (k0 + lbr < K) bv = *(const float4*)(B + (size_t)(k0 + lbr) * Nc + n0 + lbc);
    *(float4*)(&Bs[lbr][lbc]) = bv;
    __syncthreads();
    #pragma unroll
    for (int k = 0; k < 16; ++k) {
      float4 a = *(const float4*)(&As[k][ty << 2]);
      float4 b = *(const float4*)(&Bs[k][tx << 2]);
      acc[0][0] += a.x*b.x; acc[0][1] += a.x*b.y; acc[0][2] += a.x*b.z; acc[0][3] += a.x*b.w;
      acc[1][0] += a.y*b.x; acc[1][1] += a.y*b.y; acc[1][2] += a.y*b.z; acc[1][3] += a.y*b.w;
      acc[2][0] += a.z*b.x; acc[2][1] += a.z*b.y; acc[2][2] += a.z*b.z; acc[2][3] += a.z*b.w;
      acc[3][0] += a.w*b.x; acc[3][1] += a.w*b.y; acc[3][2] += a.w*b.z; acc[3][3] += a.w*b.w;
    }
    __syncthreads();
  }
  #pragma unroll
  for (int i = 0; i < 4; ++i) {
    int row = m0 + (ty << 2) + i;
    #pragma unroll
    for (int j = 0; j < 4; ++j) {
      int col = n0 + (tx << 2) + j;
      float v = acc[i][j] + bias[col];
      if (act) v = eluf(v);
      C[(size_t)row * Nc + col] = v;
    }
  }
}

// ---------- weighted readout: seq[t, s*64+d] = sum_n xn[t,n]*h4[n,d] ----------
__global__ __launch_bounds__(256)
void readout_kernel(const float* __restrict__ h4, const float* __restrict__ xn1,
                    const float* __restrict__ xn2, float* __restrict__ seq, int c0) {
  int gl = blockIdx.x;
  int gi = c0 + gl;
  int t = gi >> 1, s = gi & 1;
  const float* xn = (s ? xn2 : xn1) + (size_t)t * NN;
  int tid = threadIdx.x;
  int d = tid & 63, stripe = tid >> 6;   // 4 stripes
  float acc = 0.f;
  for (int n = stripe; n < NN; n += 4)
    acc += xn[n] * h4[((size_t)gl * NN + n) * 64 + d];
  __shared__ float sh[256];
  sh[tid] = acc;
  __syncthreads();
  if (tid < 64)
    seq[t * 128 + s * 64 + tid] = sh[tid] + sh[tid + 64] + sh[tid + 128] + sh[tid + 192];
}

// ---------- sequential GRU + MLP head (single block) ----------
__global__ __launch_bounds__(128)
void gru_head_kernel(const float* __restrict__ seq, const float* __restrict__ Wih,
                     const float* __restrict__ Whh, const float* __restrict__ bih,
                     const float* __restrict__ bhh, const float* __restrict__ Wc1,
                     const float* __restrict__ bc1, const float* __restrict__ Wc2,
                     const float* __restrict__ bc2, float* __restrict__ rnn,
                     float* __restrict__ out) {
  __shared__ float WihT[128 * 96];   // [k][j]
  __shared__ float WhhT[32 * 96];    // [k][j]
  __shared__ float xs[128];
  __shared__ float gis[96], ghs[96];
  __shared__ float hs[32];
  int tid = threadIdx.x;
  for (int idx = tid; idx < 96 * 128; idx += 128) { int j = idx >> 7, k = idx & 127; WihT[k * 96 + j] = Wih[idx]; }
  for (int idx = tid; idx < 96 * 32;  idx += 128) { int j = idx >> 5, k = idx & 31;  WhhT[k * 96 + j] = Whh[idx]; }
  if (tid < 32) hs[tid] = 0.f;
  __syncthreads();
  for (int t = 0; t < TS; ++t) {
    xs[tid] = seq[t * 128 + tid];
    __syncthreads();
    if (tid < 96) {
      float a = bih[tid];
      #pragma unroll 4
      for (int k = 0; k < 128; ++k) a += WihT[k * 96 + tid] * xs[k];
      float b = bhh[tid];
      #pragma unroll 4
      for (int k = 0; k < 32; ++k) b += WhhT[k * 96 + tid] * hs[k];
      gis[tid] = a; ghs[tid] = b;
    }
    __syncthreads();
    if (tid < 32) {
      float r = sigm(gis[tid] + ghs[tid]);
      float z = sigm(gis[32 + tid] + ghs[32 + tid]);
      float nv = tanhf(gis[64 + tid] + r * ghs[64 + tid]);
      float h2 = (1.f - z) * nv + z * hs[tid];
      hs[tid] = h2;
      rnn[t * 32 + tid] = h2;
    }
    __syncthreads();
  }
  for (int o = tid; o < TS * 3; o += 128) {
    int t = o / 3, c = o - t * 3;
    float accv = bc2[c];
    for (int m = 0; m < 16; ++m) {
      float hv = bc1[m];
      for (int k = 0; k < 32; ++k) hv += rnn[t * 32 + k] * Wc1[k * 16 + m];
      hv = fmaxf(hv, 0.f);
      accv += hv * Wc2[m * 3 + c];
    }
    out[o] = accv;
  }
}

static inline size_t alignup(size_t x) { return (x + 255) & ~(size_t)255; }

extern "C" void kernel_launch(void* const* d_in, const int* in_sizes, int n_in,
                              void* d_out, int out_size, void* d_ws, size_t ws_size,
                              hipStream_t stream) {
  const float* x1  = (const float*)d_in[0];
  const float* x2  = (const float*)d_in[1];
  const int*   ei1 = (const int*)d_in[2];
  const int*   ei2 = (const int*)d_in[3];
  const float* ew1 = (const float*)d_in[4];
  const float* ew2 = (const float*)d_in[5];
  const float* xn1 = (const float*)d_in[6];
  const float* xn2 = (const float*)d_in[7];
  // d_in[8] = window_size (unused)
  const float* Wih = (const float*)d_in[25];
  const float* Whh = (const float*)d_in[26];
  const float* bih = (const float*)d_in[27];
  const float* bhh = (const float*)d_in[28];
  const float* Wc1 = (const float*)d_in[29];
  const float* bc1 = (const float*)d_in[30];
  const float* Wc2 = (const float*)d_in[31];
  const float* bc2 = (const float*)d_in[32];
  float* out = (float*)d_out;

  const int FINs[4]  = {4, 128, 128, 64};
  const int FOUTs[4] = {128, 128, 64, 64};
  const int Ks[4]    = {24, 768, 768, 384};
  const size_t uoffs[4] = {0, 24, 792, 1560};          // cum of H*FIN
  const size_t woffs[4] = {0, 3072, 101376, 150528};   // cum of K*FOUT

  // ---- workspace carve ----
  size_t off = 0;
  auto take = [&](size_t bytes) -> size_t { size_t o = off; off += alignup(bytes); return o; };
  size_t o_rowptr = take((size_t)NB * (NN + 1) * sizeof(int));
  size_t o_cursor = take((size_t)NB * NN * sizeof(int));
  size_t o_src    = take((size_t)NB * NE * sizeof(int));
  size_t o_ewsrt  = take((size_t)NB * NE * sizeof(float));
  size_t o_uS     = take(1944 * sizeof(float));
  size_t o_uD     = take(1944 * sizeof(float));
  size_t o_wcat   = take(175104 * sizeof(float));
  size_t o_seq    = take((size_t)TS * 128 * sizeof(float));
  size_t o_rnn    = take((size_t)TS * 32 * sizeof(float));
  size_t persistent = off;

  int G = 1;
  const int cand[8] = {128, 64, 32, 16, 8, 4, 2, 1};
  for (int ci = 0; ci < 8; ++ci) {
    int g = cand[ci];
    size_t need = persistent
                + 2 * alignup((size_t)g * NN * 128 * sizeof(float))
                + alignup((size_t)g * NN * 12 * sizeof(float))
                + alignup((size_t)g * NN * 768 * sizeof(float));
    if (need <= ws_size) { G = g; break; }
  }
  size_t o_hping = take((size_t)G * NN * 128 * sizeof(float));
  size_t o_hpong = take((size_t)G * NN * 128 * sizeof(float));
  size_t o_sd    = take((size_t)G * NN * 12 * sizeof(float));
  size_t o_agg   = take((size_t)G * NN * 768 * sizeof(float));

  char* ws = (char*)d_ws;
  int*   row_ptr    = (int*)(ws + o_rowptr);
  int*   cursor     = (int*)(ws + o_cursor);
  int*   src_sorted = (int*)(ws + o_src);
  float* ew_sorted  = (float*)(ws + o_ewsrt);
  float* uS    = (float*)(ws + o_uS);
  float* uD    = (float*)(ws + o_uD);
  float* wcat  = (float*)(ws + o_wcat);
  float* seq   = (float*)(ws + o_seq);
  float* rnn   = (float*)(ws + o_rnn);
  float* h_ping = (float*)(ws + o_hping);
  float* h_pong = (float*)(ws + o_hpong);
  float* sdbuf  = (float*)(ws + o_sd);
  float* aggbuf = (float*)(ws + o_agg);

  // ---- per-layer weight prep ----
  for (int l = 0; l < 4; ++l) {
    const float* Wl  = (const float*)d_in[9 + 4 * l];
    const float* aSl = (const float*)d_in[10 + 4 * l];
    const float* aDl = (const float*)d_in[11 + 4 * l];
    int totw = NH * FINs[l] * FOUTs[l];
    prep_layer_kernel<<<(totw + 255) / 256, 256, 0, stream>>>(
        Wl, aSl, aDl, uS + uoffs[l], uD + uoffs[l], wcat + woffs[l], FINs[l], FOUTs[l]);
  }

  // ---- CSR build (all 128 graph instances) ----
  hipMemsetAsync(cursor, 0, (size_t)NB * NN * sizeof(int), stream);
  hist_kernel<<<(NB * NE) / 256, 256, 0, stream>>>(ei1, ei2, cursor);
  scan_kernel<<<NB, 256, 0, stream>>>(cursor, row_ptr);
  scatter_kernel<<<(NB * NE) / 256, 256, 0, stream>>>(ei1, ei2, ew1, ew2, cursor,
                                                      src_sorted, ew_sorted);

  // ---- chunked GAT pipeline ----
  for (int c0 = 0; c0 < NB; c0 += G) {
    copyx_kernel<<<(G * NN * 4 + 255) / 256, 256, 0, stream>>>(x1, x2, h_ping, c0, G);
    float* hin = h_ping;
    float* hout = h_pong;
    int rows = G * NN;
    for (int l = 0; l < 4; ++l) {
      int FIN = FINs[l], FOUT = FOUTs[l], K = Ks[l];
      sd_kernel<<<((size_t)rows * 12 + 255) / 256, 256, 0, stream>>>(
          hin, uS + uoffs[l], uD + uoffs[l], sdbuf, FIN, rows);
      if (l == 0)
        agg_kernel<4, 64, 1><<<rows, 64, 0, stream>>>(hin, sdbuf, row_ptr, src_sorted,
                                                      ew_sorted, aggbuf, c0);
      else if (l == 3)
        agg_kernel<64, 128, 3><<<rows, 128, 0, stream>>>(hin, sdbuf, row_ptr, src_sorted,
                                                         ew_sorted, aggbuf, c0);
      else
        agg_kernel<128, 256, 3><<<rows, 256, 0, stream>>>(hin, sdbuf, row_ptr, src_sorted,
                                                          ew_sorted, aggbuf, c0);
      dim3 gg(rows / 64, FOUT / 64);
      gemm_kernel<<<gg, 256, 0, stream>>>(aggbuf, wcat + woffs[l],
                                          (const float*)d_in[12 + 4 * l], hout,
                                          rows, K, FOUT, l < 3 ? 1 : 0);
      float* tmp = hin; hin = hout; hout = tmp;
    }
    readout_kernel<<<G, 256, 0, stream>>>(hin, xn1, xn2, seq, c0);
  }

  // ---- GRU + head ----
  gru_head_kernel<<<1, 128, 0, stream>>>(seq, Wih, Whh, bih, bhh, Wc1, bc1, Wc2, bc2,
                                         rnn, out);
}

// Round 2
// 6898.188 us; speedup vs baseline: 1.8335x; 1.8335x over previous
//
#include <hip/hip_runtime.h>
#include <math.h>

#define TS 64
#define NN 2048
#define NE 32768
#define NH 6
#define NB 128   // 2*TS graph instances

typedef __attribute__((ext_vector_type(8))) __bf16 bf16x8;
typedef __attribute__((ext_vector_type(4))) float f32x4;

__device__ __forceinline__ float lrelu(float x){ return x >= 0.0f ? x : 0.2f*x; }
__device__ __forceinline__ float eluf(float x){ return x > 0.0f ? x : expm1f(x); }
__device__ __forceinline__ float sigm(float x){ return 1.0f/(1.0f+expf(-x)); }
__device__ __forceinline__ unsigned short bfhi(float x){ return (unsigned short)(__float_as_uint(x) >> 16); }
__device__ __forceinline__ float bff(unsigned short u){ return __uint_as_float(((unsigned int)u) << 16); }

// ---------- per-layer prep: uS,uD [H*FIN]; B split+transposed bf16 hi/lo [N][K] ----------
__global__ void prep_layer_kernel(const float* __restrict__ W,
                                  const float* __restrict__ aS,
                                  const float* __restrict__ aD,
                                  float* __restrict__ uS, float* __restrict__ uD,
                                  unsigned short* __restrict__ bth,
                                  unsigned short* __restrict__ btl,
                                  int FIN, int FOUT) {
  int idx = blockIdx.x * blockDim.x + threadIdx.x;
  int K = NH * FIN;
  if (idx < K * FOUT) {
    int k = idx / FOUT, o = idx - k * FOUT;
    int h = k / FIN, f = k - h * FIN;
    float v = W[(size_t)(f * NH + h) * FOUT + o] * (1.0f / NH);
    unsigned short hb = bfhi(v);
    unsigned short lb = bfhi(v - bff(hb));
    bth[(size_t)o * K + k] = hb;
    btl[(size_t)o * K + k] = lb;
  }
  if (idx < NH * FIN) {
    int h = idx / FIN, f = idx - h * FIN;
    const float* wr = W + (size_t)(f * NH + h) * FOUT;
    const float* as = aS + h * FOUT;
    const float* ad = aD + h * FOUT;
    float ss = 0.f, dd = 0.f;
    for (int o = 0; o < FOUT; ++o) { float w = wr[o]; ss += w * as[o]; dd += w * ad[o]; }
    uS[idx] = ss; uD[idx] = dd;
  }
}

// ---------- CSR build ----------
__global__ void hist_kernel(const int* __restrict__ ei1, const int* __restrict__ ei2,
                            int* __restrict__ deg) {
  int gid = blockIdx.x * blockDim.x + threadIdx.x;
  if (gid >= NB * NE) return;
  int gi = gid / NE, e = gid - gi * NE;
  int t = gi >> 1, s = gi & 1;
  const int* ei = s ? ei2 : ei1;
  int dst = ei[(size_t)(t * 2 + 1) * NE + e];
  atomicAdd(&deg[gi * NN + dst], 1);
}

__global__ void scan_kernel(int* __restrict__ degcur, int* __restrict__ row_ptr) {
  int g = blockIdx.x, t = threadIdx.x;           // 128 blocks x 256 threads
  const int PER = NN / 256;                       // 8
  int base = g * NN;
  int loc[PER]; int run = 0;
  for (int i = 0; i < PER; ++i) { loc[i] = run; run += degcur[base + t*PER + i]; }
  __shared__ int part[256];
  __shared__ int offs[256];
  part[t] = run;
  __syncthreads();
  if (t == 0) { int acc = 0; for (int i = 0; i < 256; ++i) { offs[i] = acc; acc += part[i]; } }
  __syncthreads();
  int o = offs[t];
  for (int i = 0; i < PER; ++i) {
    int v = o + loc[i];
    row_ptr[g * (NN + 1) + t*PER + i] = v;
    degcur[base + t*PER + i] = v;                 // becomes scatter cursor
  }
  if (t == 255) row_ptr[g * (NN + 1) + NN] = o + run;
}

__global__ void scatter_kernel(const int* __restrict__ ei1, const int* __restrict__ ei2,
                               const float* __restrict__ ew1, const float* __restrict__ ew2,
                               int* __restrict__ cursor, int* __restrict__ src_sorted,
                               float* __restrict__ ew_sorted) {
  int gid = blockIdx.x * blockDim.x + threadIdx.x;
  if (gid >= NB * NE) return;
  int gi = gid / NE, e = gid - gi * NE;
  int t = gi >> 1, s = gi & 1;
  const int* ei = s ? ei2 : ei1;
  const float* ew = s ? ew2 : ew1;
  int src = ei[(size_t)(t * 2) * NE + e];
  int dst = ei[(size_t)(t * 2 + 1) * NE + e];
  float w = ew[(size_t)t * NE + e];
  int pos = atomicAdd(&cursor[gi * NN + dst], 1);
  src_sorted[(size_t)gi * NE + pos] = src;
  ew_sorted[(size_t)gi * NE + pos] = w;
}

// ---------- stage x into h_ping (stride 4) ----------
__global__ void copyx_kernel(const float* __restrict__ x1, const float* __restrict__ x2,
                             float* __restrict__ hping, int c0, int G) {
  int gid = blockIdx.x * blockDim.x + threadIdx.x;
  int tot = G * NN * 4;
  if (gid >= tot) return;
  int gl = gid / (NN * 4);
  int rem = gid - gl * (NN * 4);
  int gi = c0 + gl;
  int t = gi >> 1, s = gi & 1;
  const float* x = s ? x2 : x1;
  hping[(size_t)gl * NN * 4 + rem] = x[(size_t)t * NN * 4 + rem];
}

// ---------- s/d logits: sdv[row*12 + j] ; j<6 = s(h), j>=6 = d(h) ----------
__global__ void sd_kernel(const float* __restrict__ h, const float* __restrict__ uS,
                          const float* __restrict__ uD, float* __restrict__ sdv,
                          int FIN, int rows) {
  int gid = blockIdx.x * blockDim.x + threadIdx.x;
  if (gid >= rows * 12) return;
  int n = gid / 12, j = gid - n * 12;
  const float* u = (j < 6 ? uS + j * FIN : uD + (j - 6) * FIN);
  const float* hr = h + (size_t)n * FIN;
  float a = 0.f;
  for (int f = 0; f < FIN; f += 4) {
    float4 hv = *(const float4*)(hr + f);
    float4 uv = *(const float4*)(u + f);
    a += hv.x*uv.x + hv.y*uv.y + hv.z*uv.z + hv.w*uv.w;
  }
  sdv[gid] = a;
}

// ---------- per-(edge,head) softmax weight: aw[e][h] = alpha*ew ----------
__global__ __launch_bounds__(256)
void alpha_kernel(const float* __restrict__ sdv, const int* __restrict__ row_ptr,
                  const int* __restrict__ src_sorted, const float* __restrict__ ew_sorted,
                  float* __restrict__ aw, int c0) {
  int t = threadIdx.x;
  int j = t & 7;
  int nodeg = blockIdx.x * 32 + (t >> 3);
  if (j >= 6) return;
  int gl = nodeg >> 11, n = nodeg & (NN - 1);
  int gi = c0 + gl;
  int rp = row_ptr[gi * (NN + 1) + n];
  int re = row_ptr[gi * (NN + 1) + n + 1];
  if (rp == re) return;
  const int*   srcs = src_sorted + (size_t)gi * NE;
  const float* ews  = ew_sorted  + (size_t)gi * NE;
  const float* sdb  = sdv + (size_t)gl * NN * 12;
  float d = sdb[n * 12 + 6 + j];
  float m = -INFINITY;
  for (int e = rp; e < re; ++e)
    m = fmaxf(m, lrelu(sdb[srcs[e] * 12 + j] + d));
  float den = 0.f;
  for (int e = rp; e < re; ++e)
    den += expf(lrelu(sdb[srcs[e] * 12 + j] + d) - m);
  float inv = 1.f / (den + 1e-16f);
  float* awg = aw + (size_t)gl * NE * 6;
  for (int e = rp; e < re; ++e)
    awg[(size_t)e * 6 + j] = expf(lrelu(sdb[srcs[e] * 12 + j] + d) - m) * inv * ews[e];
}

// ---------- aggregation: agg[n][h*FIN+f] = sum_e aw[e][h]*h[src][f] ----------
template<int FIN>
__global__ __launch_bounds__(256)
void agg2_kernel(const float* __restrict__ h, const float* __restrict__ aw,
                 const int* __restrict__ row_ptr, const int* __restrict__ src_sorted,
                 float* __restrict__ agg, int c0) {
  const int NPB = 256 / FIN;
  int t = threadIdx.x;
  int f  = t & (FIN - 1);
  int nl = t / FIN;
  int nodeg = blockIdx.x * NPB + nl;
  int gl = nodeg >> 11, n = nodeg & (NN - 1);
  int gi = c0 + gl;
  int rp = row_ptr[gi * (NN + 1) + n];
  int re = row_ptr[gi * (NN + 1) + n + 1];
  const int*   srcs = src_sorted + (size_t)gi * NE;
  const float* awg  = aw + (size_t)gl * NE * 6;
  const float* hb   = h + (size_t)gl * NN * FIN;
  float a0=0.f,a1=0.f,a2=0.f,a3=0.f,a4=0.f,a5=0.f;
  for (int e = rp; e < re; ++e) {
    int s = srcs[e];
    float hv = hb[(size_t)s * FIN + f];
    const float* w6 = awg + (size_t)e * 6;
    float2 w01 = *(const float2*)(w6);
    float2 w23 = *(const float2*)(w6 + 2);
    float2 w45 = *(const float2*)(w6 + 4);
    a0 += w01.x * hv; a1 += w01.y * hv;
    a2 += w23.x * hv; a3 += w23.y * hv;
    a4 += w45.x * hv; a5 += w45.y * hv;
  }
  float* ar = agg + (size_t)nodeg * (6 * FIN) + f;
  ar[0]       = a0; ar[FIN]     = a1; ar[2 * FIN] = a2;
  ar[3 * FIN] = a3; ar[4 * FIN] = a4; ar[5 * FIN] = a5;
}

// ---------- MFMA GEMM, f32-accurate via bf16 hi/lo 3-term split ----------
// C[M,BN] = A[M,K](f32) * Bt[BN,K](pre-split bf16) + bias (+ELU)
template<int MF, int NF, int WMC, int WCC>
__global__ __launch_bounds__(256)
void gemm_mfma_kernel(const float* __restrict__ A,
                      const unsigned short* __restrict__ Bth,
                      const unsigned short* __restrict__ Btl,
                      const float* __restrict__ bias, float* __restrict__ C,
                      int K, int act) {
  const int BN = WCC * NF * 16;
  __shared__ unsigned short AhL[128 * 32], AlL[128 * 32];
  __shared__ unsigned short BhL[BN * 32],  BlL[BN * 32];
  int t = threadIdx.x;
  int lane = t & 63, wv = t >> 6;
  int wm = wv % WMC, wc = wv / WMC;
  int l15 = lane & 15, lq = lane >> 4;
  int m0 = blockIdx.x * 128;
  f32x4 acc[MF][NF];
  #pragma unroll
  for (int i = 0; i < MF; ++i)
    #pragma unroll
    for (int j = 0; j < NF; ++j) { f32x4 z = {0.f,0.f,0.f,0.f}; acc[i][j] = z; }

  for (int k0 = 0; k0 < K; k0 += 32) {
    __syncthreads();
    // stage A tile 128x32 f32 -> bf16 hi/lo, swizzled
    #pragma unroll
    for (int i = 0; i < 4; ++i) {
      int q = t + i * 256;
      int row = q >> 3, c4 = q & 7;
      float4 av = make_float4(0.f, 0.f, 0.f, 0.f);
      int k = k0 + c4 * 4;
      if (k < K) av = *(const float4*)(A + (size_t)(m0 + row) * K + k);
      unsigned short h0 = bfhi(av.x), h1 = bfhi(av.y), h2 = bfhi(av.z), h3 = bfhi(av.w);
      unsigned short g0 = bfhi(av.x - bff(h0)), g1 = bfhi(av.y - bff(h1));
      unsigned short g2 = bfhi(av.z - bff(h2)), g3 = bfhi(av.w - bff(h3));
      int pos = row * 32 + (((c4 >> 1) ^ ((row >> 1) & 3)) << 3) + ((c4 & 1) << 2);
      *(ushort4*)&AhL[pos] = make_ushort4(h0, h1, h2, h3);
      *(ushort4*)&AlL[pos] = make_ushort4(g0, g1, g2, g3);
    }
    // stage B tile BNx32 bf16 hi/lo (already transposed+split in global)
    #pragma unroll
    for (int i = 0; i < BN / 64; ++i) {
      int q = t + i * 256;
      int n = q >> 2, c = q & 3;
      uint4 vh = make_uint4(0, 0, 0, 0), vl = make_uint4(0, 0, 0, 0);
      int k = k0 + c * 8;
      if (k < K) {
        vh = *(const uint4*)(Bth + (size_t)n * K + k);
        vl = *(const uint4*)(Btl + (size_t)n * K + k);
      }
      int pos = n * 32 + ((c ^ ((n >> 1) & 3)) << 3);
      *(uint4*)&BhL[pos] = vh;
      *(uint4*)&BlL[pos] = vl;
    }
    __syncthreads();
    bf16x8 ah[MF], al[MF], bh[NF], bl[NF];
    #pragma unroll
    for (int fr = 0; fr < MF; ++fr) {
      int row = wm * MF * 16 + fr * 16 + l15;
      int p = row * 32 + ((lq ^ ((row >> 1) & 3)) << 3);
      ah[fr] = *(const bf16x8*)&AhL[p];
      al[fr] = *(const bf16x8*)&AlL[p];
    }
    #pragma unroll
    for (int fc = 0; fc < NF; ++fc) {
      int row = wc * NF * 16 + fc * 16 + l15;
      int p = row * 32 + ((lq ^ ((row >> 1) & 3)) << 3);
      bh[fc] = *(const bf16x8*)&BhL[p];
      bl[fc] = *(const bf16x8*)&BlL[p];
    }
    #pragma unroll
    for (int fr = 0; fr < MF; ++fr)
      #pragma unroll
      for (int fc = 0; fc < NF; ++fc) {
        acc[fr][fc] = __builtin_amdgcn_mfma_f32_16x16x32_bf16(ah[fr], bh[fc], acc[fr][fc], 0, 0, 0);
        acc[fr][fc] = __builtin_amdgcn_mfma_f32_16x16x32_bf16(ah[fr], bl[fc], acc[fr][fc], 0, 0, 0);
        acc[fr][fc] = __builtin_amdgcn_mfma_f32_16x16x32_bf16(al[fr], bh[fc], acc[fr][fc], 0, 0, 0);
      }
  }
  #pragma unroll
  for (int fr = 0; fr < MF; ++fr) {
    int row = m0 + wm * MF * 16 + fr * 16 + lq * 4;
    #pragma unroll
    for (int fc = 0; fc < NF; ++fc) {
      int col = wc * NF * 16 + fc * 16 + l15;
      float bv = bias[col];
      #pragma unroll
      for (int r = 0; r < 4; ++r) {
        float v = acc[fr][fc][r] + bv;
        if (act) v = eluf(v);
        C[(size_t)(row + r) * BN + col] = v;
      }
    }
  }
}

// ---------- weighted readout: seq[t, s*64+d] = sum_n xn[t,n]*h4[n,d] ----------
__global__ __launch_bounds__(256)
void readout_kernel(const float* __restrict__ h4, const float* __restrict__ xn1,
                    const float* __restrict__ xn2, float* __restrict__ seq, int c0) {
  int gl = blockIdx.x;
  int gi = c0 + gl;
  int t = gi >> 1, s = gi & 1;
  const float* xn = (s ? xn2 : xn1) + (size_t)t * NN;
  int tid = threadIdx.x;
  int d = tid & 63, stripe = tid >> 6;   // 4 stripes
  float acc = 0.f;
  for (int n = stripe; n < NN; n += 4)
    acc += xn[n] * h4[((size_t)gl * NN + n) * 64 + d];
  __shared__ float sh[256];
  sh[tid] = acc;
  __syncthreads();
  if (tid < 64)
    seq[t * 128 + s * 64 + tid] = sh[tid] + sh[tid + 64] + sh[tid + 128] + sh[tid + 192];
}

// ---------- sequential GRU + MLP head (single block) ----------
__global__ __launch_bounds__(128)
void gru_head_kernel(const float* __restrict__ seq, const float* __restrict__ Wih,
                     const float* __restrict__ Whh, const float* __restrict__ bih,
                     const float* __restrict__ bhh, const float* __restrict__ Wc1,
                     const float* __restrict__ bc1, const float* __restrict__ Wc2,
                     const float* __restrict__ bc2, float* __restrict__ rnn,
                     float* __restrict__ out) {
  __shared__ float WihT[128 * 96];   // [k][j]
  __shared__ float WhhT[32 * 96];    // [k][j]
  __shared__ float xs[128];
  __shared__ float gis[96], ghs[96];
  __shared__ float hs[32];
  int tid = threadIdx.x;
  for (int idx = tid; idx < 96 * 128; idx += 128) { int j = idx >> 7, k = idx & 127; WihT[k * 96 + j] = Wih[idx]; }
  for (int idx = tid; idx < 96 * 32;  idx += 128) { int j = idx >> 5, k = idx & 31;  WhhT[k * 96 + j] = Whh[idx]; }
  if (tid < 32) hs[tid] = 0.f;
  __syncthreads();
  for (int t = 0; t < TS; ++t) {
    xs[tid] = seq[t * 128 + tid];
    __syncthreads();
    if (tid < 96) {
      float a = bih[tid];
      #pragma unroll 4
      for (int k = 0; k < 128; ++k) a += WihT[k * 96 + tid] * xs[k];
      float b = bhh[tid];
      #pragma unroll 4
      for (int k = 0; k < 32; ++k) b += WhhT[k * 96 + tid] * hs[k];
      gis[tid] = a; ghs[tid] = b;
    }
    __syncthreads();
    if (tid < 32) {
      float r = sigm(gis[tid] + ghs[tid]);
      float z = sigm(gis[32 + tid] + ghs[32 + tid]);
      float nv = tanhf(gis[64 + tid] + r * ghs[64 + tid]);
      float h2 = (1.f - z) * nv + z * hs[tid];
      hs[tid] = h2;
      rnn[t * 32 + tid] = h2;
    }
    __syncthreads();
  }
  for (int o = tid; o < TS * 3; o += 128) {
    int t = o / 3, c = o - t * 3;
    float accv = bc2[c];
    for (int m = 0; m < 16; ++m) {
      float hv = bc1[m];
      for (int k = 0; k < 32; ++k) hv += rnn[t * 32 + k] * Wc1[k * 16 + m];
      hv = fmaxf(hv, 0.f);
      accv += hv * Wc2[m * 3 + c];
    }
    out[o] = accv;
  }
}

static inline size_t alignup(size_t x) { return (x + 255) & ~(size_t)255; }

extern "C" void kernel_launch(void* const* d_in, const int* in_sizes, int n_in,
                              void* d_out, int out_size, void* d_ws, size_t ws_size,
                              hipStream_t stream) {
  const float* x1  = (const float*)d_in[0];
  const float* x2  = (const float*)d_in[1];
  const int*   ei1 = (const int*)d_in[2];
  const int*   ei2 = (const int*)d_in[3];
  const float* ew1 = (const float*)d_in[4];
  const float* ew2 = (const float*)d_in[5];
  const float* xn1 = (const float*)d_in[6];
  const float* xn2 = (const float*)d_in[7];
  const float* Wih = (const float*)d_in[25];
  const float* Whh = (const float*)d_in[26];
  const float* bih = (const float*)d_in[27];
  const float* bhh = (const float*)d_in[28];
  const float* Wc1 = (const float*)d_in[29];
  const float* bc1 = (const float*)d_in[30];
  const float* Wc2 = (const float*)d_in[31];
  const float* bc2 = (const float*)d_in[32];
  float* out = (float*)d_out;

  const int FINs[4]  = {4, 128, 128, 64};
  const int FOUTs[4] = {128, 128, 64, 64};
  const size_t uoffs[4] = {0, 24, 792, 1560};          // cum of H*FIN
  const size_t woffs[4] = {0, 3072, 101376, 150528};   // cum of K*FOUT (175104 total)

  // ---- workspace carve ----
  size_t off = 0;
  auto take = [&](size_t bytes) -> size_t { size_t o = off; off += alignup(bytes); return o; };
  size_t o_rowptr = take((size_t)NB * (NN + 1) * sizeof(int));
  size_t o_cursor = take((size_t)NB * NN * sizeof(int));
  size_t o_src    = take((size_t)NB * NE * sizeof(int));
  size_t o_ewsrt  = take((size_t)NB * NE * sizeof(float));
  size_t o_uS     = take(1944 * sizeof(float));
  size_t o_uD     = take(1944 * sizeof(float));
  size_t o_bth    = take(175104 * sizeof(unsigned short));
  size_t o_btl    = take(175104 * sizeof(unsigned short));
  size_t o_seq    = take((size_t)TS * 128 * sizeof(float));
  size_t o_rnn    = take((size_t)TS * 32 * sizeof(float));
  size_t persistent = off;

  int G = 1;
  const int cand[8] = {128, 64, 32, 16, 8, 4, 2, 1};
  for (int ci = 0; ci < 8; ++ci) {
    int g = cand[ci];
    size_t need = persistent
                + 2 * alignup((size_t)g * NN * 128 * sizeof(float))
                + alignup((size_t)g * NN * 12 * sizeof(float))
                + alignup((size_t)g * NN * 768 * sizeof(float))
                + alignup((size_t)g * NE * 6 * sizeof(float));
    if (need <= ws_size) { G = g; break; }
  }
  size_t o_hping = take((size_t)G * NN * 128 * sizeof(float));
  size_t o_hpong = take((size_t)G * NN * 128 * sizeof(float));
  size_t o_sd    = take((size_t)G * NN * 12 * sizeof(float));
  size_t o_agg   = take((size_t)G * NN * 768 * sizeof(float));
  size_t o_aw    = take((size_t)G * NE * 6 * sizeof(float));

  char* ws = (char*)d_ws;
  int*   row_ptr    = (int*)(ws + o_rowptr);
  int*   cursor     = (int*)(ws + o_cursor);
  int*   src_sorted = (int*)(ws + o_src);
  float* ew_sorted  = (float*)(ws + o_ewsrt);
  float* uS   = (float*)(ws + o_uS);
  float* uD   = (float*)(ws + o_uD);
  unsigned short* bth = (unsigned short*)(ws + o_bth);
  unsigned short* btl = (unsigned short*)(ws + o_btl);
  float* seq  = (float*)(ws + o_seq);
  float* rnn  = (float*)(ws + o_rnn);
  float* h_ping = (float*)(ws + o_hping);
  float* h_pong = (float*)(ws + o_hpong);
  float* sdbuf  = (float*)(ws + o_sd);
  float* aggbuf = (float*)(ws + o_agg);
  float* awbuf  = (float*)(ws + o_aw);

  // ---- per-layer weight prep ----
  for (int l = 0; l < 4; ++l) {
    const float* Wl  = (const float*)d_in[9 + 4 * l];
    const float* aSl = (const float*)d_in[10 + 4 * l];
    const float* aDl = (const float*)d_in[11 + 4 * l];
    int totw = NH * FINs[l] * FOUTs[l];
    prep_layer_kernel<<<(totw + 255) / 256, 256, 0, stream>>>(
        Wl, aSl, aDl, uS + uoffs[l], uD + uoffs[l],
        bth + woffs[l], btl + woffs[l], FINs[l], FOUTs[l]);
  }

  // ---- CSR build (all 128 graph instances) ----
  hipMemsetAsync(cursor, 0, (size_t)NB * NN * sizeof(int), stream);
  hist_kernel<<<(NB * NE) / 256, 256, 0, stream>>>(ei1, ei2, cursor);
  scan_kernel<<<NB, 256, 0, stream>>>(cursor, row_ptr);
  scatter_kernel<<<(NB * NE) / 256, 256, 0, stream>>>(ei1, ei2, ew1, ew2, cursor,
                                                      src_sorted, ew_sorted);

  // ---- chunked GAT pipeline ----
  for (int c0 = 0; c0 < NB; c0 += G) {
    copyx_kernel<<<(G * NN * 4 + 255) / 256, 256, 0, stream>>>(x1, x2, h_ping, c0, G);
    float* hin = h_ping;
    float* hout = h_pong;
    int rows = G * NN;
    for (int l = 0; l < 4; ++l) {
      int FIN = FINs[l], K = NH * FIN;
      sd_kernel<<<((size_t)rows * 12 + 255) / 256, 256, 0, stream>>>(
          hin, uS + uoffs[l], uD + uoffs[l], sdbuf, FIN, rows);
      alpha_kernel<<<rows / 32, 256, 0, stream>>>(sdbuf, row_ptr, src_sorted,
                                                  ew_sorted, awbuf, c0);
      if (l == 0)
        agg2_kernel<4><<<rows / 64, 256, 0, stream>>>(hin, awbuf, row_ptr, src_sorted, aggbuf, c0);
      else if (l == 3)
        agg2_kernel<64><<<rows / 4, 256, 0, stream>>>(hin, awbuf, row_ptr, src_sorted, aggbuf, c0);
      else
        agg2_kernel<128><<<rows / 2, 256, 0, stream>>>(hin, awbuf, row_ptr, src_sorted, aggbuf, c0);
      const float* bias = (const float*)d_in[12 + 4 * l];
      int act = (l < 3) ? 1 : 0;
      if (FOUTs[l] == 128)
        gemm_mfma_kernel<4, 4, 2, 2><<<rows / 128, 256, 0, stream>>>(
            aggbuf, bth + woffs[l], btl + woffs[l], bias, hout, K, act);
      else
        gemm_mfma_kernel<2, 4, 4, 1><<<rows / 128, 256, 0, stream>>>(
            aggbuf, bth + woffs[l], btl + woffs[l], bias, hout, K, act);
      float* tmp = hin; hin = hout; hout = tmp;
    }
    readout_kernel<<<G, 256, 0, stream>>>(hin, xn1, xn2, seq, c0);
  }

  // ---- GRU + head ----
  gru_head_kernel<<<1, 128, 0, stream>>>(seq, Wih, Whh, bih, bhh, Wc1, bc1, Wc2, bc2,
                                         rnn, out);
}

// Round 3
// 5176.406 us; speedup vs baseline: 2.4434x; 1.3326x over previous
//
#include <hip/hip_runtime.h>
#include <math.h>

#define TS 64
#define NN 2048
#define NE 32768
#define NH 6
#define NB 128   // 2*TS graph instances

typedef __attribute__((ext_vector_type(8))) __bf16 bf16x8;
typedef __attribute__((ext_vector_type(4))) float f32x4;

__device__ __forceinline__ float lrelu(float x){ return x >= 0.0f ? x : 0.2f*x; }
__device__ __forceinline__ float eluf(float x){ return x > 0.0f ? x : expm1f(x); }
__device__ __forceinline__ float sigm(float x){ return 1.0f/(1.0f+expf(-x)); }
__device__ __forceinline__ unsigned short bfhi(float x){ return (unsigned short)(__float_as_uint(x) >> 16); }
__device__ __forceinline__ float bff(unsigned short u){ return __uint_as_float(((unsigned int)u) << 16); }

// ---------- per-layer prep: uS,uD [H*FIN]; B split+transposed bf16 hi/lo [N][K] ----------
__global__ void prep_layer_kernel(const float* __restrict__ W,
                                  const float* __restrict__ aS,
                                  const float* __restrict__ aD,
                                  float* __restrict__ uS, float* __restrict__ uD,
                                  unsigned short* __restrict__ bth,
                                  unsigned short* __restrict__ btl,
                                  int FIN, int FOUT) {
  int idx = blockIdx.x * blockDim.x + threadIdx.x;
  int K = NH * FIN;
  if (idx < K * FOUT) {
    int k = idx / FOUT, o = idx - k * FOUT;
    int h = k / FIN, f = k - h * FIN;
    float v = W[(size_t)(f * NH + h) * FOUT + o] * (1.0f / NH);
    unsigned short hb = bfhi(v);
    unsigned short lb = bfhi(v - bff(hb));
    bth[(size_t)o * K + k] = hb;
    btl[(size_t)o * K + k] = lb;
  }
  if (idx < NH * FIN) {
    int h = idx / FIN, f = idx - h * FIN;
    const float* wr = W + (size_t)(f * NH + h) * FOUT;
    const float* as = aS + h * FOUT;
    const float* ad = aD + h * FOUT;
    float ss = 0.f, dd = 0.f;
    for (int o = 0; o < FOUT; ++o) { float w = wr[o]; ss += w * as[o]; dd += w * ad[o]; }
    uS[idx] = ss; uD[idx] = dd;
  }
}

// ---------- CSR build ----------
__global__ void hist_kernel(const int* __restrict__ ei1, const int* __restrict__ ei2,
                            int* __restrict__ deg) {
  int gid = blockIdx.x * blockDim.x + threadIdx.x;
  if (gid >= NB * NE) return;
  int gi = gid / NE, e = gid - gi * NE;
  int t = gi >> 1, s = gi & 1;
  const int* ei = s ? ei2 : ei1;
  int dst = ei[(size_t)(t * 2 + 1) * NE + e];
  atomicAdd(&deg[gi * NN + dst], 1);
}

__global__ void scan_kernel(int* __restrict__ degcur, int* __restrict__ row_ptr) {
  int g = blockIdx.x, t = threadIdx.x;           // 128 blocks x 256 threads
  const int PER = NN / 256;                       // 8
  int base = g * NN;
  int loc[PER]; int run = 0;
  for (int i = 0; i < PER; ++i) { loc[i] = run; run += degcur[base + t*PER + i]; }
  __shared__ int part[256];
  __shared__ int offs[256];
  part[t] = run;
  __syncthreads();
  if (t == 0) { int acc = 0; for (int i = 0; i < 256; ++i) { offs[i] = acc; acc += part[i]; } }
  __syncthreads();
  int o = offs[t];
  for (int i = 0; i < PER; ++i) {
    int v = o + loc[i];
    row_ptr[g * (NN + 1) + t*PER + i] = v;
    degcur[base + t*PER + i] = v;                 // becomes scatter cursor
  }
  if (t == 255) row_ptr[g * (NN + 1) + NN] = o + run;
}

__global__ void scatter_kernel(const int* __restrict__ ei1, const int* __restrict__ ei2,
                               const float* __restrict__ ew1, const float* __restrict__ ew2,
                               int* __restrict__ cursor, int* __restrict__ src_sorted,
                               float* __restrict__ ew_sorted) {
  int gid = blockIdx.x * blockDim.x + threadIdx.x;
  if (gid >= NB * NE) return;
  int gi = gid / NE, e = gid - gi * NE;
  int t = gi >> 1, s = gi & 1;
  const int* ei = s ? ei2 : ei1;
  const float* ew = s ? ew2 : ew1;
  int src = ei[(size_t)(t * 2) * NE + e];
  int dst = ei[(size_t)(t * 2 + 1) * NE + e];
  float w = ew[(size_t)t * NE + e];
  int pos = atomicAdd(&cursor[gi * NN + dst], 1);
  src_sorted[(size_t)gi * NE + pos] = src;
  ew_sorted[(size_t)gi * NE + pos] = w;
}

// ---------- stage x into h_ping (stride 4) ----------
__global__ void copyx_kernel(const float* __restrict__ x1, const float* __restrict__ x2,
                             float* __restrict__ hping, int c0, int G) {
  int gid = blockIdx.x * blockDim.x + threadIdx.x;
  int tot = G * NN * 4;
  if (gid >= tot) return;
  int gl = gid / (NN * 4);
  int rem = gid - gl * (NN * 4);
  int gi = c0 + gl;
  int t = gi >> 1, s = gi & 1;
  const float* x = s ? x2 : x1;
  hping[(size_t)gl * NN * 4 + rem] = x[(size_t)t * NN * 4 + rem];
}

// ---------- s/d logits: sdv[row*12 + j] ; j<6 = s(h), j>=6 = d(h) ----------
__global__ void sd_kernel(const float* __restrict__ h, const float* __restrict__ uS,
                          const float* __restrict__ uD, float* __restrict__ sdv,
                          int FIN, int rows) {
  int gid = blockIdx.x * blockDim.x + threadIdx.x;
  if (gid >= rows * 12) return;
  int n = gid / 12, j = gid - n * 12;
  const float* u = (j < 6 ? uS + j * FIN : uD + (j - 6) * FIN);
  const float* hr = h + (size_t)n * FIN;
  float a = 0.f;
  for (int f = 0; f < FIN; f += 4) {
    float4 hv = *(const float4*)(hr + f);
    float4 uv = *(const float4*)(u + f);
    a += hv.x*uv.x + hv.y*uv.y + hv.z*uv.z + hv.w*uv.w;
  }
  sdv[gid] = a;
}

// ---------- per-(edge,head) softmax weight: aw[e][h] = alpha*ew ----------
// grid: (rows/32) blocks, 256 threads, 8 threads/node (6 active). XCD-swizzled.
__global__ __launch_bounds__(256)
void alpha_kernel(const float* __restrict__ sdv, const int* __restrict__ row_ptr,
                  const int* __restrict__ src_sorted, const float* __restrict__ ew_sorted,
                  float* __restrict__ aw, int c0, int sw) {
  int t = threadIdx.x;
  int j = t & 7;
  if (j >= 6) return;
  int blk = blockIdx.x;
  const int BPG = NN / 32;   // 64 blocks per graph
  int gl, nb;
  if (sw) { int xcd = blk & 7, q = blk >> 3; gl = xcd + ((q / BPG) << 3); nb = q % BPG; }
  else    { gl = blk / BPG; nb = blk % BPG; }
  int n = nb * 32 + (t >> 3);
  int gi = c0 + gl;
  int rp = row_ptr[gi * (NN + 1) + n];
  int re = row_ptr[gi * (NN + 1) + n + 1];
  if (rp == re) return;
  const int*   srcs = src_sorted + (size_t)gi * NE;
  const float* ews  = ew_sorted  + (size_t)gi * NE;
  const float* sdb  = sdv + (size_t)gl * NN * 12;
  float d = sdb[n * 12 + 6 + j];
  float m = -INFINITY;
  for (int e = rp; e < re; ++e)
    m = fmaxf(m, lrelu(sdb[srcs[e] * 12 + j] + d));
  float den = 0.f;
  for (int e = rp; e < re; ++e)
    den += expf(lrelu(sdb[srcs[e] * 12 + j] + d) - m);
  float inv = 1.f / (den + 1e-16f);
  float* awg = aw + (size_t)gl * NE * 6;
  for (int e = rp; e < re; ++e)
    awg[(size_t)e * 6 + j] = expf(lrelu(sdb[srcs[e] * 12 + j] + d) - m) * inv * ews[e];
}

// ---------- aggregation: agg[n][h*FIN+f] = sum_e aw[e][h]*h[src][f] ----------
template<int FIN>
__global__ __launch_bounds__(256)
void agg2_kernel(const float* __restrict__ h, const float* __restrict__ aw,
                 const int* __restrict__ row_ptr, const int* __restrict__ src_sorted,
                 float* __restrict__ agg, int c0, int sw) {
  const int NPB = 256 / FIN;
  const int BPG = NN / NPB;
  int t = threadIdx.x;
  int f  = t & (FIN - 1);
  int nl = t / FIN;
  int blk = blockIdx.x;
  int gl, nb;
  if (sw) { int xcd = blk & 7, q = blk >> 3; gl = xcd + ((q / BPG) << 3); nb = q % BPG; }
  else    { gl = blk / BPG; nb = blk % BPG; }
  int n = nb * NPB + nl;
  int gi = c0 + gl;
  int rp = row_ptr[gi * (NN + 1) + n];
  int re = row_ptr[gi * (NN + 1) + n + 1];
  const int*   srcs = src_sorted + (size_t)gi * NE;
  const float* awg  = aw + (size_t)gl * NE * 6;
  const float* hb   = h + (size_t)gl * NN * FIN;
  float a0=0.f,a1=0.f,a2=0.f,a3=0.f,a4=0.f,a5=0.f;
  for (int e = rp; e < re; ++e) {
    int s = srcs[e];
    float hv = hb[(size_t)s * FIN + f];
    const float* w6 = awg + (size_t)e * 6;
    float2 w01 = *(const float2*)(w6);
    float2 w23 = *(const float2*)(w6 + 2);
    float2 w45 = *(const float2*)(w6 + 4);
    a0 += w01.x * hv; a1 += w01.y * hv;
    a2 += w23.x * hv; a3 += w23.y * hv;
    a4 += w45.x * hv; a5 += w45.y * hv;
  }
  float* ar = agg + ((size_t)gl * NN + n) * (6 * FIN) + f;
  ar[0]       = a0; ar[FIN]     = a1; ar[2 * FIN] = a2;
  ar[3 * FIN] = a3; ar[4 * FIN] = a4; ar[5 * FIN] = a5;
}

// ---------- MFMA GEMM, f32-accurate via bf16 hi/lo 3-term split ----------
// C[M,BN] = A[M,K](f32) * Bt[BN,K](pre-split bf16) + bias (+ELU). BM=64 rows/block.
template<int MF, int NF, int WMC, int WCC>
__global__ __launch_bounds__(256)
void gemm_mfma_kernel(const float* __restrict__ A,
                      const unsigned short* __restrict__ Bth,
                      const unsigned short* __restrict__ Btl,
                      const float* __restrict__ bias, float* __restrict__ C,
                      int K, int act, int sw) {
  const int BN = WCC * NF * 16;
  __shared__ unsigned short AhL[64 * 32], AlL[64 * 32];
  __shared__ unsigned short BhL[BN * 32], BlL[BN * 32];
  int t = threadIdx.x;
  int lane = t & 63, wv = t >> 6;
  int wm = wv % WMC, wc = wv / WMC;
  int l15 = lane & 15, lq = lane >> 4;
  int blk = blockIdx.x;
  const int BPG = NN / 64;   // 32 blocks per graph
  int m0;
  if (sw) { int xcd = blk & 7, q = blk >> 3; int gl = xcd + ((q / BPG) << 3); int nb = q % BPG; m0 = gl * NN + nb * 64; }
  else    m0 = blk * 64;
  f32x4 acc[MF][NF];
  #pragma unroll
  for (int i = 0; i < MF; ++i)
    #pragma unroll
    for (int j = 0; j < NF; ++j) { f32x4 z = {0.f,0.f,0.f,0.f}; acc[i][j] = z; }

  for (int k0 = 0; k0 < K; k0 += 32) {
    __syncthreads();
    // stage A tile 64x32 f32 -> bf16 hi/lo, swizzled
    #pragma unroll
    for (int i = 0; i < 2; ++i) {
      int q = t + i * 256;
      int row = q >> 3, c4 = q & 7;
      float4 av = make_float4(0.f, 0.f, 0.f, 0.f);
      int k = k0 + c4 * 4;
      if (k < K) av = *(const float4*)(A + (size_t)(m0 + row) * K + k);
      unsigned short h0 = bfhi(av.x), h1 = bfhi(av.y), h2 = bfhi(av.z), h3 = bfhi(av.w);
      unsigned short g0 = bfhi(av.x - bff(h0)), g1 = bfhi(av.y - bff(h1));
      unsigned short g2 = bfhi(av.z - bff(h2)), g3 = bfhi(av.w - bff(h3));
      int pos = row * 32 + (((c4 >> 1) ^ ((row >> 1) & 3)) << 3) + ((c4 & 1) << 2);
      *(ushort4*)&AhL[pos] = make_ushort4(h0, h1, h2, h3);
      *(ushort4*)&AlL[pos] = make_ushort4(g0, g1, g2, g3);
    }
    // stage B tile BNx32 bf16 hi/lo (already transposed+split in global)
    #pragma unroll
    for (int i = 0; i < BN / 64; ++i) {
      int q = t + i * 256;
      int n = q >> 2, c = q & 3;
      uint4 vh = make_uint4(0, 0, 0, 0), vl = make_uint4(0, 0, 0, 0);
      int k = k0 + c * 8;
      if (k < K) {
        vh = *(const uint4*)(Bth + (size_t)n * K + k);
        vl = *(const uint4*)(Btl + (size_t)n * K + k);
      }
      int pos = n * 32 + ((c ^ ((n >> 1) & 3)) << 3);
      *(uint4*)&BhL[pos] = vh;
      *(uint4*)&BlL[pos] = vl;
    }
    __syncthreads();
    bf16x8 ah[MF], al[MF], bh[NF], bl[NF];
    #pragma unroll
    for (int fr = 0; fr < MF; ++fr) {
      int row = wm * MF * 16 + fr * 16 + l15;
      int p = row * 32 + ((lq ^ ((row >> 1) & 3)) << 3);
      ah[fr] = *(const bf16x8*)&AhL[p];
      al[fr] = *(const bf16x8*)&AlL[p];
    }
    #pragma unroll
    for (int fc = 0; fc < NF; ++fc) {
      int row = wc * NF * 16 + fc * 16 + l15;
      int p = row * 32 + ((lq ^ ((row >> 1) & 3)) << 3);
      bh[fc] = *(const bf16x8*)&BhL[p];
      bl[fc] = *(const bf16x8*)&BlL[p];
    }
    #pragma unroll
    for (int fr = 0; fr < MF; ++fr)
      #pragma unroll
      for (int fc = 0; fc < NF; ++fc) {
        acc[fr][fc] = __builtin_amdgcn_mfma_f32_16x16x32_bf16(ah[fr], bh[fc], acc[fr][fc], 0, 0, 0);
        acc[fr][fc] = __builtin_amdgcn_mfma_f32_16x16x32_bf16(ah[fr], bl[fc], acc[fr][fc], 0, 0, 0);
        acc[fr][fc] = __builtin_amdgcn_mfma_f32_16x16x32_bf16(al[fr], bh[fc], acc[fr][fc], 0, 0, 0);
      }
  }
  #pragma unroll
  for (int fr = 0; fr < MF; ++fr) {
    int row = m0 + wm * MF * 16 + fr * 16 + lq * 4;
    #pragma unroll
    for (int fc = 0; fc < NF; ++fc) {
      int col = wc * NF * 16 + fc * 16 + l15;
      float bv = bias[col];
      #pragma unroll
      for (int r = 0; r < 4; ++r) {
        float v = acc[fr][fc][r] + bv;
        if (act) v = eluf(v);
        C[(size_t)(row + r) * BN + col] = v;
      }
    }
  }
}

// ---------- weighted readout: seq[t, s*64+d] += sum_n xn[t,n]*h4[n,d] ----------
// grid: G*32 blocks (64 nodes each), atomicAdd into pre-zeroed seq. XCD-swizzled.
__global__ __launch_bounds__(256)
void readout_kernel(const float* __restrict__ h4, const float* __restrict__ xn1,
                    const float* __restrict__ xn2, float* __restrict__ seq, int c0, int sw) {
  int blk = blockIdx.x;
  const int BPG = 32;
  int gl, nb;
  if (sw) { int xcd = blk & 7, q = blk >> 3; gl = xcd + ((q / BPG) << 3); nb = q % BPG; }
  else    { gl = blk / BPG; nb = blk % BPG; }
  int gi = c0 + gl;
  int t = gi >> 1, s = gi & 1;
  const float* xn = (s ? xn2 : xn1) + (size_t)t * NN;
  int tid = threadIdx.x;
  int d = tid & 63, grp = tid >> 6;   // 4 groups of 16 nodes
  int n0 = nb * 64 + grp * 16;
  float acc = 0.f;
  #pragma unroll
  for (int i = 0; i < 16; ++i) {
    int n = n0 + i;
    acc += xn[n] * h4[((size_t)gl * NN + n) * 64 + d];
  }
  __shared__ float sh[256];
  sh[tid] = acc;
  __syncthreads();
  if (tid < 64)
    atomicAdd(&seq[t * 128 + s * 64 + tid],
              sh[tid] + sh[tid + 64] + sh[tid + 128] + sh[tid + 192]);
}

// ---------- GRU + MLP head: parallel gi precompute, short sequential loop ----------
__global__ __launch_bounds__(128)
void gru_head_kernel(const float* __restrict__ seq, const float* __restrict__ Wih,
                     const float* __restrict__ Whh, const float* __restrict__ bih,
                     const float* __restrict__ bhh, const float* __restrict__ Wc1,
                     const float* __restrict__ bc1, const float* __restrict__ Wc2,
                     const float* __restrict__ bc2, float* __restrict__ out) {
  __shared__ float seqs[TS * 128];     // 32 KB
  __shared__ float giAll[TS * 96];     // 24 KB
  __shared__ float WhhT[32 * 96];      // 12 KB  [k][j]
  __shared__ float rnnS[TS * 32];      // 8 KB
  __shared__ float ghs[96];
  __shared__ float hs[32];
  int tid = threadIdx.x;
  for (int idx = tid; idx < TS * 128; idx += 128) seqs[idx] = seq[idx];
  for (int idx = tid; idx < 96 * 32; idx += 128) { int j = idx >> 5, k = idx & 31; WhhT[k * 96 + j] = Whh[idx]; }
  if (tid < 32) hs[tid] = 0.f;
  __syncthreads();
  // parallel: giAll[t][j] = bih[j] + Wih[j,:] . seq[t,:]
  for (int o = tid; o < TS * 96; o += 128) {
    int t = o / 96, j = o - t * 96;
    float a = bih[j];
    const float* wr = Wih + (size_t)j * 128;
    const float* xr = seqs + t * 128;
    #pragma unroll 4
    for (int k = 0; k < 128; ++k) a += wr[k] * xr[k];
    giAll[o] = a;
  }
  __syncthreads();
  // sequential GRU
  for (int t = 0; t < TS; ++t) {
    if (tid < 96) {
      float b = bhh[tid];
      #pragma unroll 4
      for (int k = 0; k < 32; ++k) b += WhhT[k * 96 + tid] * hs[k];
      ghs[tid] = b;
    }
    __syncthreads();
    if (tid < 32) {
      const float* gi = giAll + t * 96;
      float r = sigm(gi[tid] + ghs[tid]);
      float z = sigm(gi[32 + tid] + ghs[32 + tid]);
      float nv = tanhf(gi[64 + tid] + r * ghs[64 + tid]);
      float h2 = (1.f - z) * nv + z * hs[tid];
      hs[tid] = h2;
      rnnS[t * 32 + tid] = h2;
    }
    __syncthreads();
  }
  // head
  for (int o = tid; o < TS * 3; o += 128) {
    int t = o / 3, c = o - t * 3;
    float accv = bc2[c];
    for (int m = 0; m < 16; ++m) {
      float hv = bc1[m];
      for (int k = 0; k < 32; ++k) hv += rnnS[t * 32 + k] * Wc1[k * 16 + m];
      hv = fmaxf(hv, 0.f);
      accv += hv * Wc2[m * 3 + c];
    }
    out[o] = accv;
  }
}

static inline size_t alignup(size_t x) { return (x + 255) & ~(size_t)255; }

extern "C" void kernel_launch(void* const* d_in, const int* in_sizes, int n_in,
                              void* d_out, int out_size, void* d_ws, size_t ws_size,
                              hipStream_t stream) {
  const float* x1  = (const float*)d_in[0];
  const float* x2  = (const float*)d_in[1];
  const int*   ei1 = (const int*)d_in[2];
  const int*   ei2 = (const int*)d_in[3];
  const float* ew1 = (const float*)d_in[4];
  const float* ew2 = (const float*)d_in[5];
  const float* xn1 = (const float*)d_in[6];
  const float* xn2 = (const float*)d_in[7];
  const float* Wih = (const float*)d_in[25];
  const float* Whh = (const float*)d_in[26];
  const float* bih = (const float*)d_in[27];
  const float* bhh = (const float*)d_in[28];
  const float* Wc1 = (const float*)d_in[29];
  const float* bc1 = (const float*)d_in[30];
  const float* Wc2 = (const float*)d_in[31];
  const float* bc2 = (const float*)d_in[32];
  float* out = (float*)d_out;

  const int FINs[4]  = {4, 128, 128, 64};
  const int FOUTs[4] = {128, 128, 64, 64};
  const size_t uoffs[4] = {0, 24, 792, 1560};          // cum of H*FIN
  const size_t woffs[4] = {0, 3072, 101376, 150528};   // cum of K*FOUT (175104 total)

  // ---- workspace carve ----
  size_t off = 0;
  auto take = [&](size_t bytes) -> size_t { size_t o = off; off += alignup(bytes); return o; };
  size_t o_rowptr = take((size_t)NB * (NN + 1) * sizeof(int));
  size_t o_cursor = take((size_t)NB * NN * sizeof(int));
  size_t o_src    = take((size_t)NB * NE * sizeof(int));
  size_t o_ewsrt  = take((size_t)NB * NE * sizeof(float));
  size_t o_uS     = take(1944 * sizeof(float));
  size_t o_uD     = take(1944 * sizeof(float));
  size_t o_bth    = take(175104 * sizeof(unsigned short));
  size_t o_btl    = take(175104 * sizeof(unsigned short));
  size_t o_seq    = take((size_t)TS * 128 * sizeof(float));
  size_t persistent = off;

  // G capped at 16: with 8 XCDs this pins <=2 graphs per XCD's L2 (h + aw + sdv < 4 MiB)
  int G = 1;
  const int cand[5] = {16, 8, 4, 2, 1};
  for (int ci = 0; ci < 5; ++ci) {
    int g = cand[ci];
    size_t need = persistent
                + 2 * alignup((size_t)g * NN * 128 * sizeof(float))
                + alignup((size_t)g * NN * 12 * sizeof(float))
                + alignup((size_t)g * NN * 768 * sizeof(float))
                + alignup((size_t)g * NE * 6 * sizeof(float));
    if (need <= ws_size) { G = g; break; }
  }
  size_t o_hping = take((size_t)G * NN * 128 * sizeof(float));
  size_t o_hpong = take((size_t)G * NN * 128 * sizeof(float));
  size_t o_sd    = take((size_t)G * NN * 12 * sizeof(float));
  size_t o_agg   = take((size_t)G * NN * 768 * sizeof(float));
  size_t o_aw    = take((size_t)G * NE * 6 * sizeof(float));
  int sw = ((G & 7) == 0) ? 1 : 0;   // XCD swizzle only when G multiple of 8

  char* ws = (char*)d_ws;
  int*   row_ptr    = (int*)(ws + o_rowptr);
  int*   cursor     = (int*)(ws + o_cursor);
  int*   src_sorted = (int*)(ws + o_src);
  float* ew_sorted  = (float*)(ws + o_ewsrt);
  float* uS   = (float*)(ws + o_uS);
  float* uD   = (float*)(ws + o_uD);
  unsigned short* bth = (unsigned short*)(ws + o_bth);
  unsigned short* btl = (unsigned short*)(ws + o_btl);
  float* seq  = (float*)(ws + o_seq);
  float* h_ping = (float*)(ws + o_hping);
  float* h_pong = (float*)(ws + o_hpong);
  float* sdbuf  = (float*)(ws + o_sd);
  float* aggbuf = (float*)(ws + o_agg);
  float* awbuf  = (float*)(ws + o_aw);

  // ---- per-layer weight prep ----
  for (int l = 0; l < 4; ++l) {
    const float* Wl  = (const float*)d_in[9 + 4 * l];
    const float* aSl = (const float*)d_in[10 + 4 * l];
    const float* aDl = (const float*)d_in[11 + 4 * l];
    int totw = NH * FINs[l] * FOUTs[l];
    prep_layer_kernel<<<(totw + 255) / 256, 256, 0, stream>>>(
        Wl, aSl, aDl, uS + uoffs[l], uD + uoffs[l],
        bth + woffs[l], btl + woffs[l], FINs[l], FOUTs[l]);
  }

  // ---- CSR build (all 128 graph instances) + zero seq accumulator ----
  hipMemsetAsync(cursor, 0, (size_t)NB * NN * sizeof(int), stream);
  hipMemsetAsync(seq, 0, (size_t)TS * 128 * sizeof(float), stream);
  hist_kernel<<<(NB * NE) / 256, 256, 0, stream>>>(ei1, ei2, cursor);
  scan_kernel<<<NB, 256, 0, stream>>>(cursor, row_ptr);
  scatter_kernel<<<(NB * NE) / 256, 256, 0, stream>>>(ei1, ei2, ew1, ew2, cursor,
                                                      src_sorted, ew_sorted);

  // ---- chunked GAT pipeline ----
  for (int c0 = 0; c0 < NB; c0 += G) {
    copyx_kernel<<<(G * NN * 4 + 255) / 256, 256, 0, stream>>>(x1, x2, h_ping, c0, G);
    float* hin = h_ping;
    float* hout = h_pong;
    int rows = G * NN;
    for (int l = 0; l < 4; ++l) {
      int FIN = FINs[l], K = NH * FIN;
      sd_kernel<<<((size_t)rows * 12 + 255) / 256, 256, 0, stream>>>(
          hin, uS + uoffs[l], uD + uoffs[l], sdbuf, FIN, rows);
      alpha_kernel<<<rows / 32, 256, 0, stream>>>(sdbuf, row_ptr, src_sorted,
                                                  ew_sorted, awbuf, c0, sw);
      if (l == 0)
        agg2_kernel<4><<<rows / 64, 256, 0, stream>>>(hin, awbuf, row_ptr, src_sorted, aggbuf, c0, sw);
      else if (l == 3)
        agg2_kernel<64><<<rows / 4, 256, 0, stream>>>(hin, awbuf, row_ptr, src_sorted, aggbuf, c0, sw);
      else
        agg2_kernel<128><<<rows / 2, 256, 0, stream>>>(hin, awbuf, row_ptr, src_sorted, aggbuf, c0, sw);
      const float* bias = (const float*)d_in[12 + 4 * l];
      int act = (l < 3) ? 1 : 0;
      if (FOUTs[l] == 128)
        gemm_mfma_kernel<2, 4, 2, 2><<<rows / 64, 256, 0, stream>>>(
            aggbuf, bth + woffs[l], btl + woffs[l], bias, hout, K, act, sw);
      else
        gemm_mfma_kernel<1, 4, 4, 1><<<rows / 64, 256, 0, stream>>>(
            aggbuf, bth + woffs[l], btl + woffs[l], bias, hout, K, act, sw);
      float* tmp = hin; hin = hout; hout = tmp;
    }
    readout_kernel<<<G * 32, 256, 0, stream>>>(hin, xn1, xn2, seq, c0, sw);
  }

  // ---- GRU + head ----
  gru_head_kernel<<<1, 128, 0, stream>>>(seq, Wih, Whh, bih, bhh, Wc1, bc1, Wc2, bc2, out);
}

// Round 4
// 4528.595 us; speedup vs baseline: 2.7929x; 1.1430x over previous
//
#include <hip/hip_runtime.h>
#include <math.h>

#define TS 64
#define NN 2048
#define NE 32768
#define NH 6
#define NB 128   // 2*TS graph instances

typedef __attribute__((ext_vector_type(8))) __bf16 bf16x8;
typedef __attribute__((ext_vector_type(4))) float f32x4;

__device__ __forceinline__ float lrelu(float x){ return x >= 0.0f ? x : 0.2f*x; }
__device__ __forceinline__ float eluf(float x){ return x > 0.0f ? x : expm1f(x); }
__device__ __forceinline__ float sigm(float x){ return 1.0f/(1.0f+expf(-x)); }
__device__ __forceinline__ unsigned short bfhi(float x){ return (unsigned short)(__float_as_uint(x) >> 16); }
__device__ __forceinline__ float bff(unsigned short u){ return __uint_as_float(((unsigned int)u) << 16); }

// ---------- per-layer prep: uS,uD [H*FIN]; B split+transposed bf16 hi/lo [N][K] ----------
__global__ void prep_layer_kernel(const float* __restrict__ W,
                                  const float* __restrict__ aS,
                                  const float* __restrict__ aD,
                                  float* __restrict__ uS, float* __restrict__ uD,
                                  unsigned short* __restrict__ bth,
                                  unsigned short* __restrict__ btl,
                                  int FIN, int FOUT) {
  int idx = blockIdx.x * blockDim.x + threadIdx.x;
  int K = NH * FIN;
  if (idx < K * FOUT) {
    int k = idx / FOUT, o = idx - k * FOUT;
    int h = k / FIN, f = k - h * FIN;
    float v = W[(size_t)(f * NH + h) * FOUT + o] * (1.0f / NH);
    unsigned short hb = bfhi(v);
    unsigned short lb = bfhi(v - bff(hb));
    bth[(size_t)o * K + k] = hb;
    btl[(size_t)o * K + k] = lb;
  }
  if (idx < NH * FIN) {
    int h = idx / FIN, f = idx - h * FIN;
    const float* wr = W + (size_t)(f * NH + h) * FOUT;
    const float* as = aS + h * FOUT;
    const float* ad = aD + h * FOUT;
    float ss = 0.f, dd = 0.f;
    for (int o = 0; o < FOUT; ++o) { float w = wr[o]; ss += w * as[o]; dd += w * ad[o]; }
    uS[idx] = ss; uD[idx] = dd;
  }
}

// ---------- CSR build: one workgroup per graph, LDS hist/scan/cursor ----------
__global__ __launch_bounds__(256)
void csr_kernel(const int* __restrict__ ei1, const int* __restrict__ ei2,
                const float* __restrict__ ew1, const float* __restrict__ ew2,
                int* __restrict__ row_ptr, int* __restrict__ src_sorted,
                float* __restrict__ ew_sorted) {
  __shared__ int cnt[NN];
  __shared__ int part[256];
  int gi = blockIdx.x, t = threadIdx.x;
  int tt = gi >> 1, s = gi & 1;
  const int* ei = s ? ei2 : ei1;
  const float* ew = s ? ew2 : ew1;
  const int* srcp = ei + (size_t)(tt * 2) * NE;
  const int* dstp = ei + (size_t)(tt * 2 + 1) * NE;
  const float* ewp = ew + (size_t)tt * NE;
  for (int i = t; i < NN; i += 256) cnt[i] = 0;
  __syncthreads();
  for (int e = t; e < NE; e += 256) atomicAdd(&cnt[dstp[e]], 1);
  __syncthreads();
  int loc[8]; int run = 0;
  for (int i = 0; i < 8; ++i) { loc[i] = run; run += cnt[t * 8 + i]; }
  part[t] = run;
  __syncthreads();
  if (t == 0) { int acc = 0; for (int i = 0; i < 256; ++i) { int v = part[i]; part[i] = acc; acc += v; } }
  __syncthreads();
  int o = part[t];
  int* rp = row_ptr + (size_t)gi * (NN + 1);
  for (int i = 0; i < 8; ++i) { rp[t * 8 + i] = o + loc[i]; cnt[t * 8 + i] = o + loc[i]; }
  if (t == 255) rp[NN] = o + run;
  __syncthreads();
  int* srcd = src_sorted + (size_t)gi * NE;
  float* ewd = ew_sorted + (size_t)gi * NE;
  for (int e = t; e < NE; e += 256) {
    int d = dstp[e];
    int pos = atomicAdd(&cnt[d], 1);
    srcd[pos] = srcp[e];
    ewd[pos] = ewp[e];
  }
}

// ---------- stage x into h_ping + layer-0 s/d logits ----------
__global__ __launch_bounds__(256)
void copyx_sd0_kernel(const float* __restrict__ x1, const float* __restrict__ x2,
                      const float* __restrict__ uS0, const float* __restrict__ uD0,
                      float* __restrict__ hping, float* __restrict__ sdv, int c0) {
  __shared__ float uL[48];
  int t = threadIdx.x;
  if (t < 24) uL[t] = uS0[t];
  else if (t < 48) uL[t] = uD0[t - 24];
  __syncthreads();
  int nodeg = blockIdx.x * 256 + t;
  int gl = nodeg >> 11, n = nodeg & (NN - 1);
  int gi = c0 + gl;
  int tt = gi >> 1, s = gi & 1;
  const float* x = s ? x2 : x1;
  float4 xv = *(const float4*)(x + ((size_t)tt * NN + n) * 4);
  *(float4*)(hping + (size_t)nodeg * 4) = xv;
  float* sd = sdv + (size_t)nodeg * 12;
  #pragma unroll
  for (int j = 0; j < 12; ++j) {
    const float* u = uL + (j < 6 ? j * 4 : 24 + (j - 6) * 4);
    sd[j] = xv.x * u[0] + xv.y * u[1] + xv.z * u[2] + xv.w * u[3];
  }
}

// ---------- layer-0 fused softmax+aggregate (FIN=4, recompute path) ----------
__global__ __launch_bounds__(256)
void agg0_kernel(const float* __restrict__ h, const float* __restrict__ sdv,
                 const int* __restrict__ row_ptr, const int* __restrict__ src_sorted,
                 const float* __restrict__ ew_sorted, float* __restrict__ agg,
                 int c0, int sw) {
  const int NPB = 64, IL = 4, BPG = NN / (NPB * IL);   // 8
  __shared__ float mL[NPB * 6], ivL[NPB * 6];
  int t = threadIdx.x, blk = blockIdx.x;
  int gl, nb;
  if (sw) { int xcd = blk & 7, q = blk >> 3; gl = xcd + ((q / BPG) << 3); nb = q % BPG; }
  else    { gl = blk / BPG; nb = blk % BPG; }
  int gi = c0 + gl;
  const int* rpg = row_ptr + (size_t)gi * (NN + 1);
  const int* srcs = src_sorted + (size_t)gi * NE;
  const float* ews = ew_sorted + (size_t)gi * NE;
  const float* sdg = sdv + (size_t)gl * NN * 12;
  const float* hb = h + (size_t)gl * NN * 4;
  float* aggb = agg + (size_t)gl * NN * 24;
  for (int it = 0; it < IL; ++it) {
    __syncthreads();
    int n0 = nb * (NPB * IL) + it * NPB;
    for (int pid = t; pid < NPB * 6; pid += 256) {
      int nl = pid / 6, j = pid - nl * 6;
      int n = n0 + nl;
      int rp = rpg[n], re = rpg[n + 1];
      float d = sdg[n * 12 + 6 + j];
      float m = -INFINITY;
      for (int e = rp; e < re; ++e) m = fmaxf(m, lrelu(sdg[srcs[e] * 12 + j] + d));
      float den = 0.f;
      for (int e = rp; e < re; ++e) den += expf(lrelu(sdg[srcs[e] * 12 + j] + d) - m);
      mL[pid] = m; ivL[pid] = 1.f / (den + 1e-16f);
    }
    __syncthreads();
    int nl = t >> 2, f = t & 3;
    int n = n0 + nl;
    int rp = rpg[n], re = rpg[n + 1];
    float dj[6], mj[6], ij[6];
    #pragma unroll
    for (int j = 0; j < 6; ++j) { dj[j] = sdg[n * 12 + 6 + j]; mj[j] = mL[nl * 6 + j]; ij[j] = ivL[nl * 6 + j]; }
    float acc[6] = {0.f, 0.f, 0.f, 0.f, 0.f, 0.f};
    for (int e = rp; e < re; ++e) {
      int sct = srcs[e];
      float wh = ews[e] * hb[(size_t)sct * 4 + f];
      const float* srow = sdg + (size_t)sct * 12;
      #pragma unroll
      for (int j = 0; j < 6; ++j) acc[j] += expf(lrelu(srow[j] + dj[j]) - mj[j]) * ij[j] * wh;
    }
    float* ar = aggb + (size_t)n * 24;
    #pragma unroll
    for (int j = 0; j < 6; ++j) ar[j * 4 + f] = acc[j];
  }
}

// ---------- fused softmax+aggregate, LDS-cached alpha (FIN=64/128) ----------
template<int FIN, int PT>
__global__ __launch_bounds__(256)
void aggc_kernel(const float* __restrict__ h, const float* __restrict__ sdv,
                 const int* __restrict__ row_ptr, const int* __restrict__ src_sorted,
                 const float* __restrict__ ew_sorted, float* __restrict__ agg,
                 int c0, int sw) {
  const int TPN = FIN / 2;           // threads per node (float2)
  const int NPB = 256 / TPN;
  const int IL = 4;
  const int BPG = NN / (NPB * IL);
  const int CAP = 80;
  __shared__ float awL[NPB][CAP][6];
  __shared__ float mL[NPB * 6], ivL[NPB * 6];
  int t = threadIdx.x, blk = blockIdx.x;
  int gl, nb;
  if (sw) { int xcd = blk & 7, q = blk >> 3; gl = xcd + ((q / BPG) << 3); nb = q % BPG; }
  else    { gl = blk / BPG; nb = blk % BPG; }
  int gi = c0 + gl;
  const int* rpg = row_ptr + (size_t)gi * (NN + 1);
  const int* srcs = src_sorted + (size_t)gi * NE;
  const float* ews = ew_sorted + (size_t)gi * NE;
  const float* sdg = sdv + (size_t)gl * NN * 12;
  const float2* hb2 = (const float2*)(h + (size_t)gl * NN * FIN);
  float* aggb = agg + (size_t)gl * NN * (6 * FIN);
  for (int it = 0; it < IL; ++it) {
    __syncthreads();
    int n0 = nb * (NPB * IL) + it * NPB;
    int pid = t / PT, sub = t % PT;
    if (pid < NPB * 6) {
      int nl = pid / 6, j = pid - nl * 6;
      int n = n0 + nl;
      int rp = rpg[n], re = rpg[n + 1];
      float d = sdg[n * 12 + 6 + j];
      float m = -INFINITY;
      for (int e = rp + sub; e < re; e += PT) m = fmaxf(m, lrelu(sdg[srcs[e] * 12 + j] + d));
      #pragma unroll
      for (int msk = PT >> 1; msk; msk >>= 1) m = fmaxf(m, __shfl_xor(m, msk, PT));
      float den = 0.f;
      for (int e = rp + sub; e < re; e += PT) den += expf(lrelu(sdg[srcs[e] * 12 + j] + d) - m);
      #pragma unroll
      for (int msk = PT >> 1; msk; msk >>= 1) den += __shfl_xor(den, msk, PT);
      float iv = 1.f / (den + 1e-16f);
      for (int e = rp + sub; e < re; e += PT) {
        int idx = e - rp;
        if (idx < CAP)
          awL[nl][idx][j] = expf(lrelu(sdg[srcs[e] * 12 + j] + d) - m) * iv * ews[e];
      }
      if (sub == 0) { mL[pid] = m; ivL[pid] = iv; }
    }
    __syncthreads();
    int nl = t / TPN, f2 = t % TPN;
    int n = n0 + nl;
    int rp = rpg[n], re = rpg[n + 1];
    float2 acc[6];
    #pragma unroll
    for (int j = 0; j < 6; ++j) acc[j] = make_float2(0.f, 0.f);
    if (re - rp <= CAP) {
      for (int e = rp; e < re; ++e) {
        int idx = e - rp, sct = srcs[e];
        float2 hv = hb2[(size_t)sct * TPN + f2];
        #pragma unroll
        for (int j = 0; j < 6; ++j) { float a = awL[nl][idx][j]; acc[j].x += a * hv.x; acc[j].y += a * hv.y; }
      }
    } else {
      float dj[6], mj[6], ij[6];
      #pragma unroll
      for (int j = 0; j < 6; ++j) { dj[j] = sdg[n * 12 + 6 + j]; mj[j] = mL[nl * 6 + j]; ij[j] = ivL[nl * 6 + j]; }
      for (int e = rp; e < re; ++e) {
        int idx = e - rp, sct = srcs[e];
        float2 hv = hb2[(size_t)sct * TPN + f2];
        if (idx < CAP) {
          #pragma unroll
          for (int j = 0; j < 6; ++j) { float a = awL[nl][idx][j]; acc[j].x += a * hv.x; acc[j].y += a * hv.y; }
        } else {
          float w = ews[e];
          const float* srow = sdg + (size_t)sct * 12;
          #pragma unroll
          for (int j = 0; j < 6; ++j) {
            float a = expf(lrelu(srow[j] + dj[j]) - mj[j]) * ij[j] * w;
            acc[j].x += a * hv.x; acc[j].y += a * hv.y;
          }
        }
      }
    }
    float2* ar = (float2*)(aggb + (size_t)n * (6 * FIN));
    #pragma unroll
    for (int j = 0; j < 6; ++j) ar[j * TPN + f2] = acc[j];
  }
}

// ---------- MFMA GEMM (bf16 hi/lo split) + fused epilogue ----------
// EPI: 1 = write C + next-layer s/d logits; 2 = readout only (no C write)
template<int MF, int NF, int WMC, int WCC, int EPI>
__global__ __launch_bounds__(256)
void gemm_mfma_kernel(const float* __restrict__ A,
                      const unsigned short* __restrict__ Bth,
                      const unsigned short* __restrict__ Btl,
                      const float* __restrict__ bias, float* __restrict__ C,
                      int K, int act, int sw,
                      const float* __restrict__ uSn, const float* __restrict__ uDn,
                      float* __restrict__ sdv,
                      const float* __restrict__ xn1, const float* __restrict__ xn2,
                      float* __restrict__ seqv, int c0) {
  const int BN = WCC * NF * 16;
  __shared__ unsigned short AhL[64 * 32], AlL[64 * 32];
  __shared__ unsigned short BhL[BN * 32], BlL[BN * 32];
  __shared__ float CT[64][BN + 1];
  __shared__ float uLDS[12 * (BN + 1)];
  __shared__ float xnL[64];
  __shared__ float red[256];
  int t = threadIdx.x;
  int lane = t & 63, wv = t >> 6;
  int wm = wv % WMC, wc = wv / WMC;
  int l15 = lane & 15, lq = lane >> 4;
  int blk = blockIdx.x;
  const int BPG = NN / 64;
  int m0;
  if (sw) { int xcd = blk & 7, q = blk >> 3; int gl = xcd + ((q / BPG) << 3); int nb = q % BPG; m0 = gl * NN + nb * 64; }
  else    m0 = blk * 64;
  f32x4 acc[MF][NF];
  #pragma unroll
  for (int i = 0; i < MF; ++i)
    #pragma unroll
    for (int j = 0; j < NF; ++j) { f32x4 z = {0.f, 0.f, 0.f, 0.f}; acc[i][j] = z; }

  for (int k0 = 0; k0 < K; k0 += 32) {
    __syncthreads();
    #pragma unroll
    for (int i = 0; i < 2; ++i) {
      int q = t + i * 256;
      int row = q >> 3, c4 = q & 7;
      float4 av = make_float4(0.f, 0.f, 0.f, 0.f);
      int k = k0 + c4 * 4;
      if (k < K) av = *(const float4*)(A + (size_t)(m0 + row) * K + k);
      unsigned short h0 = bfhi(av.x), h1 = bfhi(av.y), h2 = bfhi(av.z), h3 = bfhi(av.w);
      unsigned short g0 = bfhi(av.x - bff(h0)), g1 = bfhi(av.y - bff(h1));
      unsigned short g2 = bfhi(av.z - bff(h2)), g3 = bfhi(av.w - bff(h3));
      int pos = row * 32 + (((c4 >> 1) ^ ((row >> 1) & 3)) << 3) + ((c4 & 1) << 2);
      *(ushort4*)&AhL[pos] = make_ushort4(h0, h1, h2, h3);
      *(ushort4*)&AlL[pos] = make_ushort4(g0, g1, g2, g3);
    }
    #pragma unroll
    for (int i = 0; i < BN / 64; ++i) {
      int q = t + i * 256;
      int n = q >> 2, c = q & 3;
      uint4 vh = make_uint4(0, 0, 0, 0), vl = make_uint4(0, 0, 0, 0);
      int k = k0 + c * 8;
      if (k < K) {
        vh = *(const uint4*)(Bth + (size_t)n * K + k);
        vl = *(const uint4*)(Btl + (size_t)n * K + k);
      }
      int pos = n * 32 + ((c ^ ((n >> 1) & 3)) << 3);
      *(uint4*)&BhL[pos] = vh;
      *(uint4*)&BlL[pos] = vl;
    }
    __syncthreads();
    bf16x8 ah[MF], al[MF], bh[NF], bl[NF];
    #pragma unroll
    for (int fr = 0; fr < MF; ++fr) {
      int row = wm * MF * 16 + fr * 16 + l15;
      int p = row * 32 + ((lq ^ ((row >> 1) & 3)) << 3);
      ah[fr] = *(const bf16x8*)&AhL[p];
      al[fr] = *(const bf16x8*)&AlL[p];
    }
    #pragma unroll
    for (int fc = 0; fc < NF; ++fc) {
      int row = wc * NF * 16 + fc * 16 + l15;
      int p = row * 32 + ((lq ^ ((row >> 1) & 3)) << 3);
      bh[fc] = *(const bf16x8*)&BhL[p];
      bl[fc] = *(const bf16x8*)&BlL[p];
    }
    #pragma unroll
    for (int fr = 0; fr < MF; ++fr)
      #pragma unroll
      for (int fc = 0; fc < NF; ++fc) {
        acc[fr][fc] = __builtin_amdgcn_mfma_f32_16x16x32_bf16(ah[fr], bh[fc], acc[fr][fc], 0, 0, 0);
        acc[fr][fc] = __builtin_amdgcn_mfma_f32_16x16x32_bf16(ah[fr], bl[fc], acc[fr][fc], 0, 0, 0);
        acc[fr][fc] = __builtin_amdgcn_mfma_f32_16x16x32_bf16(al[fr], bh[fc], acc[fr][fc], 0, 0, 0);
      }
  }
  __syncthreads();
  #pragma unroll
  for (int fr = 0; fr < MF; ++fr) {
    int rl0 = wm * MF * 16 + fr * 16 + lq * 4;
    #pragma unroll
    for (int fc = 0; fc < NF; ++fc) {
      int col = wc * NF * 16 + fc * 16 + l15;
      float bv = bias[col];
      #pragma unroll
      for (int r = 0; r < 4; ++r) {
        float v = acc[fr][fc][r] + bv;
        if (act) v = eluf(v);
        if (EPI != 2) C[(size_t)(m0 + rl0 + r) * BN + col] = v;
        CT[rl0 + r][col] = v;
      }
    }
  }
  __syncthreads();
  if (EPI == 1) {
    for (int idx = t; idx < 12 * BN; idx += 256) {
      int j = idx / BN, f = idx - j * BN;
      uLDS[j * (BN + 1) + f] = (j < 6) ? uSn[j * BN + f] : uDn[(j - 6) * BN + f];
    }
    __syncthreads();
    for (int o = t; o < 64 * 12; o += 256) {
      int rl = o / 12, j = o - rl * 12;
      const float* ur = uLDS + j * (BN + 1);
      float a = 0.f;
      for (int f = 0; f < BN; ++f) a += CT[rl][f] * ur[f];
      sdv[(size_t)(m0 + rl) * 12 + j] = a;
    }
  } else {
    int gl = m0 >> 11;
    int gi = c0 + gl;
    int tt = gi >> 1, ss = gi & 1;
    const float* xn = (ss ? xn2 : xn1) + (size_t)tt * NN;
    int nl0 = m0 & (NN - 1);
    if (t < 64) xnL[t] = xn[nl0 + t];
    __syncthreads();
    int d = t & 63, q = t >> 6;
    float a = 0.f;
    #pragma unroll
    for (int i = 0; i < 16; ++i) a += xnL[q * 16 + i] * CT[q * 16 + i][d];
    red[t] = a;
    __syncthreads();
    if (t < 64)
      atomicAdd(&seqv[tt * 128 + ss * 64 + t], red[t] + red[t + 64] + red[t + 128] + red[t + 192]);
  }
}

// ---------- GRU + MLP head: all weights in LDS ----------
__global__ __launch_bounds__(256)
void gru_head_kernel(const float* __restrict__ seq, const float* __restrict__ Wih,
                     const float* __restrict__ Whh, const float* __restrict__ bih,
                     const float* __restrict__ bhh, const float* __restrict__ Wc1,
                     const float* __restrict__ bc1, const float* __restrict__ Wc2,
                     const float* __restrict__ bc2, float* __restrict__ out) {
  __shared__ float seqs[TS * 128];   // 32 KB
  __shared__ float WihT[128 * 96];   // 48 KB [k][j]
  __shared__ float WhhT[32 * 96];    // 12 KB [k][j]
  __shared__ float giAll[TS * 96];   // 24 KB
  __shared__ float rnnS[TS * 32];    // 8 KB
  __shared__ float Wc1L[32 * 16];
  __shared__ float Wc2L[16 * 3];
  __shared__ float bihL[96], bhhL[96], bc1L[16], bc2L[3];
  __shared__ float ghs[96], hs[32];
  int t = threadIdx.x;
  for (int idx = t; idx < TS * 128; idx += 256) seqs[idx] = seq[idx];
  for (int idx = t; idx < 96 * 128; idx += 256) { int j = idx >> 7, k = idx & 127; WihT[k * 96 + j] = Wih[idx]; }
  for (int idx = t; idx < 96 * 32; idx += 256) { int j = idx >> 5, k = idx & 31; WhhT[k * 96 + j] = Whh[idx]; }
  for (int idx = t; idx < 512; idx += 256) Wc1L[idx] = Wc1[idx];
  if (t < 48) Wc2L[t] = Wc2[t];
  if (t < 96) { bihL[t] = bih[t]; bhhL[t] = bhh[t]; }
  if (t >= 96 && t < 112) bc1L[t - 96] = bc1[t - 96];
  if (t >= 112 && t < 115) bc2L[t - 112] = bc2[t - 112];
  if (t < 32) hs[t] = 0.f;
  __syncthreads();
  for (int o = t; o < TS * 96; o += 256) {
    int tt = o / 96, j = o - tt * 96;
    float a = bihL[j];
    const float* xr = seqs + tt * 128;
    #pragma unroll 4
    for (int k = 0; k < 128; ++k) a += WihT[k * 96 + j] * xr[k];
    giAll[o] = a;
  }
  __syncthreads();
  for (int tt = 0; tt < TS; ++tt) {
    if (t < 96) {
      float b = bhhL[t];
      #pragma unroll
      for (int k = 0; k < 32; ++k) b += WhhT[k * 96 + t] * hs[k];
      ghs[t] = b;
    }
    __syncthreads();
    if (t < 32) {
      const float* gi = giAll + tt * 96;
      float r = sigm(gi[t] + ghs[t]);
      float z = sigm(gi[32 + t] + ghs[32 + t]);
      float nv = tanhf(gi[64 + t] + r * ghs[64 + t]);
      float h2 = (1.f - z) * nv + z * hs[t];
      hs[t] = h2;
      rnnS[tt * 32 + t] = h2;
    }
    __syncthreads();
  }
  for (int o = t; o < TS * 3; o += 256) {
    int tt = o / 3, c = o - tt * 3;
    float accv = bc2L[c];
    #pragma unroll
    for (int m = 0; m < 16; ++m) {
      float hv = bc1L[m];
      #pragma unroll
      for (int k = 0; k < 32; ++k) hv += rnnS[tt * 32 + k] * Wc1L[k * 16 + m];
      hv = fmaxf(hv, 0.f);
      accv += hv * Wc2L[m * 3 + c];
    }
    out[o] = accv;
  }
}

static inline size_t alignup(size_t x) { return (x + 255) & ~(size_t)255; }

extern "C" void kernel_launch(void* const* d_in, const int* in_sizes, int n_in,
                              void* d_out, int out_size, void* d_ws, size_t ws_size,
                              hipStream_t stream) {
  const float* x1  = (const float*)d_in[0];
  const float* x2  = (const float*)d_in[1];
  const int*   ei1 = (const int*)d_in[2];
  const int*   ei2 = (const int*)d_in[3];
  const float* ew1 = (const float*)d_in[4];
  const float* ew2 = (const float*)d_in[5];
  const float* xn1 = (const float*)d_in[6];
  const float* xn2 = (const float*)d_in[7];
  const float* Wih = (const float*)d_in[25];
  const float* Whh = (const float*)d_in[26];
  const float* bih = (const float*)d_in[27];
  const float* bhh = (const float*)d_in[28];
  const float* Wc1 = (const float*)d_in[29];
  const float* bc1 = (const float*)d_in[30];
  const float* Wc2 = (const float*)d_in[31];
  const float* bc2 = (const float*)d_in[32];
  float* out = (float*)d_out;

  const int FINs[4]  = {4, 128, 128, 64};
  const int FOUTs[4] = {128, 128, 64, 64};
  const size_t uoffs[4] = {0, 24, 792, 1560};          // cum of H*FIN
  const size_t woffs[4] = {0, 3072, 101376, 150528};   // cum of K*FOUT (175104 total)

  // ---- workspace carve ----
  size_t off = 0;
  auto take = [&](size_t bytes) -> size_t { size_t o = off; off += alignup(bytes); return o; };
  size_t o_rowptr = take((size_t)NB * (NN + 1) * sizeof(int));
  size_t o_src    = take((size_t)NB * NE * sizeof(int));
  size_t o_ewsrt  = take((size_t)NB * NE * sizeof(float));
  size_t o_uS     = take(1944 * sizeof(float));
  size_t o_uD     = take(1944 * sizeof(float));
  size_t o_bth    = take(175104 * sizeof(unsigned short));
  size_t o_btl    = take(175104 * sizeof(unsigned short));
  size_t o_seq    = take((size_t)TS * 128 * sizeof(float));
  size_t persistent = off;

  int G = 8;
  const int cand[3] = {32, 16, 8};
  for (int ci = 0; ci < 3; ++ci) {
    int g = cand[ci];
    size_t need = persistent
                + 2 * alignup((size_t)g * NN * 128 * sizeof(float))
                + alignup((size_t)g * NN * 12 * sizeof(float))
                + alignup((size_t)g * NN * 768 * sizeof(float));
    if (need <= ws_size) { G = g; break; }
  }
  size_t o_hping = take((size_t)G * NN * 128 * sizeof(float));
  size_t o_hpong = take((size_t)G * NN * 128 * sizeof(float));
  size_t o_sd    = take((size_t)G * NN * 12 * sizeof(float));
  size_t o_agg   = take((size_t)G * NN * 768 * sizeof(float));
  int sw = ((G & 7) == 0) ? 1 : 0;

  char* ws = (char*)d_ws;
  int*   row_ptr    = (int*)(ws + o_rowptr);
  int*   src_sorted = (int*)(ws + o_src);
  float* ew_sorted  = (float*)(ws + o_ewsrt);
  float* uS   = (float*)(ws + o_uS);
  float* uD   = (float*)(ws + o_uD);
  unsigned short* bth = (unsigned short*)(ws + o_bth);
  unsigned short* btl = (unsigned short*)(ws + o_btl);
  float* seq  = (float*)(ws + o_seq);
  float* h_ping = (float*)(ws + o_hping);
  float* h_pong = (float*)(ws + o_hpong);
  float* sdbuf  = (float*)(ws + o_sd);
  float* aggbuf = (float*)(ws + o_agg);

  // ---- weight prep + CSR + seq zero ----
  for (int l = 0; l < 4; ++l) {
    const float* Wl  = (const float*)d_in[9 + 4 * l];
    const float* aSl = (const float*)d_in[10 + 4 * l];
    const float* aDl = (const float*)d_in[11 + 4 * l];
    int totw = NH * FINs[l] * FOUTs[l];
    prep_layer_kernel<<<(totw + 255) / 256, 256, 0, stream>>>(
        Wl, aSl, aDl, uS + uoffs[l], uD + uoffs[l],
        bth + woffs[l], btl + woffs[l], FINs[l], FOUTs[l]);
  }
  csr_kernel<<<NB, 256, 0, stream>>>(ei1, ei2, ew1, ew2, row_ptr, src_sorted, ew_sorted);
  hipMemsetAsync(seq, 0, (size_t)TS * 128 * sizeof(float), stream);

  // ---- chunked GAT pipeline (9 dispatches per chunk) ----
  for (int c0 = 0; c0 < NB; c0 += G) {
    int rows = G * NN;
    copyx_sd0_kernel<<<rows / 256, 256, 0, stream>>>(x1, x2, uS, uD, h_ping, sdbuf, c0);

    // layer 0: FIN=4 -> FOUT=128 (sd epilogue for layer 1)
    agg0_kernel<<<rows / 256, 256, 0, stream>>>(h_ping, sdbuf, row_ptr, src_sorted,
                                                ew_sorted, aggbuf, c0, sw);
    gemm_mfma_kernel<2, 4, 2, 2, 1><<<rows / 64, 256, 0, stream>>>(
        aggbuf, bth + woffs[0], btl + woffs[0], (const float*)d_in[12], h_pong,
        24, 1, sw, uS + uoffs[1], uD + uoffs[1], sdbuf, nullptr, nullptr, nullptr, c0);

    // layer 1: FIN=128 -> FOUT=128 (sd epilogue for layer 2)
    aggc_kernel<128, 8><<<rows / 16, 256, 0, stream>>>(h_pong, sdbuf, row_ptr, src_sorted,
                                                       ew_sorted, aggbuf, c0, sw);
    gemm_mfma_kernel<2, 4, 2, 2, 1><<<rows / 64, 256, 0, stream>>>(
        aggbuf, bth + woffs[1], btl + woffs[1], (const float*)d_in[16], h_ping,
        768, 1, sw, uS + uoffs[2], uD + uoffs[2], sdbuf, nullptr, nullptr, nullptr, c0);

    // layer 2: FIN=128 -> FOUT=64 (sd epilogue for layer 3)
    aggc_kernel<128, 8><<<rows / 16, 256, 0, stream>>>(h_ping, sdbuf, row_ptr, src_sorted,
                                                       ew_sorted, aggbuf, c0, sw);
    gemm_mfma_kernel<1, 4, 4, 1, 1><<<rows / 64, 256, 0, stream>>>(
        aggbuf, bth + woffs[2], btl + woffs[2], (const float*)d_in[20], h_pong,
        768, 1, sw, uS + uoffs[3], uD + uoffs[3], sdbuf, nullptr, nullptr, nullptr, c0);

    // layer 3: FIN=64 -> FOUT=64, readout epilogue (no C write, no activation)
    aggc_kernel<64, 4><<<rows / 32, 256, 0, stream>>>(h_pong, sdbuf, row_ptr, src_sorted,
                                                      ew_sorted, aggbuf, c0, sw);
    gemm_mfma_kernel<1, 4, 4, 1, 2><<<rows / 64, 256, 0, stream>>>(
        aggbuf, bth + woffs[3], btl + woffs[3], (const float*)d_in[24], nullptr,
        384, 0, sw, nullptr, nullptr, nullptr, xn1, xn2, seq, c0);
  }

  // ---- GRU + head ----
  gru_head_kernel<<<1, 256, 0, stream>>>(seq, Wih, Whh, bih, bhh, Wc1, bc1, Wc2, bc2, out);
}

// Round 5
// 4256.742 us; speedup vs baseline: 2.9713x; 1.0639x over previous
//
#include <hip/hip_runtime.h>
#include <math.h>

#define TS 64
#define NN 2048
#define NE 32768
#define NH 6
#define NB 128   // 2*TS graph instances

typedef __attribute__((ext_vector_type(8))) __bf16 bf16x8;
typedef __attribute__((ext_vector_type(4))) float f32x4;

__device__ __forceinline__ float lrelu(float x){ return x >= 0.0f ? x : 0.2f*x; }
__device__ __forceinline__ float eluf(float x){ return x > 0.0f ? x : expm1f(x); }
__device__ __forceinline__ float sigm(float x){ return 1.0f/(1.0f+expf(-x)); }
__device__ __forceinline__ unsigned short bfhi(float x){ return (unsigned short)(__float_as_uint(x) >> 16); }
__device__ __forceinline__ float bff(unsigned short u){ return __uint_as_float(((unsigned int)u) << 16); }

// ---------- per-layer prep: uS,uD [H*FIN]; B split+transposed bf16 hi/lo [N][K] ----------
__global__ void prep_layer_kernel(const float* __restrict__ W,
                                  const float* __restrict__ aS,
                                  const float* __restrict__ aD,
                                  float* __restrict__ uS, float* __restrict__ uD,
                                  unsigned short* __restrict__ bth,
                                  unsigned short* __restrict__ btl,
                                  int FIN, int FOUT) {
  int idx = blockIdx.x * blockDim.x + threadIdx.x;
  int K = NH * FIN;
  if (idx < K * FOUT) {
    int k = idx / FOUT, o = idx - k * FOUT;
    int h = k / FIN, f = k - h * FIN;
    float v = W[(size_t)(f * NH + h) * FOUT + o] * (1.0f / NH);
    unsigned short hb = bfhi(v);
    unsigned short lb = bfhi(v - bff(hb));
    bth[(size_t)o * K + k] = hb;
    btl[(size_t)o * K + k] = lb;
  }
  if (idx < NH * FIN) {
    int h = idx / FIN, f = idx - h * FIN;
    const float* wr = W + (size_t)(f * NH + h) * FOUT;
    const float* as = aS + h * FOUT;
    const float* ad = aD + h * FOUT;
    float ss = 0.f, dd = 0.f;
    for (int o = 0; o < FOUT; ++o) { float w = wr[o]; ss += w * as[o]; dd += w * ad[o]; }
    uS[idx] = ss; uD[idx] = dd;
  }
}

// ---------- CSR build: one WG per graph; packed (src,ew) int2; dst-tiled scatter ----------
__global__ __launch_bounds__(256)
void csr_kernel(const int* __restrict__ ei1, const int* __restrict__ ei2,
                const float* __restrict__ ew1, const float* __restrict__ ew2,
                int* __restrict__ row_ptr, int2* __restrict__ edges) {
  __shared__ int cnt[NN];
  __shared__ int part[256];
  int gi = blockIdx.x, t = threadIdx.x;
  int tt = gi >> 1, s = gi & 1;
  const int* ei = s ? ei2 : ei1;
  const float* ew = s ? ew2 : ew1;
  const int* srcp = ei + (size_t)(tt * 2) * NE;
  const int* dstp = ei + (size_t)(tt * 2 + 1) * NE;
  const float* ewp = ew + (size_t)tt * NE;
  for (int i = t; i < NN; i += 256) cnt[i] = 0;
  __syncthreads();
  for (int e = t; e < NE; e += 256) atomicAdd(&cnt[dstp[e]], 1);
  __syncthreads();
  int loc[8]; int run = 0;
  for (int i = 0; i < 8; ++i) { loc[i] = run; run += cnt[t * 8 + i]; }
  part[t] = run;
  __syncthreads();
  if (t == 0) { int acc = 0; for (int i = 0; i < 256; ++i) { int v = part[i]; part[i] = acc; acc += v; } }
  __syncthreads();
  int o = part[t];
  int* rp = row_ptr + (size_t)gi * (NN + 1);
  for (int i = 0; i < 8; ++i) { rp[t * 8 + i] = o + loc[i]; cnt[t * 8 + i] = o + loc[i]; }
  if (t == 255) rp[NN] = o + run;
  __syncthreads();
  int2* ed = edges + (size_t)gi * NE;
  // 4 passes over dst ranges of 512: writes land in a compact window -> no write amp
  #pragma unroll 1
  for (int tile = 0; tile < 4; ++tile) {
    int lo = tile << 9, hi = lo + 512;
    for (int e = t; e < NE; e += 256) {
      int d = dstp[e];
      if (d >= lo && d < hi) {
        int pos = atomicAdd(&cnt[d], 1);
        ed[pos] = make_int2(srcp[e], __float_as_int(ewp[e]));
      }
    }
  }
}

// ---------- stage x into h_ping + layer-0 s/d logits ----------
__global__ __launch_bounds__(256)
void copyx_sd0_kernel(const float* __restrict__ x1, const float* __restrict__ x2,
                      const float* __restrict__ uS0, const float* __restrict__ uD0,
                      float* __restrict__ hping, float* __restrict__ sdv, int c0) {
  __shared__ float uL[48];
  int t = threadIdx.x;
  if (t < 24) uL[t] = uS0[t];
  else if (t < 48) uL[t] = uD0[t - 24];
  __syncthreads();
  int nodeg = blockIdx.x * 256 + t;
  int gl = nodeg >> 11, n = nodeg & (NN - 1);
  int gi = c0 + gl;
  int tt = gi >> 1, s = gi & 1;
  const float* x = s ? x2 : x1;
  float4 xv = *(const float4*)(x + ((size_t)tt * NN + n) * 4);
  *(float4*)(hping + (size_t)nodeg * 4) = xv;
  float* sd = sdv + (size_t)nodeg * 12;
  #pragma unroll
  for (int j = 0; j < 12; ++j) {
    const float* u = uL + (j < 6 ? j * 4 : 24 + (j - 6) * 4);
    sd[j] = xv.x * u[0] + xv.y * u[1] + xv.z * u[2] + xv.w * u[3];
  }
}

// ---------- layer-0 fused softmax+aggregate (FIN=4, recompute path) ----------
__global__ __launch_bounds__(256)
void agg0_kernel(const float* __restrict__ h, const float* __restrict__ sdv,
                 const int* __restrict__ row_ptr, const int2* __restrict__ edges,
                 float* __restrict__ agg, int c0, int sw) {
  const int NPB = 64, IL = 4, BPG = NN / (NPB * IL);   // 8
  __shared__ float mL[NPB * 6], ivL[NPB * 6];
  int t = threadIdx.x, blk = blockIdx.x;
  int gl, nb;
  if (sw) { int xcd = blk & 7, q = blk >> 3; gl = xcd + ((q / BPG) << 3); nb = q % BPG; }
  else    { gl = blk / BPG; nb = blk % BPG; }
  int gi = c0 + gl;
  const int* rpg = row_ptr + (size_t)gi * (NN + 1);
  const int2* eg = edges + (size_t)gi * NE;
  const float* sdg = sdv + (size_t)gl * NN * 12;
  const float* hb = h + (size_t)gl * NN * 4;
  float* aggb = agg + (size_t)gl * NN * 24;
  for (int it = 0; it < IL; ++it) {
    __syncthreads();
    int n0 = nb * (NPB * IL) + it * NPB;
    for (int pid = t; pid < NPB * 6; pid += 256) {
      int nl = pid / 6, j = pid - nl * 6;
      int n = n0 + nl;
      int rp = rpg[n], re = rpg[n + 1];
      float d = sdg[n * 12 + 6 + j];
      float m = -INFINITY;
      for (int e = rp; e < re; ++e) m = fmaxf(m, lrelu(sdg[eg[e].x * 12 + j] + d));
      float den = 0.f;
      for (int e = rp; e < re; ++e) den += expf(lrelu(sdg[eg[e].x * 12 + j] + d) - m);
      mL[pid] = m; ivL[pid] = 1.f / (den + 1e-16f);
    }
    __syncthreads();
    int nl = t >> 2, f = t & 3;
    int n = n0 + nl;
    int rp = rpg[n], re = rpg[n + 1];
    float dj[6], mj[6], ij[6];
    #pragma unroll
    for (int j = 0; j < 6; ++j) { dj[j] = sdg[n * 12 + 6 + j]; mj[j] = mL[nl * 6 + j]; ij[j] = ivL[nl * 6 + j]; }
    float acc[6] = {0.f, 0.f, 0.f, 0.f, 0.f, 0.f};
    for (int e = rp; e < re; ++e) {
      int2 p = eg[e];
      float wh = __int_as_float(p.y) * hb[(size_t)p.x * 4 + f];
      const float* srow = sdg + (size_t)p.x * 12;
      #pragma unroll
      for (int j = 0; j < 6; ++j) acc[j] += expf(lrelu(srow[j] + dj[j]) - mj[j]) * ij[j] * wh;
    }
    float* ar = aggb + (size_t)n * 24;
    #pragma unroll
    for (int j = 0; j < 6; ++j) ar[j * 4 + f] = acc[j];
  }
}

// ---------- fused softmax+aggregate, LDS-cached alpha (FIN=64/128) ----------
template<int FIN, int PT>
__global__ __launch_bounds__(256)
void aggc_kernel(const float* __restrict__ h, const float* __restrict__ sdv,
                 const int* __restrict__ row_ptr, const int2* __restrict__ edges,
                 float* __restrict__ agg, int c0, int sw) {
  const int TPN = FIN / 2;           // threads per node (float2)
  const int NPB = 256 / TPN;
  const int IL = 4;
  const int BPG = NN / (NPB * IL);
  const int CAP = 80;
  __shared__ float awL[NPB][CAP][6];
  __shared__ float mL[NPB * 6], ivL[NPB * 6];
  int t = threadIdx.x, blk = blockIdx.x;
  int gl, nb;
  if (sw) { int xcd = blk & 7, q = blk >> 3; gl = xcd + ((q / BPG) << 3); nb = q % BPG; }
  else    { gl = blk / BPG; nb = blk % BPG; }
  int gi = c0 + gl;
  const int* rpg = row_ptr + (size_t)gi * (NN + 1);
  const int2* eg = edges + (size_t)gi * NE;
  const float* sdg = sdv + (size_t)gl * NN * 12;
  const float2* hb2 = (const float2*)(h + (size_t)gl * NN * FIN);
  float* aggb = agg + (size_t)gl * NN * (6 * FIN);
  for (int it = 0; it < IL; ++it) {
    __syncthreads();
    int n0 = nb * (NPB * IL) + it * NPB;
    int pid = t / PT, sub = t % PT;
    if (pid < NPB * 6) {
      int nl = pid / 6, j = pid - nl * 6;
      int n = n0 + nl;
      int rp = rpg[n], re = rpg[n + 1];
      float d = sdg[n * 12 + 6 + j];
      float m = -INFINITY;
      for (int e = rp + sub; e < re; e += PT) m = fmaxf(m, lrelu(sdg[eg[e].x * 12 + j] + d));
      #pragma unroll
      for (int msk = PT >> 1; msk; msk >>= 1) m = fmaxf(m, __shfl_xor(m, msk, PT));
      float den = 0.f;
      for (int e = rp + sub; e < re; e += PT) den += expf(lrelu(sdg[eg[e].x * 12 + j] + d) - m);
      #pragma unroll
      for (int msk = PT >> 1; msk; msk >>= 1) den += __shfl_xor(den, msk, PT);
      float iv = 1.f / (den + 1e-16f);
      for (int e = rp + sub; e < re; e += PT) {
        int idx = e - rp;
        if (idx < CAP) {
          int2 p = eg[e];
          awL[nl][idx][j] = expf(lrelu(sdg[p.x * 12 + j] + d) - m) * iv * __int_as_float(p.y);
        }
      }
      if (sub == 0) { mL[pid] = m; ivL[pid] = iv; }
    }
    __syncthreads();
    int nl = t / TPN, f2 = t % TPN;
    int n = n0 + nl;
    int rp = rpg[n], re = rpg[n + 1];
    float2 acc[6];
    #pragma unroll
    for (int j = 0; j < 6; ++j) acc[j] = make_float2(0.f, 0.f);
    if (re - rp <= CAP) {
      for (int e = rp; e < re; ++e) {
        int idx = e - rp, sct = eg[e].x;
        float2 hv = hb2[(size_t)sct * TPN + f2];
        #pragma unroll
        for (int j = 0; j < 6; ++j) { float a = awL[nl][idx][j]; acc[j].x += a * hv.x; acc[j].y += a * hv.y; }
      }
    } else {
      float dj[6], mj[6], ij[6];
      #pragma unroll
      for (int j = 0; j < 6; ++j) { dj[j] = sdg[n * 12 + 6 + j]; mj[j] = mL[nl * 6 + j]; ij[j] = ivL[nl * 6 + j]; }
      for (int e = rp; e < re; ++e) {
        int idx = e - rp;
        int2 p = eg[e];
        float2 hv = hb2[(size_t)p.x * TPN + f2];
        if (idx < CAP) {
          #pragma unroll
          for (int j = 0; j < 6; ++j) { float a = awL[nl][idx][j]; acc[j].x += a * hv.x; acc[j].y += a * hv.y; }
        } else {
          float w = __int_as_float(p.y);
          const float* srow = sdg + (size_t)p.x * 12;
          #pragma unroll
          for (int j = 0; j < 6; ++j) {
            float a = expf(lrelu(srow[j] + dj[j]) - mj[j]) * ij[j] * w;
            acc[j].x += a * hv.x; acc[j].y += a * hv.y;
          }
        }
      }
    }
    float2* ar = (float2*)(aggb + (size_t)n * (6 * FIN));
    #pragma unroll
    for (int j = 0; j < 6; ++j) ar[j * TPN + f2] = acc[j];
  }
}

// ---------- MFMA GEMM (bf16 hi/lo split) + fused epilogue; LDS overlay ----------
// EPI: 1 = write C + next-layer s/d logits; 2 = readout only (no C write)
template<int BN, int MF, int NF, int WMC, int WCC, int EPI>
__global__ __launch_bounds__(256)
void gemm_mfma_kernel(const float* __restrict__ A,
                      const unsigned short* __restrict__ Bth,
                      const unsigned short* __restrict__ Btl,
                      const float* __restrict__ bias, float* __restrict__ C,
                      int K, int act, int sw,
                      const float* __restrict__ uSn, const float* __restrict__ uDn,
                      float* __restrict__ sdv,
                      const float* __restrict__ xn1, const float* __restrict__ xn2,
                      float* __restrict__ seqv, int c0) {
  static_assert(BN == WCC * NF * 16 && 64 == WMC * MF * 16, "tile mismatch");
  constexpr int STG_B = (2048 + 2048 + BN * 32 + BN * 32) * 2;                  // ushorts
  constexpr int EPI_B = (64 * (BN + 1) + 12 * (BN + 1) + 64 + 256) * 4;         // floats
  constexpr int SMEM_B = STG_B > EPI_B ? STG_B : EPI_B;
  __shared__ __align__(16) char smem[SMEM_B];
  unsigned short* AhL = (unsigned short*)smem;        // 64x32
  unsigned short* AlL = AhL + 2048;
  unsigned short* BhL = AlL + 2048;                   // BNx32
  unsigned short* BlL = BhL + BN * 32;
  float* CT  = (float*)smem;                          // [64][BN+1] (epilogue overlay)
  float* uL  = CT + 64 * (BN + 1);
  float* xnL = uL + 12 * (BN + 1);
  float* red = xnL + 64;
  int t = threadIdx.x;
  int lane = t & 63, wv = t >> 6;
  int wm = wv % WMC, wc = wv / WMC;
  int l15 = lane & 15, lq = lane >> 4;
  int blk = blockIdx.x;
  const int BPG = NN / 64;
  int m0;
  if (sw) { int xcd = blk & 7, q = blk >> 3; int gl = xcd + ((q / BPG) << 3); int nb = q % BPG; m0 = gl * NN + nb * 64; }
  else    m0 = blk * 64;
  f32x4 acc[MF][NF];
  #pragma unroll
  for (int i = 0; i < MF; ++i)
    #pragma unroll
    for (int j = 0; j < NF; ++j) { f32x4 z = {0.f, 0.f, 0.f, 0.f}; acc[i][j] = z; }

  for (int k0 = 0; k0 < K; k0 += 32) {
    __syncthreads();
    #pragma unroll
    for (int i = 0; i < 2; ++i) {
      int q = t + i * 256;
      int row = q >> 3, c4 = q & 7;
      float4 av = make_float4(0.f, 0.f, 0.f, 0.f);
      int k = k0 + c4 * 4;
      if (k < K) av = *(const float4*)(A + (size_t)(m0 + row) * K + k);
      unsigned short h0 = bfhi(av.x), h1 = bfhi(av.y), h2 = bfhi(av.z), h3 = bfhi(av.w);
      unsigned short g0 = bfhi(av.x - bff(h0)), g1 = bfhi(av.y - bff(h1));
      unsigned short g2 = bfhi(av.z - bff(h2)), g3 = bfhi(av.w - bff(h3));
      int pos = row * 32 + (((c4 >> 1) ^ ((row >> 1) & 3)) << 3) + ((c4 & 1) << 2);
      *(ushort4*)&AhL[pos] = make_ushort4(h0, h1, h2, h3);
      *(ushort4*)&AlL[pos] = make_ushort4(g0, g1, g2, g3);
    }
    #pragma unroll
    for (int i = 0; i < BN / 64; ++i) {
      int q = t + i * 256;
      int n = q >> 2, c = q & 3;
      uint4 vh = make_uint4(0, 0, 0, 0), vl = make_uint4(0, 0, 0, 0);
      int k = k0 + c * 8;
      if (k < K) {
        vh = *(const uint4*)(Bth + (size_t)n * K + k);
        vl = *(const uint4*)(Btl + (size_t)n * K + k);
      }
      int pos = n * 32 + ((c ^ ((n >> 1) & 3)) << 3);
      *(uint4*)&BhL[pos] = vh;
      *(uint4*)&BlL[pos] = vl;
    }
    __syncthreads();
    bf16x8 ah[MF], al[MF], bh[NF], bl[NF];
    #pragma unroll
    for (int fr = 0; fr < MF; ++fr) {
      int row = wm * MF * 16 + fr * 16 + l15;
      int p = row * 32 + ((lq ^ ((row >> 1) & 3)) << 3);
      ah[fr] = *(const bf16x8*)&AhL[p];
      al[fr] = *(const bf16x8*)&AlL[p];
    }
    #pragma unroll
    for (int fc = 0; fc < NF; ++fc) {
      int row = wc * NF * 16 + fc * 16 + l15;
      int p = row * 32 + ((lq ^ ((row >> 1) & 3)) << 3);
      bh[fc] = *(const bf16x8*)&BhL[p];
      bl[fc] = *(const bf16x8*)&BlL[p];
    }
    #pragma unroll
    for (int fr = 0; fr < MF; ++fr)
      #pragma unroll
      for (int fc = 0; fc < NF; ++fc) {
        acc[fr][fc] = __builtin_amdgcn_mfma_f32_16x16x32_bf16(ah[fr], bh[fc], acc[fr][fc], 0, 0, 0);
        acc[fr][fc] = __builtin_amdgcn_mfma_f32_16x16x32_bf16(ah[fr], bl[fc], acc[fr][fc], 0, 0, 0);
        acc[fr][fc] = __builtin_amdgcn_mfma_f32_16x16x32_bf16(al[fr], bh[fc], acc[fr][fc], 0, 0, 0);
      }
  }
  __syncthreads();   // staging reads done; safe to overlay CT
  #pragma unroll
  for (int fr = 0; fr < MF; ++fr) {
    int rl0 = wm * MF * 16 + fr * 16 + lq * 4;
    #pragma unroll
    for (int fc = 0; fc < NF; ++fc) {
      int col = wc * NF * 16 + fc * 16 + l15;
      float bv = bias[col];
      #pragma unroll
      for (int r = 0; r < 4; ++r) {
        float v = acc[fr][fc][r] + bv;
        if (act) v = eluf(v);
        if (EPI != 2) C[(size_t)(m0 + rl0 + r) * BN + col] = v;
        CT[(rl0 + r) * (BN + 1) + col] = v;
      }
    }
  }
  __syncthreads();
  if (EPI == 1) {
    for (int idx = t; idx < 12 * BN; idx += 256) {
      int j = idx / BN, f = idx - j * BN;
      uL[j * (BN + 1) + f] = (j < 6) ? uSn[j * BN + f] : uDn[(j - 6) * BN + f];
    }
    __syncthreads();
    for (int o = t; o < 64 * 12; o += 256) {
      int rl = o / 12, j = o - rl * 12;
      const float* ur = uL + j * (BN + 1);
      const float* cr = CT + rl * (BN + 1);
      float a = 0.f;
      for (int f = 0; f < BN; ++f) a += cr[f] * ur[f];
      sdv[(size_t)(m0 + rl) * 12 + j] = a;
    }
  } else {
    int gl = m0 >> 11;
    int gi = c0 + gl;
    int tt = gi >> 1, ss = gi & 1;
    const float* xn = (ss ? xn2 : xn1) + (size_t)tt * NN;
    int nl0 = m0 & (NN - 1);
    if (t < 64) xnL[t] = xn[nl0 + t];
    __syncthreads();
    int d = t & 63, q = t >> 6;
    float a = 0.f;
    #pragma unroll
    for (int i = 0; i < 16; ++i) a += xnL[q * 16 + i] * CT[(q * 16 + i) * (BN + 1) + d];
    red[t] = a;
    __syncthreads();
    if (t < 64)
      atomicAdd(&seqv[tt * 128 + ss * 64 + t], red[t] + red[t + 64] + red[t + 128] + red[t + 192]);
  }
}

// ---------- GRU + MLP head: all weights in LDS ----------
__global__ __launch_bounds__(256)
void gru_head_kernel(const float* __restrict__ seq, const float* __restrict__ Wih,
                     const float* __restrict__ Whh, const float* __restrict__ bih,
                     const float* __restrict__ bhh, const float* __restrict__ Wc1,
                     const float* __restrict__ bc1, const float* __restrict__ Wc2,
                     const float* __restrict__ bc2, float* __restrict__ out) {
  __shared__ float seqs[TS * 128];
  __shared__ float WihT[128 * 96];
  __shared__ float WhhT[32 * 96];
  __shared__ float giAll[TS * 96];
  __shared__ float rnnS[TS * 32];
  __shared__ float Wc1L[32 * 16];
  __shared__ float Wc2L[16 * 3];
  __shared__ float bihL[96], bhhL[96], bc1L[16], bc2L[3];
  __shared__ float ghs[96], hs[32];
  int t = threadIdx.x;
  for (int idx = t; idx < TS * 128; idx += 256) seqs[idx] = seq[idx];
  for (int idx = t; idx < 96 * 128; idx += 256) { int j = idx >> 7, k = idx & 127; WihT[k * 96 + j] = Wih[idx]; }
  for (int idx = t; idx < 96 * 32; idx += 256) { int j = idx >> 5, k = idx & 31; WhhT[k * 96 + j] = Whh[idx]; }
  for (int idx = t; idx < 512; idx += 256) Wc1L[idx] = Wc1[idx];
  if (t < 48) Wc2L[t] = Wc2[t];
  if (t < 96) { bihL[t] = bih[t]; bhhL[t] = bhh[t]; }
  if (t >= 96 && t < 112) bc1L[t - 96] = bc1[t - 96];
  if (t >= 112 && t < 115) bc2L[t - 112] = bc2[t - 112];
  if (t < 32) hs[t] = 0.f;
  __syncthreads();
  for (int o = t; o < TS * 96; o += 256) {
    int tt = o / 96, j = o - tt * 96;
    float a = bihL[j];
    const float* xr = seqs + tt * 128;
    #pragma unroll 4
    for (int k = 0; k < 128; ++k) a += WihT[k * 96 + j] * xr[k];
    giAll[o] = a;
  }
  __syncthreads();
  for (int tt = 0; tt < TS; ++tt) {
    if (t < 96) {
      float b = bhhL[t];
      #pragma unroll
      for (int k = 0; k < 32; ++k) b += WhhT[k * 96 + t] * hs[k];
      ghs[t] = b;
    }
    __syncthreads();
    if (t < 32) {
      const float* gi = giAll + tt * 96;
      float r = sigm(gi[t] + ghs[t]);
      float z = sigm(gi[32 + t] + ghs[32 + t]);
      float nv = tanhf(gi[64 + t] + r * ghs[64 + t]);
      float h2 = (1.f - z) * nv + z * hs[t];
      hs[t] = h2;
      rnnS[tt * 32 + t] = h2;
    }
    __syncthreads();
  }
  for (int o = t; o < TS * 3; o += 256) {
    int tt = o / 3, c = o - tt * 3;
    float accv = bc2L[c];
    #pragma unroll
    for (int m = 0; m < 16; ++m) {
      float hv = bc1L[m];
      #pragma unroll
      for (int k = 0; k < 32; ++k) hv += rnnS[tt * 32 + k] * Wc1L[k * 16 + m];
      hv = fmaxf(hv, 0.f);
      accv += hv * Wc2L[m * 3 + c];
    }
    out[o] = accv;
  }
}

static inline size_t alignup(size_t x) { return (x + 255) & ~(size_t)255; }

extern "C" void kernel_launch(void* const* d_in, const int* in_sizes, int n_in,
                              void* d_out, int out_size, void* d_ws, size_t ws_size,
                              hipStream_t stream) {
  const float* x1  = (const float*)d_in[0];
  const float* x2  = (const float*)d_in[1];
  const int*   ei1 = (const int*)d_in[2];
  const int*   ei2 = (const int*)d_in[3];
  const float* ew1 = (const float*)d_in[4];
  const float* ew2 = (const float*)d_in[5];
  const float* xn1 = (const float*)d_in[6];
  const float* xn2 = (const float*)d_in[7];
  const float* Wih = (const float*)d_in[25];
  const float* Whh = (const float*)d_in[26];
  const float* bih = (const float*)d_in[27];
  const float* bhh = (const float*)d_in[28];
  const float* Wc1 = (const float*)d_in[29];
  const float* bc1 = (const float*)d_in[30];
  const float* Wc2 = (const float*)d_in[31];
  const float* bc2 = (const float*)d_in[32];
  float* out = (float*)d_out;

  const int FINs[4]  = {4, 128, 128, 64};
  const int FOUTs[4] = {128, 128, 64, 64};
  const size_t uoffs[4] = {0, 24, 792, 1560};
  const size_t woffs[4] = {0, 3072, 101376, 150528};

  size_t off = 0;
  auto take = [&](size_t bytes) -> size_t { size_t o = off; off += alignup(bytes); return o; };
  size_t o_rowptr = take((size_t)NB * (NN + 1) * sizeof(int));
  size_t o_edges  = take((size_t)NB * NE * sizeof(int2));
  size_t o_uS     = take(1944 * sizeof(float));
  size_t o_uD     = take(1944 * sizeof(float));
  size_t o_bth    = take(175104 * sizeof(unsigned short));
  size_t o_btl    = take(175104 * sizeof(unsigned short));
  size_t o_seq    = take((size_t)TS * 128 * sizeof(float));
  size_t persistent = off;

  int G = 8;
  const int cand[4] = {64, 32, 16, 8};
  for (int ci = 0; ci < 4; ++ci) {
    int g = cand[ci];
    size_t need = persistent
                + 2 * alignup((size_t)g * NN * 128 * sizeof(float))
                + alignup((size_t)g * NN * 12 * sizeof(float))
                + alignup((size_t)g * NN * 768 * sizeof(float));
    if (need <= ws_size) { G = g; break; }
  }
  size_t o_hping = take((size_t)G * NN * 128 * sizeof(float));
  size_t o_hpong = take((size_t)G * NN * 128 * sizeof(float));
  size_t o_sd    = take((size_t)G * NN * 12 * sizeof(float));
  size_t o_agg   = take((size_t)G * NN * 768 * sizeof(float));
  int sw = ((G & 7) == 0) ? 1 : 0;

  char* ws = (char*)d_ws;
  int*   row_ptr = (int*)(ws + o_rowptr);
  int2*  edges   = (int2*)(ws + o_edges);
  float* uS   = (float*)(ws + o_uS);
  float* uD   = (float*)(ws + o_uD);
  unsigned short* bth = (unsigned short*)(ws + o_bth);
  unsigned short* btl = (unsigned short*)(ws + o_btl);
  float* seq  = (float*)(ws + o_seq);
  float* h_ping = (float*)(ws + o_hping);
  float* h_pong = (float*)(ws + o_hpong);
  float* sdbuf  = (float*)(ws + o_sd);
  float* aggbuf = (float*)(ws + o_agg);

  for (int l = 0; l < 4; ++l) {
    const float* Wl  = (const float*)d_in[9 + 4 * l];
    const float* aSl = (const float*)d_in[10 + 4 * l];
    const float* aDl = (const float*)d_in[11 + 4 * l];
    int totw = NH * FINs[l] * FOUTs[l];
    prep_layer_kernel<<<(totw + 255) / 256, 256, 0, stream>>>(
        Wl, aSl, aDl, uS + uoffs[l], uD + uoffs[l],
        bth + woffs[l], btl + woffs[l], FINs[l], FOUTs[l]);
  }
  csr_kernel<<<NB, 256, 0, stream>>>(ei1, ei2, ew1, ew2, row_ptr, edges);
  hipMemsetAsync(seq, 0, (size_t)TS * 128 * sizeof(float), stream);

  for (int c0 = 0; c0 < NB; c0 += G) {
    int rows = G * NN;
    copyx_sd0_kernel<<<rows / 256, 256, 0, stream>>>(x1, x2, uS, uD, h_ping, sdbuf, c0);

    // layer 0: FIN=4 -> FOUT=128 (sd epilogue for layer 1)
    agg0_kernel<<<rows / 256, 256, 0, stream>>>(h_ping, sdbuf, row_ptr, edges,
                                                aggbuf, c0, sw);
    gemm_mfma_kernel<128, 2, 4, 2, 2, 1><<<rows / 64, 256, 0, stream>>>(
        aggbuf, bth + woffs[0], btl + woffs[0], (const float*)d_in[12], h_pong,
        24, 1, sw, uS + uoffs[1], uD + uoffs[1], sdbuf, nullptr, nullptr, nullptr, c0);

    // layer 1: FIN=128 -> FOUT=128 (sd epilogue for layer 2)
    aggc_kernel<128, 8><<<rows / 16, 256, 0, stream>>>(h_pong, sdbuf, row_ptr, edges,
                                                       aggbuf, c0, sw);
    gemm_mfma_kernel<128, 2, 4, 2, 2, 1><<<rows / 64, 256, 0, stream>>>(
        aggbuf, bth + woffs[1], btl + woffs[1], (const float*)d_in[16], h_ping,
        768, 1, sw, uS + uoffs[2], uD + uoffs[2], sdbuf, nullptr, nullptr, nullptr, c0);

    // layer 2: FIN=128 -> FOUT=64 (sd epilogue for layer 3)
    aggc_kernel<128, 8><<<rows / 16, 256, 0, stream>>>(h_ping, sdbuf, row_ptr, edges,
                                                       aggbuf, c0, sw);
    gemm_mfma_kernel<64, 1, 4, 4, 1, 1><<<rows / 64, 256, 0, stream>>>(
        aggbuf, bth + woffs[2], btl + woffs[2], (const float*)d_in[20], h_pong,
        768, 1, sw, uS + uoffs[3], uD + uoffs[3], sdbuf, nullptr, nullptr, nullptr, c0);

    // layer 3: FIN=64 -> FOUT=64, readout epilogue (no C write)
    aggc_kernel<64, 4><<<rows / 32, 256, 0, stream>>>(h_pong, sdbuf, row_ptr, edges,
                                                      aggbuf, c0, sw);
    gemm_mfma_kernel<64, 1, 4, 4, 1, 2><<<rows / 64, 256, 0, stream>>>(
        aggbuf, bth + woffs[3], btl + woffs[3], (const float*)d_in[24], nullptr,
        384, 0, sw, nullptr, nullptr, nullptr, xn1, xn2, seq, c0);
  }

  gru_head_kernel<<<1, 256, 0, stream>>>(seq, Wih, Whh, bih, bhh, Wc1, bc1, Wc2, bc2, out);
}

// Round 6
// 3317.297 us; speedup vs baseline: 3.8128x; 1.2832x over previous
//
#include <hip/hip_runtime.h>
#include <math.h>

#define TS 64
#define NN 2048
#define NE 32768
#define NH 6
#define NB 128   // 2*TS graph instances

typedef __attribute__((ext_vector_type(8))) __bf16 bf16x8;
typedef __attribute__((ext_vector_type(4))) float f32x4;

__device__ __forceinline__ float lrelu(float x){ return x >= 0.0f ? x : 0.2f*x; }
__device__ __forceinline__ float eluf(float x){ return x > 0.0f ? x : expm1f(x); }
__device__ __forceinline__ float sigm(float x){ return 1.0f/(1.0f+expf(-x)); }
__device__ __forceinline__ unsigned short bfhi(float x){ return (unsigned short)(__float_as_uint(x) >> 16); }
__device__ __forceinline__ float bff(unsigned short u){ return __uint_as_float(((unsigned int)u) << 16); }
__device__ __forceinline__ unsigned int packf(float v){
  unsigned short h = bfhi(v);
  unsigned short l = bfhi(v - bff(h));
  return (unsigned int)h | ((unsigned int)l << 16);
}

// ---------- per-layer prep: uS,uD [H*FIN]; B split+transposed bf16 hi/lo [N][K] ----------
__global__ void prep_layer_kernel(const float* __restrict__ W,
                                  const float* __restrict__ aS,
                                  const float* __restrict__ aD,
                                  float* __restrict__ uS, float* __restrict__ uD,
                                  unsigned short* __restrict__ bth,
                                  unsigned short* __restrict__ btl,
                                  int FIN, int FOUT) {
  int idx = blockIdx.x * blockDim.x + threadIdx.x;
  int K = NH * FIN;
  if (idx < K * FOUT) {
    int k = idx / FOUT, o = idx - k * FOUT;
    int h = k / FIN, f = k - h * FIN;
    float v = W[(size_t)(f * NH + h) * FOUT + o] * (1.0f / NH);
    unsigned short hb = bfhi(v);
    unsigned short lb = bfhi(v - bff(hb));
    bth[(size_t)o * K + k] = hb;
    btl[(size_t)o * K + k] = lb;
  }
  if (idx < NH * FIN) {
    int h = idx / FIN, f = idx - h * FIN;
    const float* wr = W + (size_t)(f * NH + h) * FOUT;
    const float* as = aS + h * FOUT;
    const float* ad = aD + h * FOUT;
    float ss = 0.f, dd = 0.f;
    for (int o = 0; o < FOUT; ++o) { float w = wr[o]; ss += w * as[o]; dd += w * ad[o]; }
    uS[idx] = ss; uD[idx] = dd;
  }
}

// ---------- CSR hist+scan: one WG per graph ----------
__global__ __launch_bounds__(256)
void csr_hist_kernel(const int* __restrict__ ei1, const int* __restrict__ ei2,
                     int* __restrict__ row_ptr) {
  __shared__ int cnt[NN];
  __shared__ int part[256];
  int gi = blockIdx.x, t = threadIdx.x;
  int tt = gi >> 1, s = gi & 1;
  const int* ei = s ? ei2 : ei1;
  const int* dstp = ei + (size_t)(tt * 2 + 1) * NE;
  for (int i = t; i < NN; i += 256) cnt[i] = 0;
  __syncthreads();
  for (int e = t; e < NE; e += 256) atomicAdd(&cnt[dstp[e]], 1);
  __syncthreads();
  int loc[8]; int run = 0;
  for (int i = 0; i < 8; ++i) { loc[i] = run; run += cnt[t * 8 + i]; }
  part[t] = run;
  __syncthreads();
  if (t == 0) { int acc = 0; for (int i = 0; i < 256; ++i) { int v = part[i]; part[i] = acc; acc += v; } }
  __syncthreads();
  int o = part[t];
  int* rp = row_ptr + (size_t)gi * (NN + 1);
  for (int i = 0; i < 8; ++i) rp[t * 8 + i] = o + loc[i];
  if (t == 255) rp[NN] = o + run;
}

// ---------- CSR scatter: 8 blocks/graph, each owns a 256-node dst range ----------
// blk = r*NB + g  ->  XCD(blk%8) = g%8: all ranges of a graph share one XCD's L2
__global__ __launch_bounds__(256)
void csr_scatter_kernel(const int* __restrict__ ei1, const int* __restrict__ ei2,
                        const float* __restrict__ ew1, const float* __restrict__ ew2,
                        const int* __restrict__ row_ptr, int2* __restrict__ edges) {
  __shared__ int cur[256];
  int blk = blockIdx.x, t = threadIdx.x;
  int g = blk & (NB - 1), r = blk >> 7;
  int tt = g >> 1, s = g & 1;
  const int* ei = s ? ei2 : ei1;
  const float* ew = s ? ew2 : ew1;
  const int* srcp = ei + (size_t)(tt * 2) * NE;
  const int* dstp = ei + (size_t)(tt * 2 + 1) * NE;
  const float* ewp = ew + (size_t)tt * NE;
  int lo = r << 8;
  cur[t] = row_ptr[(size_t)g * (NN + 1) + lo + t];
  __syncthreads();
  int2* ed = edges + (size_t)g * NE;
  for (int e = t; e < NE; e += 256) {
    int d = dstp[e];
    if ((d >> 8) == r) {
      int pos = atomicAdd(&cur[d & 255], 1);
      ed[pos] = make_int2(srcp[e], __float_as_int(ewp[e]));
    }
  }
}

// ---------- stage x into h_ping + layer-0 s/d logits ----------
__global__ __launch_bounds__(256)
void copyx_sd0_kernel(const float* __restrict__ x1, const float* __restrict__ x2,
                      const float* __restrict__ uS0, const float* __restrict__ uD0,
                      float* __restrict__ hping, float* __restrict__ sdv, int c0) {
  __shared__ float uL[48];
  int t = threadIdx.x;
  if (t < 24) uL[t] = uS0[t];
  else if (t < 48) uL[t] = uD0[t - 24];
  __syncthreads();
  int nodeg = blockIdx.x * 256 + t;
  int gl = nodeg >> 11, n = nodeg & (NN - 1);
  int gi = c0 + gl;
  int tt = gi >> 1, s = gi & 1;
  const float* x = s ? x2 : x1;
  float4 xv = *(const float4*)(x + ((size_t)tt * NN + n) * 4);
  *(float4*)(hping + (size_t)nodeg * 4) = xv;
  float* sd = sdv + (size_t)nodeg * 12;
  #pragma unroll
  for (int j = 0; j < 12; ++j) {
    const float* u = uL + (j < 6 ? j * 4 : 24 + (j - 6) * 4);
    sd[j] = xv.x * u[0] + xv.y * u[1] + xv.z * u[2] + xv.w * u[3];
  }
}

// ---------- layer-0 softmax+aggregate (FIN=4): max pass + fused exp/den/acc ----------
__global__ __launch_bounds__(256)
void agg0_kernel(const float* __restrict__ h, const float* __restrict__ sdv,
                 const int* __restrict__ row_ptr, const int2* __restrict__ edges,
                 unsigned int* __restrict__ agg, int c0, int sw) {
  const int NPB = 64, IL = 4, BPG = NN / (NPB * IL);   // 8
  __shared__ float mLs[NPB * 6];
  int t = threadIdx.x, blk = blockIdx.x;
  int gl, nb;
  if (sw) { int xcd = blk & 7, q = blk >> 3; gl = xcd + ((q / BPG) << 3); nb = q % BPG; }
  else    { gl = blk / BPG; nb = blk % BPG; }
  int gi = c0 + gl;
  const int* rpg = row_ptr + (size_t)gi * (NN + 1);
  const int2* eg = edges + (size_t)gi * NE;
  const float* sdg = sdv + (size_t)gl * NN * 12;
  const float* hb = h + (size_t)gl * NN * 4;
  unsigned int* aggb = agg + (size_t)gl * NN * 24;
  for (int it = 0; it < IL; ++it) {
    __syncthreads();
    int n0 = nb * (NPB * IL) + it * NPB;
    for (int pid = t; pid < NPB * 6; pid += 256) {
      int nl = pid / 6, j = pid - nl * 6;
      int n = n0 + nl;
      int rp = rpg[n], re = rpg[n + 1];
      float d = sdg[n * 12 + 6 + j];
      float m = -INFINITY;
      for (int e = rp; e < re; ++e) m = fmaxf(m, lrelu(sdg[eg[e].x * 12 + j] + d));
      mLs[pid] = m;
    }
    __syncthreads();
    int nl = t >> 2, f = t & 3;
    int n = n0 + nl;
    int rp = rpg[n], re = rpg[n + 1];
    float dj[6], mj[6];
    #pragma unroll
    for (int j = 0; j < 6; ++j) { dj[j] = sdg[n * 12 + 6 + j]; mj[j] = mLs[nl * 6 + j]; }
    float acc[6] = {0.f,0.f,0.f,0.f,0.f,0.f};
    float den[6] = {0.f,0.f,0.f,0.f,0.f,0.f};
    for (int e = rp; e < re; ++e) {
      int2 p = eg[e];
      float w = __int_as_float(p.y);
      float hv = hb[(size_t)p.x * 4 + f];
      float wh = w * hv;
      const float* srow = sdg + (size_t)p.x * 12;
      #pragma unroll
      for (int j = 0; j < 6; ++j) {
        float ex = expf(lrelu(srow[j] + dj[j]) - mj[j]);
        den[j] += ex;
        acc[j] += ex * wh;
      }
    }
    unsigned int* ar = aggb + (size_t)n * 24;
    #pragma unroll
    for (int j = 0; j < 6; ++j) ar[j * 4 + f] = packf(acc[j] / (den[j] + 1e-16f));
  }
}

// ---------- softmax+aggregate (FIN=64/128): cached unnorm alpha, end-normalize ----------
template<int FIN, int PT>
__global__ __launch_bounds__(256)
void aggc_kernel(const float* __restrict__ h, const float* __restrict__ sdv,
                 const int* __restrict__ row_ptr, const int2* __restrict__ edges,
                 unsigned int* __restrict__ agg, int c0, int sw) {
  const int TPN = FIN / 4;           // float4 lanes per node
  const int NPB = 256 / TPN;
  const int IL = 4;
  const int BPG = NN / (NPB * IL);
  const int CAP = 80;
  __shared__ float awL[NPB][CAP][6];
  __shared__ int   srcL[NPB][CAP];
  __shared__ float mLs[NPB * 6], ivLs[NPB * 6];
  int t = threadIdx.x, blk = blockIdx.x;
  int gl, nb;
  if (sw) { int xcd = blk & 7, q = blk >> 3; gl = xcd + ((q / BPG) << 3); nb = q % BPG; }
  else    { gl = blk / BPG; nb = blk % BPG; }
  int gi = c0 + gl;
  const int* rpg = row_ptr + (size_t)gi * (NN + 1);
  const int2* eg = edges + (size_t)gi * NE;
  const float* sdg = sdv + (size_t)gl * NN * 12;
  const float4* hb4 = (const float4*)(h + (size_t)gl * NN * FIN);
  unsigned int* aggb = agg + (size_t)gl * NN * (6 * FIN);
  for (int it = 0; it < IL; ++it) {
    __syncthreads();
    int n0 = nb * (NPB * IL) + it * NPB;
    // phase 1: per (node,head) max; exp pass caching unnormalized ex*ew + src; den reduce
    int pid = t / PT, sub = t % PT;
    if (pid < NPB * 6) {
      int nl = pid / 6, j = pid - nl * 6;
      int n = n0 + nl;
      int rp = rpg[n], re = rpg[n + 1];
      float d = sdg[n * 12 + 6 + j];
      float m = -INFINITY;
      for (int e = rp + sub; e < re; e += PT) m = fmaxf(m, lrelu(sdg[eg[e].x * 12 + j] + d));
      #pragma unroll
      for (int msk = PT >> 1; msk; msk >>= 1) m = fmaxf(m, __shfl_xor(m, msk, PT));
      float den = 0.f;
      for (int e = rp + sub; e < re; e += PT) {
        int2 p = eg[e];
        float ex = expf(lrelu(sdg[p.x * 12 + j] + d) - m);
        den += ex;
        int idx = e - rp;
        if (idx < CAP) {
          awL[nl][idx][j] = ex * __int_as_float(p.y);
          if (j == 0) srcL[nl][idx] = p.x;
        }
      }
      #pragma unroll
      for (int msk = PT >> 1; msk; msk >>= 1) den += __shfl_xor(den, msk, PT);
      if (sub == 0) { mLs[pid] = m; ivLs[pid] = 1.f / (den + 1e-16f); }
    }
    __syncthreads();
    // phase 2: gather h rows (float4/lane) weighted by cached alpha; scale at end
    int nl = t / TPN, f4 = t % TPN;
    int n = n0 + nl;
    int rp = rpg[n], re = rpg[n + 1];
    float4 acc[6];
    #pragma unroll
    for (int j = 0; j < 6; ++j) acc[j] = make_float4(0.f, 0.f, 0.f, 0.f);
    if (re - rp <= CAP) {
      for (int e = rp; e < re; ++e) {
        int idx = e - rp;
        int sct = srcL[nl][idx];
        float4 hv = hb4[(size_t)sct * TPN + f4];
        #pragma unroll
        for (int j = 0; j < 6; ++j) {
          float a = awL[nl][idx][j];
          acc[j].x += a * hv.x; acc[j].y += a * hv.y;
          acc[j].z += a * hv.z; acc[j].w += a * hv.w;
        }
      }
    } else {
      float dj[6], mj[6];
      #pragma unroll
      for (int j = 0; j < 6; ++j) { dj[j] = sdg[n * 12 + 6 + j]; mj[j] = mLs[nl * 6 + j]; }
      for (int e = rp; e < re; ++e) {
        int idx = e - rp;
        int2 p = eg[e];
        float4 hv = hb4[(size_t)p.x * TPN + f4];
        if (idx < CAP) {
          #pragma unroll
          for (int j = 0; j < 6; ++j) {
            float a = awL[nl][idx][j];
            acc[j].x += a * hv.x; acc[j].y += a * hv.y;
            acc[j].z += a * hv.z; acc[j].w += a * hv.w;
          }
        } else {
          float w = __int_as_float(p.y);
          const float* srow = sdg + (size_t)p.x * 12;
          #pragma unroll
          for (int j = 0; j < 6; ++j) {
            float a = expf(lrelu(srow[j] + dj[j]) - mj[j]) * w;
            acc[j].x += a * hv.x; acc[j].y += a * hv.y;
            acc[j].z += a * hv.z; acc[j].w += a * hv.w;
          }
        }
      }
    }
    unsigned int* ar = aggb + (size_t)n * (6 * FIN);
    #pragma unroll
    for (int j = 0; j < 6; ++j) {
      float iv = ivLs[nl * 6 + j];
      uint4 pk;
      pk.x = packf(acc[j].x * iv); pk.y = packf(acc[j].y * iv);
      pk.z = packf(acc[j].z * iv); pk.w = packf(acc[j].w * iv);
      *(uint4*)(ar + j * FIN + f4 * 4) = pk;
    }
  }
}

// ---------- MFMA GEMM (A pre-split packed bf16 hi|lo) + fused epilogue; LDS overlay ----------
// EPI: 1 = write C + next-layer s/d logits; 2 = readout only (no C write)
template<int BN, int MF, int NF, int WMC, int WCC, int EPI>
__global__ __launch_bounds__(256)
void gemm_mfma_kernel(const unsigned int* __restrict__ A,
                      const unsigned short* __restrict__ Bth,
                      const unsigned short* __restrict__ Btl,
                      const float* __restrict__ bias, float* __restrict__ C,
                      int K, int act, int sw,
                      const float* __restrict__ uSn, const float* __restrict__ uDn,
                      float* __restrict__ sdv,
                      const float* __restrict__ xn1, const float* __restrict__ xn2,
                      float* __restrict__ seqv, int c0) {
  static_assert(BN == WCC * NF * 16 && 64 == WMC * MF * 16, "tile mismatch");
  constexpr int STG_B = (2048 + 2048 + BN * 32 + BN * 32) * 2;
  constexpr int EPI_B = (64 * (BN + 1) + 12 * (BN + 1) + 64 + 256) * 4;
  constexpr int SMEM_B = STG_B > EPI_B ? STG_B : EPI_B;
  __shared__ __align__(16) char smem[SMEM_B];
  unsigned short* AhL = (unsigned short*)smem;
  unsigned short* AlL = AhL + 2048;
  unsigned short* BhL = AlL + 2048;
  unsigned short* BlL = BhL + BN * 32;
  float* CT  = (float*)smem;
  float* uL  = CT + 64 * (BN + 1);
  float* xnL = uL + 12 * (BN + 1);
  float* red = xnL + 64;
  int t = threadIdx.x;
  int lane = t & 63, wv = t >> 6;
  int wm = wv % WMC, wc = wv / WMC;
  int l15 = lane & 15, lq = lane >> 4;
  int blk = blockIdx.x;
  const int BPG = NN / 64;
  int m0;
  if (sw) { int xcd = blk & 7, q = blk >> 3; int gl = xcd + ((q / BPG) << 3); int nb = q % BPG; m0 = gl * NN + nb * 64; }
  else    m0 = blk * 64;
  f32x4 acc[MF][NF];
  #pragma unroll
  for (int i = 0; i < MF; ++i)
    #pragma unroll
    for (int j = 0; j < NF; ++j) { f32x4 z = {0.f, 0.f, 0.f, 0.f}; acc[i][j] = z; }

  for (int k0 = 0; k0 < K; k0 += 32) {
    __syncthreads();
    #pragma unroll
    for (int i = 0; i < 2; ++i) {
      int q = t + i * 256;
      int row = q >> 3, c4 = q & 7;
      uint4 av = make_uint4(0, 0, 0, 0);
      int k = k0 + c4 * 4;
      if (k < K) av = *(const uint4*)(A + (size_t)(m0 + row) * K + k);
      int pos = row * 32 + (((c4 >> 1) ^ ((row >> 1) & 3)) << 3) + ((c4 & 1) << 2);
      *(ushort4*)&AhL[pos] = make_ushort4(av.x & 0xffff, av.y & 0xffff, av.z & 0xffff, av.w & 0xffff);
      *(ushort4*)&AlL[pos] = make_ushort4(av.x >> 16, av.y >> 16, av.z >> 16, av.w >> 16);
    }
    #pragma unroll
    for (int i = 0; i < BN / 64; ++i) {
      int q = t + i * 256;
      int n = q >> 2, c = q & 3;
      uint4 vh = make_uint4(0, 0, 0, 0), vl = make_uint4(0, 0, 0, 0);
      int k = k0 + c * 8;
      if (k < K) {
        vh = *(const uint4*)(Bth + (size_t)n * K + k);
        vl = *(const uint4*)(Btl + (size_t)n * K + k);
      }
      int pos = n * 32 + ((c ^ ((n >> 1) & 3)) << 3);
      *(uint4*)&BhL[pos] = vh;
      *(uint4*)&BlL[pos] = vl;
    }
    __syncthreads();
    bf16x8 ah[MF], al[MF], bh[NF], bl[NF];
    #pragma unroll
    for (int fr = 0; fr < MF; ++fr) {
      int row = wm * MF * 16 + fr * 16 + l15;
      int p = row * 32 + ((lq ^ ((row >> 1) & 3)) << 3);
      ah[fr] = *(const bf16x8*)&AhL[p];
      al[fr] = *(const bf16x8*)&AlL[p];
    }
    #pragma unroll
    for (int fc = 0; fc < NF; ++fc) {
      int row = wc * NF * 16 + fc * 16 + l15;
      int p = row * 32 + ((lq ^ ((row >> 1) & 3)) << 3);
      bh[fc] = *(const bf16x8*)&BhL[p];
      bl[fc] = *(const bf16x8*)&BlL[p];
    }
    #pragma unroll
    for (int fr = 0; fr < MF; ++fr)
      #pragma unroll
      for (int fc = 0; fc < NF; ++fc) {
        acc[fr][fc] = __builtin_amdgcn_mfma_f32_16x16x32_bf16(ah[fr], bh[fc], acc[fr][fc], 0, 0, 0);
        acc[fr][fc] = __builtin_amdgcn_mfma_f32_16x16x32_bf16(ah[fr], bl[fc], acc[fr][fc], 0, 0, 0);
        acc[fr][fc] = __builtin_amdgcn_mfma_f32_16x16x32_bf16(al[fr], bh[fc], acc[fr][fc], 0, 0, 0);
      }
  }
  __syncthreads();
  #pragma unroll
  for (int fr = 0; fr < MF; ++fr) {
    int rl0 = wm * MF * 16 + fr * 16 + lq * 4;
    #pragma unroll
    for (int fc = 0; fc < NF; ++fc) {
      int col = wc * NF * 16 + fc * 16 + l15;
      float bv = bias[col];
      #pragma unroll
      for (int r = 0; r < 4; ++r) {
        float v = acc[fr][fc][r] + bv;
        if (act) v = eluf(v);
        if (EPI != 2) C[(size_t)(m0 + rl0 + r) * BN + col] = v;
        CT[(rl0 + r) * (BN + 1) + col] = v;
      }
    }
  }
  __syncthreads();
  if (EPI == 1) {
    for (int idx = t; idx < 12 * BN; idx += 256) {
      int j = idx / BN, f = idx - j * BN;
      uL[j * (BN + 1) + f] = (j < 6) ? uSn[j * BN + f] : uDn[(j - 6) * BN + f];
    }
    __syncthreads();
    for (int o = t; o < 64 * 12; o += 256) {
      int rl = o / 12, j = o - rl * 12;
      const float* ur = uL + j * (BN + 1);
      const float* cr = CT + rl * (BN + 1);
      float a = 0.f;
      for (int f = 0; f < BN; ++f) a += cr[f] * ur[f];
      sdv[(size_t)(m0 + rl) * 12 + j] = a;
    }
  } else {
    int gl = m0 >> 11;
    int gi = c0 + gl;
    int tt = gi >> 1, ss = gi & 1;
    const float* xn = (ss ? xn2 : xn1) + (size_t)tt * NN;
    int nl0 = m0 & (NN - 1);
    if (t < 64) xnL[t] = xn[nl0 + t];
    __syncthreads();
    int d = t & 63, q = t >> 6;
    float a = 0.f;
    #pragma unroll
    for (int i = 0; i < 16; ++i) a += xnL[q * 16 + i] * CT[(q * 16 + i) * (BN + 1) + d];
    red[t] = a;
    __syncthreads();
    if (t < 64)
      atomicAdd(&seqv[tt * 128 + ss * 64 + t], red[t] + red[t + 64] + red[t + 128] + red[t + 192]);
  }
}

// ---------- GRU + MLP head: all weights in LDS ----------
__global__ __launch_bounds__(256)
void gru_head_kernel(const float* __restrict__ seq, const float* __restrict__ Wih,
                     const float* __restrict__ Whh, const float* __restrict__ bih,
                     const float* __restrict__ bhh, const float* __restrict__ Wc1,
                     const float* __restrict__ bc1, const float* __restrict__ Wc2,
                     const float* __restrict__ bc2, float* __restrict__ out) {
  __shared__ float seqs[TS * 128];
  __shared__ float WihT[128 * 96];
  __shared__ float WhhT[32 * 96];
  __shared__ float giAll[TS * 96];
  __shared__ float rnnS[TS * 32];
  __shared__ float Wc1L[32 * 16];
  __shared__ float Wc2L[16 * 3];
  __shared__ float bihL[96], bhhL[96], bc1L[16], bc2L[3];
  __shared__ float ghs[96], hs[32];
  int t = threadIdx.x;
  for (int idx = t; idx < TS * 128; idx += 256) seqs[idx] = seq[idx];
  for (int idx = t; idx < 96 * 128; idx += 256) { int j = idx >> 7, k = idx & 127; WihT[k * 96 + j] = Wih[idx]; }
  for (int idx = t; idx < 96 * 32; idx += 256) { int j = idx >> 5, k = idx & 31; WhhT[k * 96 + j] = Whh[idx]; }
  for (int idx = t; idx < 512; idx += 256) Wc1L[idx] = Wc1[idx];
  if (t < 48) Wc2L[t] = Wc2[t];
  if (t < 96) { bihL[t] = bih[t]; bhhL[t] = bhh[t]; }
  if (t >= 96 && t < 112) bc1L[t - 96] = bc1[t - 96];
  if (t >= 112 && t < 115) bc2L[t - 112] = bc2[t - 112];
  if (t < 32) hs[t] = 0.f;
  __syncthreads();
  for (int o = t; o < TS * 96; o += 256) {
    int tt = o / 96, j = o - tt * 96;
    float a = bihL[j];
    const float* xr = seqs + tt * 128;
    #pragma unroll 4
    for (int k = 0; k < 128; ++k) a += WihT[k * 96 + j] * xr[k];
    giAll[o] = a;
  }
  __syncthreads();
  for (int tt = 0; tt < TS; ++tt) {
    if (t < 96) {
      float b = bhhL[t];
      #pragma unroll
      for (int k = 0; k < 32; ++k) b += WhhT[k * 96 + t] * hs[k];
      ghs[t] = b;
    }
    __syncthreads();
    if (t < 32) {
      const float* gi = giAll + tt * 96;
      float r = sigm(gi[t] + ghs[t]);
      float z = sigm(gi[32 + t] + ghs[32 + t]);
      float nv = tanhf(gi[64 + t] + r * ghs[64 + t]);
      float h2 = (1.f - z) * nv + z * hs[t];
      hs[t] = h2;
      rnnS[tt * 32 + t] = h2;
    }
    __syncthreads();
  }
  for (int o = t; o < TS * 3; o += 256) {
    int tt = o / 3, c = o - tt * 3;
    float accv = bc2L[c];
    #pragma unroll
    for (int m = 0; m < 16; ++m) {
      float hv = bc1L[m];
      #pragma unroll
      for (int k = 0; k < 32; ++k) hv += rnnS[tt * 32 + k] * Wc1L[k * 16 + m];
      hv = fmaxf(hv, 0.f);
      accv += hv * Wc2L[m * 3 + c];
    }
    out[o] = accv;
  }
}

static inline size_t alignup(size_t x) { return (x + 255) & ~(size_t)255; }

extern "C" void kernel_launch(void* const* d_in, const int* in_sizes, int n_in,
                              void* d_out, int out_size, void* d_ws, size_t ws_size,
                              hipStream_t stream) {
  const float* x1  = (const float*)d_in[0];
  const float* x2  = (const float*)d_in[1];
  const int*   ei1 = (const int*)d_in[2];
  const int*   ei2 = (const int*)d_in[3];
  const float* ew1 = (const float*)d_in[4];
  const float* ew2 = (const float*)d_in[5];
  const float* xn1 = (const float*)d_in[6];
  const float* xn2 = (const float*)d_in[7];
  const float* Wih = (const float*)d_in[25];
  const float* Whh = (const float*)d_in[26];
  const float* bih = (const float*)d_in[27];
  const float* bhh = (const float*)d_in[28];
  const float* Wc1 = (const float*)d_in[29];
  const float* bc1 = (const float*)d_in[30];
  const float* Wc2 = (const float*)d_in[31];
  const float* bc2 = (const float*)d_in[32];
  float* out = (float*)d_out;

  const int FINs[4]  = {4, 128, 128, 64};
  const int FOUTs[4] = {128, 128, 64, 64};
  const size_t uoffs[4] = {0, 24, 792, 1560};
  const size_t woffs[4] = {0, 3072, 101376, 150528};

  size_t off = 0;
  auto take = [&](size_t bytes) -> size_t { size_t o = off; off += alignup(bytes); return o; };
  size_t o_rowptr = take((size_t)NB * (NN + 1) * sizeof(int));
  size_t o_edges  = take((size_t)NB * NE * sizeof(int2));
  size_t o_uS     = take(1944 * sizeof(float));
  size_t o_uD     = take(1944 * sizeof(float));
  size_t o_bth    = take(175104 * sizeof(unsigned short));
  size_t o_btl    = take(175104 * sizeof(unsigned short));
  size_t o_seq    = take((size_t)TS * 128 * sizeof(float));
  size_t persistent = off;

  // G capped at 16: 2 graphs/XCD keeps the gather working set inside one L2
  int G = 8;
  const int cand[2] = {16, 8};
  for (int ci = 0; ci < 2; ++ci) {
    int g = cand[ci];
    size_t need = persistent
                + 2 * alignup((size_t)g * NN * 128 * sizeof(float))
                + alignup((size_t)g * NN * 12 * sizeof(float))
                + alignup((size_t)g * NN * 768 * sizeof(unsigned int));
    if (need <= ws_size) { G = g; break; }
  }
  size_t o_hping = take((size_t)G * NN * 128 * sizeof(float));
  size_t o_hpong = take((size_t)G * NN * 128 * sizeof(float));
  size_t o_sd    = take((size_t)G * NN * 12 * sizeof(float));
  size_t o_agg   = take((size_t)G * NN * 768 * sizeof(unsigned int));
  int sw = ((G & 7) == 0) ? 1 : 0;

  char* ws = (char*)d_ws;
  int*   row_ptr = (int*)(ws + o_rowptr);
  int2*  edges   = (int2*)(ws + o_edges);
  float* uS   = (float*)(ws + o_uS);
  float* uD   = (float*)(ws + o_uD);
  unsigned short* bth = (unsigned short*)(ws + o_bth);
  unsigned short* btl = (unsigned short*)(ws + o_btl);
  float* seq  = (float*)(ws + o_seq);
  float* h_ping = (float*)(ws + o_hping);
  float* h_pong = (float*)(ws + o_hpong);
  float* sdbuf  = (float*)(ws + o_sd);
  unsigned int* aggbuf = (unsigned int*)(ws + o_agg);

  for (int l = 0; l < 4; ++l) {
    const float* Wl  = (const float*)d_in[9 + 4 * l];
    const float* aSl = (const float*)d_in[10 + 4 * l];
    const float* aDl = (const float*)d_in[11 + 4 * l];
    int totw = NH * FINs[l] * FOUTs[l];
    prep_layer_kernel<<<(totw + 255) / 256, 256, 0, stream>>>(
        Wl, aSl, aDl, uS + uoffs[l], uD + uoffs[l],
        bth + woffs[l], btl + woffs[l], FINs[l], FOUTs[l]);
  }
  csr_hist_kernel<<<NB, 256, 0, stream>>>(ei1, ei2, row_ptr);
  csr_scatter_kernel<<<NB * 8, 256, 0, stream>>>(ei1, ei2, ew1, ew2, row_ptr, edges);
  hipMemsetAsync(seq, 0, (size_t)TS * 128 * sizeof(float), stream);

  for (int c0 = 0; c0 < NB; c0 += G) {
    int rows = G * NN;
    copyx_sd0_kernel<<<rows / 256, 256, 0, stream>>>(x1, x2, uS, uD, h_ping, sdbuf, c0);

    // layer 0: FIN=4 -> FOUT=128 (sd epilogue for layer 1)
    agg0_kernel<<<rows / 256, 256, 0, stream>>>(h_ping, sdbuf, row_ptr, edges,
                                                aggbuf, c0, sw);
    gemm_mfma_kernel<128, 2, 4, 2, 2, 1><<<rows / 64, 256, 0, stream>>>(
        aggbuf, bth + woffs[0], btl + woffs[0], (const float*)d_in[12], h_pong,
        24, 1, sw, uS + uoffs[1], uD + uoffs[1], sdbuf, nullptr, nullptr, nullptr, c0);

    // layer 1: FIN=128 -> FOUT=128 (sd epilogue for layer 2)
    aggc_kernel<128, 4><<<rows / 32, 256, 0, stream>>>(h_pong, sdbuf, row_ptr, edges,
                                                       aggbuf, c0, sw);
    gemm_mfma_kernel<128, 2, 4, 2, 2, 1><<<rows / 64, 256, 0, stream>>>(
        aggbuf, bth + woffs[1], btl + woffs[1], (const float*)d_in[16], h_ping,
        768, 1, sw, uS + uoffs[2], uD + uoffs[2], sdbuf, nullptr, nullptr, nullptr, c0);

    // layer 2: FIN=128 -> FOUT=64 (sd epilogue for layer 3)
    aggc_kernel<128, 4><<<rows / 32, 256, 0, stream>>>(h_ping, sdbuf, row_ptr, edges,
                                                       aggbuf, c0, sw);
    gemm_mfma_kernel<64, 1, 4, 4, 1, 1><<<rows / 64, 256, 0, stream>>>(
        aggbuf, bth + woffs[2], btl + woffs[2], (const float*)d_in[20], h_pong,
        768, 1, sw, uS + uoffs[3], uD + uoffs[3], sdbuf, nullptr, nullptr, nullptr, c0);

    // layer 3: FIN=64 -> FOUT=64, readout epilogue (no C write)
    aggc_kernel<64, 2><<<rows / 64, 256, 0, stream>>>(h_pong, sdbuf, row_ptr, edges,
                                                      aggbuf, c0, sw);
    gemm_mfma_kernel<64, 1, 4, 4, 1, 2><<<rows / 64, 256, 0, stream>>>(
        aggbuf, bth + woffs[3], btl + woffs[3], (const float*)d_in[24], nullptr,
        384, 0, sw, nullptr, nullptr, nullptr, xn1, xn2, seq, c0);
  }

  gru_head_kernel<<<1, 256, 0, stream>>>(seq, Wih, Whh, bih, bhh, Wc1, bc1, Wc2, bc2, out);
}

// Round 7
// 2702.146 us; speedup vs baseline: 4.6808x; 1.2277x over previous
//
#include <hip/hip_runtime.h>
#include <math.h>

#define TS 64
#define NN 2048
#define NE 32768
#define NH 6
#define NB 128   // 2*TS graph instances
#define BCAP 6144  // bucket capacity per (graph, dst-range); avg 4096, sd~60

typedef __attribute__((ext_vector_type(8))) __bf16 bf16x8;
typedef __attribute__((ext_vector_type(4))) float f32x4;

__device__ __forceinline__ float lrelu(float x){ return x >= 0.0f ? x : 0.2f*x; }
__device__ __forceinline__ float eluf(float x){ return x > 0.0f ? x : expm1f(x); }
__device__ __forceinline__ float sigm(float x){ return 1.0f/(1.0f+expf(-x)); }
__device__ __forceinline__ unsigned short bfhi(float x){ return (unsigned short)(__float_as_uint(x) >> 16); }
__device__ __forceinline__ float bff(unsigned short u){ return __uint_as_float(((unsigned int)u) << 16); }
__device__ __forceinline__ unsigned int packf(float v){
  unsigned short h = bfhi(v);
  unsigned short l = bfhi(v - bff(h));
  return (unsigned int)h | ((unsigned int)l << 16);
}

struct PrepArgs {
  const float* W[4];
  const float* aS[4];
  const float* aD[4];
};

// ---------- all-layer prep: uS,uD [H*FIN]; B split+transposed bf16 hi/lo [N][K] ----------
__global__ void prep_all_kernel(PrepArgs pa, float* __restrict__ uS, float* __restrict__ uD,
                                unsigned short* __restrict__ bth,
                                unsigned short* __restrict__ btl) {
  const int FINs[4]  = {4, 128, 128, 64};
  const int FOUTs[4] = {128, 128, 64, 64};
  const int uoffs[4] = {0, 24, 792, 1560};
  const int woffs[4] = {0, 3072, 101376, 150528};
  int l = blockIdx.y;
  int FIN = FINs[l], FOUT = FOUTs[l], K = NH * FIN;
  const float* W = pa.W[l];
  int idx = blockIdx.x * 256 + threadIdx.x;
  if (idx < K * FOUT) {
    int k = idx / FOUT, o = idx - k * FOUT;
    int h = k / FIN, f = k - h * FIN;
    float v = W[(size_t)(f * NH + h) * FOUT + o] * (1.0f / NH);
    unsigned short hb = bfhi(v);
    unsigned short lb = bfhi(v - bff(hb));
    bth[woffs[l] + (size_t)o * K + k] = hb;
    btl[woffs[l] + (size_t)o * K + k] = lb;
  }
  if (idx < NH * FIN) {
    int h = idx / FIN, f = idx - h * FIN;
    const float* wr = W + (size_t)(f * NH + h) * FOUT;
    const float* as = pa.aS[l] + h * FOUT;
    const float* ad = pa.aD[l] + h * FOUT;
    float ss = 0.f, dd = 0.f;
    for (int o = 0; o < FOUT; ++o) { float w = wr[o]; ss += w * as[o]; dd += w * ad[o]; }
    uS[uoffs[l] + idx] = ss;
    uD[uoffs[l] + idx] = dd;
  }
}

// ---------- CSR step 1: partial histograms (8 blocks/graph) ----------
__global__ __launch_bounds__(256)
void hist_part_kernel(const int* __restrict__ ei1, const int* __restrict__ ei2,
                      int* __restrict__ deg) {
  __shared__ int cnt[NN];
  int blk = blockIdx.x, t = threadIdx.x;
  int g = blk & (NB - 1), c = blk >> 7;
  int tt = g >> 1, s = g & 1;
  const int* dstp = (s ? ei2 : ei1) + (size_t)(tt * 2 + 1) * NE;
  for (int i = t; i < NN; i += 256) cnt[i] = 0;
  __syncthreads();
  int e0 = c * 4096;
  for (int i = t; i < 4096; i += 256) atomicAdd(&cnt[dstp[e0 + i]], 1);
  __syncthreads();
  for (int i = t; i < NN; i += 256) { int v = cnt[i]; if (v) atomicAdd(&deg[(size_t)g * NN + i], v); }
}

// ---------- CSR step 2: per-graph exclusive scan ----------
__global__ __launch_bounds__(256)
void scan_kernel(const int* __restrict__ deg, int* __restrict__ row_ptr) {
  __shared__ int part[256];
  int g = blockIdx.x, t = threadIdx.x;
  const int* dg = deg + (size_t)g * NN;
  int loc[8]; int run = 0;
  for (int i = 0; i < 8; ++i) { loc[i] = run; run += dg[t * 8 + i]; }
  part[t] = run;
  __syncthreads();
  if (t == 0) { int acc = 0; for (int i = 0; i < 256; ++i) { int v = part[i]; part[i] = acc; acc += v; } }
  __syncthreads();
  int o = part[t];
  int* rp = row_ptr + (size_t)g * (NN + 1);
  for (int i = 0; i < 8; ++i) rp[t * 8 + i] = o + loc[i];
  if (t == 255) rp[NN] = o + run;
}

// ---------- CSR step 3: bucket edges by dst-range, coalesced appends ----------
__global__ __launch_bounds__(256)
void bucketA_kernel(const int* __restrict__ ei1, const int* __restrict__ ei2,
                    const float* __restrict__ ew1, const float* __restrict__ ew2,
                    int* __restrict__ bktCnt, int2* __restrict__ bkt) {
  __shared__ int cnt8[8], base8[8], cur8[8];
  int blk = blockIdx.x, t = threadIdx.x;
  int g = blk & (NB - 1), c = blk >> 7;
  int tt = g >> 1, s = g & 1;
  const int* ei = s ? ei2 : ei1;
  const int* srcp = ei + (size_t)(tt * 2) * NE;
  const int* dstp = ei + (size_t)(tt * 2 + 1) * NE;
  const float* ewp = (s ? ew2 : ew1) + (size_t)tt * NE;
  if (t < 8) cnt8[t] = 0;
  __syncthreads();
  int e0 = c * 4096;
  for (int i = t; i < 4096; i += 256) atomicAdd(&cnt8[dstp[e0 + i] >> 8], 1);
  __syncthreads();
  if (t < 8) { base8[t] = atomicAdd(&bktCnt[g * 8 + t], cnt8[t]); cur8[t] = 0; }
  __syncthreads();
  for (int i = t; i < 4096; i += 256) {
    int e = e0 + i;
    int d = dstp[e];
    int r = d >> 8;
    int pos = base8[r] + atomicAdd(&cur8[r], 1);
    bkt[((size_t)g * 8 + r) * BCAP + pos] =
        make_int2(srcp[e] | ((d & 255) << 16), __float_as_int(ewp[e]));
  }
}

// ---------- CSR step 4: within-bucket scatter (sequential read, windowed write) ----------
__global__ __launch_bounds__(256)
void scatterB_kernel(const int* __restrict__ bktCnt, const int2* __restrict__ bkt,
                     const int* __restrict__ row_ptr, int2* __restrict__ edges) {
  __shared__ int cur[256];
  int blk = blockIdx.x, t = threadIdx.x;
  int g = blk & (NB - 1), r = blk >> 7;
  cur[t] = row_ptr[(size_t)g * (NN + 1) + r * 256 + t];
  __syncthreads();
  int n = bktCnt[g * 8 + r];
  const int2* bp = bkt + ((size_t)g * 8 + r) * BCAP;
  int2* ed = edges + (size_t)g * NE;
  for (int e = t; e < n; e += 256) {
    int2 v = bp[e];
    int dr = v.x >> 16;
    int src = v.x & 0xffff;
    int pos = atomicAdd(&cur[dr], 1);
    ed[pos] = make_int2(src, v.y);
  }
}

// ---------- stage x into xbuf + layer-0 s/d logits ----------
__global__ __launch_bounds__(256)
void copyx_sd0_kernel(const float* __restrict__ x1, const float* __restrict__ x2,
                      const float* __restrict__ uS0, const float* __restrict__ uD0,
                      float* __restrict__ xbuf, float* __restrict__ sdv, int c0) {
  __shared__ float uL[48];
  int t = threadIdx.x;
  if (t < 24) uL[t] = uS0[t];
  else if (t < 48) uL[t] = uD0[t - 24];
  __syncthreads();
  int nodeg = blockIdx.x * 256 + t;
  int gl = nodeg >> 11, n = nodeg & (NN - 1);
  int gi = c0 + gl;
  int tt = gi >> 1, s = gi & 1;
  const float* x = s ? x2 : x1;
  float4 xv = *(const float4*)(x + ((size_t)tt * NN + n) * 4);
  *(float4*)(xbuf + (size_t)nodeg * 4) = xv;
  float* sd = sdv + (size_t)nodeg * 12;
  #pragma unroll
  for (int j = 0; j < 12; ++j) {
    const float* u = uL + (j < 6 ? j * 4 : 24 + (j - 6) * 4);
    sd[j] = xv.x * u[0] + xv.y * u[1] + xv.z * u[2] + xv.w * u[3];
  }
}

// ---------- FUSED layer-0: softmax+aggregate (FIN=4) directly into MFMA staging + GEMM ----------
// reads xbuf (stride 4) + sdA; writes C (stride 128) + sdB (layer-1 logits)
__global__ __launch_bounds__(256)
void gemm0f_kernel(const float* __restrict__ hx, const float* __restrict__ sdv,
                   const int* __restrict__ row_ptr, const int2* __restrict__ edges,
                   const unsigned short* __restrict__ Bth, const unsigned short* __restrict__ Btl,
                   const float* __restrict__ bias, float* __restrict__ C,
                   int sw, const float* __restrict__ uSn, const float* __restrict__ uDn,
                   float* __restrict__ sdo, int c0) {
  constexpr int BN = 128, K = 24;
  constexpr int STG_B = (2048 + 2048 + BN * 32 + BN * 32) * 2;
  constexpr int EPI_B = (64 * (BN + 1) + 12 * (BN + 1)) * 4;
  constexpr int SMEM_B = STG_B > EPI_B ? STG_B : EPI_B;
  __shared__ __align__(16) char smem[SMEM_B];
  __shared__ float mLs[64 * 6];
  unsigned short* AhL = (unsigned short*)smem;
  unsigned short* AlL = AhL + 2048;
  unsigned short* BhL = AlL + 2048;
  unsigned short* BlL = BhL + BN * 32;
  float* CT = (float*)smem;
  float* uL = CT + 64 * (BN + 1);
  int t = threadIdx.x;
  int lane = t & 63, wv = t >> 6;
  int wm = wv & 1, wc = wv >> 1;          // WMC=2, WCC=2
  int l15 = lane & 15, lq = lane >> 4;
  int blk = blockIdx.x;
  const int BPG = NN / 64;
  int m0;
  if (sw) { int xcd = blk & 7, q = blk >> 3; int glx = xcd + ((q / BPG) << 3); int nb = q % BPG; m0 = glx * NN + nb * 64; }
  else    m0 = blk * 64;
  int gl = m0 >> 11, n0 = m0 & (NN - 1);
  int gi = c0 + gl;
  const int* rpg = row_ptr + (size_t)gi * (NN + 1);
  const int2* eg = edges + (size_t)gi * NE;
  const float* sdg = sdv + (size_t)gl * NN * 12;
  const float* hb = hx + (size_t)gl * NN * 4;

  // phase A1: per-(node,head) max
  for (int pid = t; pid < 64 * 6; pid += 256) {
    int nl = pid / 6, j = pid - nl * 6;
    int n = n0 + nl;
    int rp = rpg[n], re = rpg[n + 1];
    float d = sdg[n * 12 + 6 + j];
    float m = -INFINITY;
    for (int e = rp; e < re; ++e) m = fmaxf(m, lrelu(sdg[eg[e].x * 12 + j] + d));
    mLs[pid] = m;
  }
  __syncthreads();
  // phase A2: aggregate into A-staging LDS (packed bf16 hi/lo, swizzled layout)
  {
    int nl = t >> 2, f = t & 3;
    int n = n0 + nl;
    int rp = rpg[n], re = rpg[n + 1];
    float dj[6], mj[6];
    #pragma unroll
    for (int j = 0; j < 6; ++j) { dj[j] = sdg[n * 12 + 6 + j]; mj[j] = mLs[nl * 6 + j]; }
    float accv[6] = {0.f,0.f,0.f,0.f,0.f,0.f};
    float den[6]  = {0.f,0.f,0.f,0.f,0.f,0.f};
    for (int e = rp; e < re; ++e) {
      int2 p = eg[e];
      float wh = __int_as_float(p.y) * hb[(size_t)p.x * 4 + f];
      const float* srow = sdg + (size_t)p.x * 12;
      #pragma unroll
      for (int j = 0; j < 6; ++j) {
        float ex = expf(lrelu(srow[j] + dj[j]) - mj[j]);
        den[j] += ex;
        accv[j] += ex * wh;
      }
    }
    int s4 = (nl >> 1) & 3;
    #pragma unroll
    for (int j = 0; j < 6; ++j) {
      unsigned int u = packf(accv[j] / (den[j] + 1e-16f));
      int pos = nl * 32 + (((j >> 1) ^ s4) << 3) + ((j & 1) << 2) + f;
      AhL[pos] = (unsigned short)(u & 0xffff);
      AlL[pos] = (unsigned short)(u >> 16);
    }
    #pragma unroll
    for (int j = 6; j < 8; ++j) {
      int pos = nl * 32 + (((j >> 1) ^ s4) << 3) + ((j & 1) << 2) + f;
      AhL[pos] = 0; AlL[pos] = 0;
    }
  }
  // B staging (single 32-k tile, zero-padded past K=24)
  #pragma unroll
  for (int i = 0; i < 2; ++i) {
    int q = t + i * 256;
    int n = q >> 2, c = q & 3;
    uint4 vh = make_uint4(0, 0, 0, 0), vl = make_uint4(0, 0, 0, 0);
    int k = c * 8;
    if (k < K) {
      vh = *(const uint4*)(Bth + (size_t)n * K + k);
      vl = *(const uint4*)(Btl + (size_t)n * K + k);
    }
    int pos = n * 32 + ((c ^ ((n >> 1) & 3)) << 3);
    *(uint4*)&BhL[pos] = vh;
    *(uint4*)&BlL[pos] = vl;
  }
  __syncthreads();
  f32x4 acc[2][4];
  #pragma unroll
  for (int i = 0; i < 2; ++i)
    #pragma unroll
    for (int j = 0; j < 4; ++j) { f32x4 z = {0.f,0.f,0.f,0.f}; acc[i][j] = z; }
  bf16x8 ah[2], al[2], bh[4], bl[4];
  #pragma unroll
  for (int fr = 0; fr < 2; ++fr) {
    int row = wm * 32 + fr * 16 + l15;
    int p = row * 32 + ((lq ^ ((row >> 1) & 3)) << 3);
    ah[fr] = *(const bf16x8*)&AhL[p];
    al[fr] = *(const bf16x8*)&AlL[p];
  }
  #pragma unroll
  for (int fc = 0; fc < 4; ++fc) {
    int row = wc * 64 + fc * 16 + l15;
    int p = row * 32 + ((lq ^ ((row >> 1) & 3)) << 3);
    bh[fc] = *(const bf16x8*)&BhL[p];
    bl[fc] = *(const bf16x8*)&BlL[p];
  }
  #pragma unroll
  for (int fr = 0; fr < 2; ++fr)
    #pragma unroll
    for (int fc = 0; fc < 4; ++fc) {
      acc[fr][fc] = __builtin_amdgcn_mfma_f32_16x16x32_bf16(ah[fr], bh[fc], acc[fr][fc], 0, 0, 0);
      acc[fr][fc] = __builtin_amdgcn_mfma_f32_16x16x32_bf16(ah[fr], bl[fc], acc[fr][fc], 0, 0, 0);
      acc[fr][fc] = __builtin_amdgcn_mfma_f32_16x16x32_bf16(al[fr], bh[fc], acc[fr][fc], 0, 0, 0);
    }
  __syncthreads();
  #pragma unroll
  for (int fr = 0; fr < 2; ++fr) {
    int rl0 = wm * 32 + fr * 16 + lq * 4;
    #pragma unroll
    for (int fc = 0; fc < 4; ++fc) {
      int col = wc * 64 + fc * 16 + l15;
      float bv = bias[col];
      #pragma unroll
      for (int r = 0; r < 4; ++r) {
        float v = eluf(acc[fr][fc][r] + bv);
        C[(size_t)(m0 + rl0 + r) * BN + col] = v;
        CT[(rl0 + r) * (BN + 1) + col] = v;
      }
    }
  }
  __syncthreads();
  for (int idx = t; idx < 12 * BN; idx += 256) {
    int j = idx / BN, f = idx - j * BN;
    uL[j * (BN + 1) + f] = (j < 6) ? uSn[j * BN + f] : uDn[(j - 6) * BN + f];
  }
  __syncthreads();
  for (int o = t; o < 64 * 12; o += 256) {
    int rl = o / 12, j = o - rl * 12;
    const float* ur = uL + j * (BN + 1);
    const float* cr = CT + rl * (BN + 1);
    float a = 0.f;
    for (int f = 0; f < BN; ++f) a += cr[f] * ur[f];
    sdo[(size_t)(m0 + rl) * 12 + j] = a;
  }
}

// ---------- softmax+aggregate (FIN=64/128): cached unnorm alpha, end-normalize ----------
template<int FIN, int PT>
__global__ __launch_bounds__(256)
void aggc_kernel(const float* __restrict__ h, const float* __restrict__ sdv,
                 const int* __restrict__ row_ptr, const int2* __restrict__ edges,
                 unsigned int* __restrict__ agg, int c0, int sw) {
  const int TPN = FIN / 4;
  const int NPB = 256 / TPN;
  const int IL = 4;
  const int BPG = NN / (NPB * IL);
  const int CAP = 80;
  __shared__ float awL[NPB][CAP][6];
  __shared__ int   srcL[NPB][CAP];
  __shared__ float mLs[NPB * 6], ivLs[NPB * 6];
  int t = threadIdx.x, blk = blockIdx.x;
  int gl, nb;
  if (sw) { int xcd = blk & 7, q = blk >> 3; gl = xcd + ((q / BPG) << 3); nb = q % BPG; }
  else    { gl = blk / BPG; nb = blk % BPG; }
  int gi = c0 + gl;
  const int* rpg = row_ptr + (size_t)gi * (NN + 1);
  const int2* eg = edges + (size_t)gi * NE;
  const float* sdg = sdv + (size_t)gl * NN * 12;
  const float4* hb4 = (const float4*)(h + (size_t)gl * NN * FIN);
  unsigned int* aggb = agg + (size_t)gl * NN * (6 * FIN);
  for (int it = 0; it < IL; ++it) {
    __syncthreads();
    int n0 = nb * (NPB * IL) + it * NPB;
    int pid = t / PT, sub = t % PT;
    if (pid < NPB * 6) {
      int nl = pid / 6, j = pid - nl * 6;
      int n = n0 + nl;
      int rp = rpg[n], re = rpg[n + 1];
      float d = sdg[n * 12 + 6 + j];
      float m = -INFINITY;
      for (int e = rp + sub; e < re; e += PT) m = fmaxf(m, lrelu(sdg[eg[e].x * 12 + j] + d));
      #pragma unroll
      for (int msk = PT >> 1; msk; msk >>= 1) m = fmaxf(m, __shfl_xor(m, msk, PT));
      float den = 0.f;
      for (int e = rp + sub; e < re; e += PT) {
        int2 p = eg[e];
        float ex = expf(lrelu(sdg[p.x * 12 + j] + d) - m);
        den += ex;
        int idx = e - rp;
        if (idx < CAP) {
          awL[nl][idx][j] = ex * __int_as_float(p.y);
          if (j == 0) srcL[nl][idx] = p.x;
        }
      }
      #pragma unroll
      for (int msk = PT >> 1; msk; msk >>= 1) den += __shfl_xor(den, msk, PT);
      if (sub == 0) { mLs[pid] = m; ivLs[pid] = 1.f / (den + 1e-16f); }
    }
    __syncthreads();
    int nl = t / TPN, f4 = t % TPN;
    int n = n0 + nl;
    int rp = rpg[n], re = rpg[n + 1];
    float4 acc[6];
    #pragma unroll
    for (int j = 0; j < 6; ++j) acc[j] = make_float4(0.f, 0.f, 0.f, 0.f);
    if (re - rp <= CAP) {
      for (int e = rp; e < re; ++e) {
        int idx = e - rp;
        int sct = srcL[nl][idx];
        float4 hv = hb4[(size_t)sct * TPN + f4];
        #pragma unroll
        for (int j = 0; j < 6; ++j) {
          float a = awL[nl][idx][j];
          acc[j].x += a * hv.x; acc[j].y += a * hv.y;
          acc[j].z += a * hv.z; acc[j].w += a * hv.w;
        }
      }
    } else {
      float dj[6], mj[6];
      #pragma unroll
      for (int j = 0; j < 6; ++j) { dj[j] = sdg[n * 12 + 6 + j]; mj[j] = mLs[nl * 6 + j]; }
      for (int e = rp; e < re; ++e) {
        int idx = e - rp;
        int2 p = eg[e];
        float4 hv = hb4[(size_t)p.x * TPN + f4];
        if (idx < CAP) {
          #pragma unroll
          for (int j = 0; j < 6; ++j) {
            float a = awL[nl][idx][j];
            acc[j].x += a * hv.x; acc[j].y += a * hv.y;
            acc[j].z += a * hv.z; acc[j].w += a * hv.w;
          }
        } else {
          float w = __int_as_float(p.y);
          const float* srow = sdg + (size_t)p.x * 12;
          #pragma unroll
          for (int j = 0; j < 6; ++j) {
            float a = expf(lrelu(srow[j] + dj[j]) - mj[j]) * w;
            acc[j].x += a * hv.x; acc[j].y += a * hv.y;
            acc[j].z += a * hv.z; acc[j].w += a * hv.w;
          }
        }
      }
    }
    unsigned int* ar = aggb + (size_t)n * (6 * FIN);
    #pragma unroll
    for (int j = 0; j < 6; ++j) {
      float iv = ivLs[nl * 6 + j];
      uint4 pk;
      pk.x = packf(acc[j].x * iv); pk.y = packf(acc[j].y * iv);
      pk.z = packf(acc[j].z * iv); pk.w = packf(acc[j].w * iv);
      *(uint4*)(ar + j * FIN + f4 * 4) = pk;
    }
  }
}

// ---------- MFMA GEMM (A pre-split packed bf16 hi|lo) + fused epilogue; LDS overlay ----------
// EPI: 1 = write C + next-layer s/d logits; 2 = readout only (no C write)
template<int BN, int MF, int NF, int WMC, int WCC, int EPI>
__global__ __launch_bounds__(256)
void gemm_mfma_kernel(const unsigned int* __restrict__ A,
                      const unsigned short* __restrict__ Bth,
                      const unsigned short* __restrict__ Btl,
                      const float* __restrict__ bias, float* __restrict__ C,
                      int K, int act, int sw,
                      const float* __restrict__ uSn, const float* __restrict__ uDn,
                      float* __restrict__ sdv,
                      const float* __restrict__ xn1, const float* __restrict__ xn2,
                      float* __restrict__ seqv, int c0) {
  static_assert(BN == WCC * NF * 16 && 64 == WMC * MF * 16, "tile mismatch");
  constexpr int STG_B = (2048 + 2048 + BN * 32 + BN * 32) * 2;
  constexpr int EPI_B = (64 * (BN + 1) + 12 * (BN + 1) + 64 + 256) * 4;
  constexpr int SMEM_B = STG_B > EPI_B ? STG_B : EPI_B;
  __shared__ __align__(16) char smem[SMEM_B];
  unsigned short* AhL = (unsigned short*)smem;
  unsigned short* AlL = AhL + 2048;
  unsigned short* BhL = AlL + 2048;
  unsigned short* BlL = BhL + BN * 32;
  float* CT  = (float*)smem;
  float* uL  = CT + 64 * (BN + 1);
  float* xnL = uL + 12 * (BN + 1);
  float* red = xnL + 64;
  int t = threadIdx.x;
  int lane = t & 63, wv = t >> 6;
  int wm = wv % WMC, wc = wv / WMC;
  int l15 = lane & 15, lq = lane >> 4;
  int blk = blockIdx.x;
  const int BPG = NN / 64;
  int m0;
  if (sw) { int xcd = blk & 7, q = blk >> 3; int gl = xcd + ((q / BPG) << 3); int nb = q % BPG; m0 = gl * NN + nb * 64; }
  else    m0 = blk * 64;
  f32x4 acc[MF][NF];
  #pragma unroll
  for (int i = 0; i < MF; ++i)
    #pragma unroll
    for (int j = 0; j < NF; ++j) { f32x4 z = {0.f, 0.f, 0.f, 0.f}; acc[i][j] = z; }

  for (int k0 = 0; k0 < K; k0 += 32) {
    __syncthreads();
    #pragma unroll
    for (int i = 0; i < 2; ++i) {
      int q = t + i * 256;
      int row = q >> 3, c4 = q & 7;
      uint4 av = make_uint4(0, 0, 0, 0);
      int k = k0 + c4 * 4;
      if (k < K) av = *(const uint4*)(A + (size_t)(m0 + row) * K + k);
      int pos = row * 32 + (((c4 >> 1) ^ ((row >> 1) & 3)) << 3) + ((c4 & 1) << 2);
      *(ushort4*)&AhL[pos] = make_ushort4(av.x & 0xffff, av.y & 0xffff, av.z & 0xffff, av.w & 0xffff);
      *(ushort4*)&AlL[pos] = make_ushort4(av.x >> 16, av.y >> 16, av.z >> 16, av.w >> 16);
    }
    #pragma unroll
    for (int i = 0; i < BN / 64; ++i) {
      int q = t + i * 256;
      int n = q >> 2, c = q & 3;
      uint4 vh = make_uint4(0, 0, 0, 0), vl = make_uint4(0, 0, 0, 0);
      int k = k0 + c * 8;
      if (k < K) {
        vh = *(const uint4*)(Bth + (size_t)n * K + k);
        vl = *(const uint4*)(Btl + (size_t)n * K + k);
      }
      int pos = n * 32 + ((c ^ ((n >> 1) & 3)) << 3);
      *(uint4*)&BhL[pos] = vh;
      *(uint4*)&BlL[pos] = vl;
    }
    __syncthreads();
    bf16x8 ah[MF], al[MF], bh[NF], bl[NF];
    #pragma unroll
    for (int fr = 0; fr < MF; ++fr) {
      int row = wm * MF * 16 + fr * 16 + l15;
      int p = row * 32 + ((lq ^ ((row >> 1) & 3)) << 3);
      ah[fr] = *(const bf16x8*)&AhL[p];
      al[fr] = *(const bf16x8*)&AlL[p];
    }
    #pragma unroll
    for (int fc = 0; fc < NF; ++fc) {
      int row = wc * NF * 16 + fc * 16 + l15;
      int p = row * 32 + ((lq ^ ((row >> 1) & 3)) << 3);
      bh[fc] = *(const bf16x8*)&BhL[p];
      bl[fc] = *(const bf16x8*)&BlL[p];
    }
    #pragma unroll
    for (int fr = 0; fr < MF; ++fr)
      #pragma unroll
      for (int fc = 0; fc < NF; ++fc) {
        acc[fr][fc] = __builtin_amdgcn_mfma_f32_16x16x32_bf16(ah[fr], bh[fc], acc[fr][fc], 0, 0, 0);
        acc[fr][fc] = __builtin_amdgcn_mfma_f32_16x16x32_bf16(ah[fr], bl[fc], acc[fr][fc], 0, 0, 0);
        acc[fr][fc] = __builtin_amdgcn_mfma_f32_16x16x32_bf16(al[fr], bh[fc], acc[fr][fc], 0, 0, 0);
      }
  }
  __syncthreads();
  #pragma unroll
  for (int fr = 0; fr < MF; ++fr) {
    int rl0 = wm * MF * 16 + fr * 16 + lq * 4;
    #pragma unroll
    for (int fc = 0; fc < NF; ++fc) {
      int col = wc * NF * 16 + fc * 16 + l15;
      float bv = bias[col];
      #pragma unroll
      for (int r = 0; r < 4; ++r) {
        float v = acc[fr][fc][r] + bv;
        if (act) v = eluf(v);
        if (EPI != 2) C[(size_t)(m0 + rl0 + r) * BN + col] = v;
        CT[(rl0 + r) * (BN + 1) + col] = v;
      }
    }
  }
  __syncthreads();
  if (EPI == 1) {
    for (int idx = t; idx < 12 * BN; idx += 256) {
      int j = idx / BN, f = idx - j * BN;
      uL[j * (BN + 1) + f] = (j < 6) ? uSn[j * BN + f] : uDn[(j - 6) * BN + f];
    }
    __syncthreads();
    for (int o = t; o < 64 * 12; o += 256) {
      int rl = o / 12, j = o - rl * 12;
      const float* ur = uL + j * (BN + 1);
      const float* cr = CT + rl * (BN + 1);
      float a = 0.f;
      for (int f = 0; f < BN; ++f) a += cr[f] * ur[f];
      sdv[(size_t)(m0 + rl) * 12 + j] = a;
    }
  } else {
    int gl = m0 >> 11;
    int gi = c0 + gl;
    int tt = gi >> 1, ss = gi & 1;
    const float* xn = (ss ? xn2 : xn1) + (size_t)tt * NN;
    int nl0 = m0 & (NN - 1);
    if (t < 64) xnL[t] = xn[nl0 + t];
    __syncthreads();
    int d = t & 63, q = t >> 6;
    float a = 0.f;
    #pragma unroll
    for (int i = 0; i < 16; ++i) a += xnL[q * 16 + i] * CT[(q * 16 + i) * (BN + 1) + d];
    red[t] = a;
    __syncthreads();
    if (t < 64)
      atomicAdd(&seqv[tt * 128 + ss * 64 + t], red[t] + red[t + 64] + red[t + 128] + red[t + 192]);
  }
}

// ---------- GRU + MLP head: all weights in LDS ----------
__global__ __launch_bounds__(256)
void gru_head_kernel(const float* __restrict__ seq, const float* __restrict__ Wih,
                     const float* __restrict__ Whh, const float* __restrict__ bih,
                     const float* __restrict__ bhh, const float* __restrict__ Wc1,
                     const float* __restrict__ bc1, const float* __restrict__ Wc2,
                     const float* __restrict__ bc2, float* __restrict__ out) {
  __shared__ float seqs[TS * 128];
  __shared__ float WihT[128 * 96];
  __shared__ float WhhT[32 * 96];
  __shared__ float giAll[TS * 96];
  __shared__ float rnnS[TS * 32];
  __shared__ float Wc1L[32 * 16];
  __shared__ float Wc2L[16 * 3];
  __shared__ float bihL[96], bhhL[96], bc1L[16], bc2L[3];
  __shared__ float ghs[96], hs[32];
  int t = threadIdx.x;
  for (int idx = t; idx < TS * 128; idx += 256) seqs[idx] = seq[idx];
  for (int idx = t; idx < 96 * 128; idx += 256) { int j = idx >> 7, k = idx & 127; WihT[k * 96 + j] = Wih[idx]; }
  for (int idx = t; idx < 96 * 32; idx += 256) { int j = idx >> 5, k = idx & 31; WhhT[k * 96 + j] = Whh[idx]; }
  for (int idx = t; idx < 512; idx += 256) Wc1L[idx] = Wc1[idx];
  if (t < 48) Wc2L[t] = Wc2[t];
  if (t < 96) { bihL[t] = bih[t]; bhhL[t] = bhh[t]; }
  if (t >= 96 && t < 112) bc1L[t - 96] = bc1[t - 96];
  if (t >= 112 && t < 115) bc2L[t - 112] = bc2[t - 112];
  if (t < 32) hs[t] = 0.f;
  __syncthreads();
  for (int o = t; o < TS * 96; o += 256) {
    int tt = o / 96, j = o - tt * 96;
    float a = bihL[j];
    const float* xr = seqs + tt * 128;
    #pragma unroll 4
    for (int k = 0; k < 128; ++k) a += WihT[k * 96 + j] * xr[k];
    giAll[o] = a;
  }
  __syncthreads();
  for (int tt = 0; tt < TS; ++tt) {
    if (t < 96) {
      float b = bhhL[t];
      #pragma unroll
      for (int k = 0; k < 32; ++k) b += WhhT[k * 96 + t] * hs[k];
      ghs[t] = b;
    }
    __syncthreads();
    if (t < 32) {
      const float* gi = giAll + tt * 96;
      float r = sigm(gi[t] + ghs[t]);
      float z = sigm(gi[32 + t] + ghs[32 + t]);
      float nv = tanhf(gi[64 + t] + r * ghs[64 + t]);
      float h2 = (1.f - z) * nv + z * hs[t];
      hs[t] = h2;
      rnnS[tt * 32 + t] = h2;
    }
    __syncthreads();
  }
  for (int o = t; o < TS * 3; o += 256) {
    int tt = o / 3, c = o - tt * 3;
    float accv = bc2L[c];
    #pragma unroll
    for (int m = 0; m < 16; ++m) {
      float hv = bc1L[m];
      #pragma unroll
      for (int k = 0; k < 32; ++k) hv += rnnS[tt * 32 + k] * Wc1L[k * 16 + m];
      hv = fmaxf(hv, 0.f);
      accv += hv * Wc2L[m * 3 + c];
    }
    out[o] = accv;
  }
}

static inline size_t alignup(size_t x) { return (x + 255) & ~(size_t)255; }

extern "C" void kernel_launch(void* const* d_in, const int* in_sizes, int n_in,
                              void* d_out, int out_size, void* d_ws, size_t ws_size,
                              hipStream_t stream) {
  const float* x1  = (const float*)d_in[0];
  const float* x2  = (const float*)d_in[1];
  const int*   ei1 = (const int*)d_in[2];
  const int*   ei2 = (const int*)d_in[3];
  const float* ew1 = (const float*)d_in[4];
  const float* ew2 = (const float*)d_in[5];
  const float* xn1 = (const float*)d_in[6];
  const float* xn2 = (const float*)d_in[7];
  const float* Wih = (const float*)d_in[25];
  const float* Whh = (const float*)d_in[26];
  const float* bih = (const float*)d_in[27];
  const float* bhh = (const float*)d_in[28];
  const float* Wc1 = (const float*)d_in[29];
  const float* bc1 = (const float*)d_in[30];
  const float* Wc2 = (const float*)d_in[31];
  const float* bc2 = (const float*)d_in[32];
  float* out = (float*)d_out;

  const size_t uoffs[4] = {0, 24, 792, 1560};
  const size_t woffs[4] = {0, 3072, 101376, 150528};

  size_t off = 0;
  auto take = [&](size_t bytes) -> size_t { size_t o = off; off += alignup(bytes); return o; };
  size_t o_rowptr = take((size_t)NB * (NN + 1) * sizeof(int));
  size_t o_edges  = take((size_t)NB * NE * sizeof(int2));
  size_t o_uS     = take(1944 * sizeof(float));
  size_t o_uD     = take(1944 * sizeof(float));
  size_t o_bth    = take(175104 * sizeof(unsigned short));
  size_t o_btl    = take(175104 * sizeof(unsigned short));
  size_t o_seq    = take((size_t)TS * 128 * sizeof(float));
  size_t persistent = off;

  const size_t BKT_BYTES = (size_t)NB * 8 * BCAP * sizeof(int2);          // 48 MB
  const size_t BKT_NEED  = BKT_BYTES + 4096 + (size_t)NB * NN * sizeof(int);

  int G = 8;
  const int cand[3] = {32, 16, 8};
  for (int ci = 0; ci < 3; ++ci) {
    int g = cand[ci];
    size_t aggB = (size_t)g * NN * 768 * sizeof(unsigned int);
    size_t need = persistent
                + alignup((size_t)g * NN * 4 * sizeof(float))
                + alignup((size_t)g * NN * 128 * sizeof(float))
                + 2 * alignup((size_t)g * NN * 12 * sizeof(float))
                + alignup(aggB > BKT_NEED ? aggB : BKT_NEED);
    if (need <= ws_size) { G = g; break; }
  }
  size_t aggB = (size_t)G * NN * 768 * sizeof(unsigned int);
  size_t o_x   = take((size_t)G * NN * 4 * sizeof(float));
  size_t o_h   = take((size_t)G * NN * 128 * sizeof(float));
  size_t o_sdA = take((size_t)G * NN * 12 * sizeof(float));
  size_t o_sdB = take((size_t)G * NN * 12 * sizeof(float));
  size_t o_agg = take(aggB > BKT_NEED ? aggB : BKT_NEED);
  int sw = ((G & 7) == 0) ? 1 : 0;

  char* ws = (char*)d_ws;
  int*   row_ptr = (int*)(ws + o_rowptr);
  int2*  edges   = (int2*)(ws + o_edges);
  float* uS   = (float*)(ws + o_uS);
  float* uD   = (float*)(ws + o_uD);
  unsigned short* bth = (unsigned short*)(ws + o_bth);
  unsigned short* btl = (unsigned short*)(ws + o_btl);
  float* seq  = (float*)(ws + o_seq);
  float* xbuf = (float*)(ws + o_x);
  float* hbuf = (float*)(ws + o_h);
  float* sdA  = (float*)(ws + o_sdA);
  float* sdB  = (float*)(ws + o_sdB);
  unsigned int* aggbuf = (unsigned int*)(ws + o_agg);
  // transient CSR scratch aliased onto aggbuf
  int2* bkt    = (int2*)(ws + o_agg);
  int*  bktCnt = (int*)(ws + o_agg + BKT_BYTES);
  int*  deg    = (int*)(ws + o_agg + BKT_BYTES + 4096);

  // ---- prep + CSR + zero ----
  PrepArgs pa;
  for (int l = 0; l < 4; ++l) {
    pa.W[l]  = (const float*)d_in[9 + 4 * l];
    pa.aS[l] = (const float*)d_in[10 + 4 * l];
    pa.aD[l] = (const float*)d_in[11 + 4 * l];
  }
  prep_all_kernel<<<dim3(384, 4), 256, 0, stream>>>(pa, uS, uD, bth, btl);
  hipMemsetAsync(ws + o_agg + BKT_BYTES, 0, 4096 + (size_t)NB * NN * sizeof(int), stream);
  hipMemsetAsync(seq, 0, (size_t)TS * 128 * sizeof(float), stream);
  hist_part_kernel<<<NB * 8, 256, 0, stream>>>(ei1, ei2, deg);
  scan_kernel<<<NB, 256, 0, stream>>>(deg, row_ptr);
  bucketA_kernel<<<NB * 8, 256, 0, stream>>>(ei1, ei2, ew1, ew2, bktCnt, bkt);
  scatterB_kernel<<<NB * 8, 256, 0, stream>>>(bktCnt, bkt, row_ptr, edges);

  // ---- chunked GAT pipeline (8 dispatches per chunk) ----
  for (int c0 = 0; c0 < NB; c0 += G) {
    int rows = G * NN;
    copyx_sd0_kernel<<<rows / 256, 256, 0, stream>>>(x1, x2, uS, uD, xbuf, sdA, c0);

    // layer 0 fused: agg(FIN=4)+GEMM(K=24,BN=128), sd epilogue -> sdB
    gemm0f_kernel<<<rows / 64, 256, 0, stream>>>(
        xbuf, sdA, row_ptr, edges, bth + woffs[0], btl + woffs[0],
        (const float*)d_in[12], hbuf, sw, uS + uoffs[1], uD + uoffs[1], sdB, c0);

    // layer 1: FIN=128 -> FOUT=128 (sd epilogue -> sdA)
    aggc_kernel<128, 4><<<rows / 32, 256, 0, stream>>>(hbuf, sdB, row_ptr, edges,
                                                       aggbuf, c0, sw);
    gemm_mfma_kernel<128, 2, 4, 2, 2, 1><<<rows / 64, 256, 0, stream>>>(
        aggbuf, bth + woffs[1], btl + woffs[1], (const float*)d_in[16], hbuf,
        768, 1, sw, uS + uoffs[2], uD + uoffs[2], sdA, nullptr, nullptr, nullptr, c0);

    // layer 2: FIN=128 -> FOUT=64 (sd epilogue -> sdB), h written in-place stride 64
    aggc_kernel<128, 4><<<rows / 32, 256, 0, stream>>>(hbuf, sdA, row_ptr, edges,
                                                       aggbuf, c0, sw);
    gemm_mfma_kernel<64, 1, 4, 4, 1, 1><<<rows / 64, 256, 0, stream>>>(
        aggbuf, bth + woffs[2], btl + woffs[2], (const float*)d_in[20], hbuf,
        768, 1, sw, uS + uoffs[3], uD + uoffs[3], sdB, nullptr, nullptr, nullptr, c0);

    // layer 3: FIN=64 -> FOUT=64, readout epilogue (no C write)
    aggc_kernel<64, 2><<<rows / 64, 256, 0, stream>>>(hbuf, sdB, row_ptr, edges,
                                                      aggbuf, c0, sw);
    gemm_mfma_kernel<64, 1, 4, 4, 1, 2><<<rows / 64, 256, 0, stream>>>(
        aggbuf, bth + woffs[3], btl + woffs[3], (const float*)d_in[24], nullptr,
        384, 0, sw, nullptr, nullptr, nullptr, xn1, xn2, seq, c0);
  }

  gru_head_kernel<<<1, 256, 0, stream>>>(seq, Wih, Whh, bih, bhh, Wc1, bc1, Wc2, bc2, out);
}